// Round 7
// baseline (2266.863 us; speedup 1.0000x reference)
//
#include <hip/hip_runtime.h>
#include <math.h>

#define NPATCH 100000
#define CDIM   256
#define NMOOD  64
#define NGENRE 256
#define NSUB   512
#define NLBL   832          // 64+256+512
#define KTOP   9

// ---- f32 fallback screen constants (R4, known-green) ----
#define NCHUNK 39
#define CHUNK  2624
#define BLK    64
#define KC     32
#define KP     12

// ---- MFMA screen constants ----
#define PBLK   1600         // patches per chunk
#define NCH3   63           // 63*1600 = 100800 >= 100000
#define NGRP   100          // PBLK/16
#define KPS    16           // per-(label,chunk) partial size
#define SL     5            // per-lane list depth
#define NCAND  32           // exact re-rank candidate count

typedef __attribute__((ext_vector_type(8))) short bf16x8;
typedef __attribute__((ext_vector_type(8))) unsigned short u16x8;
typedef __attribute__((ext_vector_type(4))) float f32x4;

// ---------------- serial top-k insert (ascending by (val,idx)) --------------

template <int K>
__device__ __forceinline__ void tk_insert(float (&v)[K], int (&ii)[K],
                                          float s, int idx) {
  if (s < v[K - 1] || (s == v[K - 1] && idx < ii[K - 1])) {
    v[K - 1] = s; ii[K - 1] = idx;
#pragma unroll
    for (int t = K - 1; t > 0; --t) {
      bool sw = (v[t] < v[t - 1]) || (v[t] == v[t - 1] && ii[t] < ii[t - 1]);
      if (sw) {
        float fv = v[t]; v[t] = v[t - 1]; v[t - 1] = fv;
        int fi = ii[t]; ii[t] = ii[t - 1]; ii[t - 1] = fi;
      }
    }
  }
}

// ------ numpy-pairwise sum of squares over 256 contiguous floats ------------

__device__ float np_sq256(const float* a) {
  float b0, b1;
  {
    float r[8];
#pragma unroll
    for (int i = 0; i < 8; ++i) { float x = a[i]; r[i] = __fmul_rn(x, x); }
    for (int j = 8; j < 128; j += 8)
#pragma unroll
      for (int i = 0; i < 8; ++i) {
        float x = a[j + i];
        r[i] = __fadd_rn(r[i], __fmul_rn(x, x));
      }
    b0 = __fadd_rn(__fadd_rn(__fadd_rn(r[0], r[1]), __fadd_rn(r[2], r[3])),
                   __fadd_rn(__fadd_rn(r[4], r[5]), __fadd_rn(r[6], r[7])));
  }
  {
    float r[8];
#pragma unroll
    for (int i = 0; i < 8; ++i) { float x = a[128 + i]; r[i] = __fmul_rn(x, x); }
    for (int j = 8; j < 128; j += 8)
#pragma unroll
      for (int i = 0; i < 8; ++i) {
        float x = a[128 + j + i];
        r[i] = __fadd_rn(r[i], __fmul_rn(x, x));
      }
    b1 = __fadd_rn(__fadd_rn(__fadd_rn(r[0], r[1]), __fadd_rn(r[2], r[3])),
                   __fadd_rn(__fadd_rn(r[4], r[5]), __fadd_rn(r[6], r[7])));
  }
  return __fadd_rn(b0, b1);
}

__device__ __forceinline__ float np_key(float ln, float dot, float pn) {
  return __fadd_rn(__fsub_rn(ln, __fmul_rn(2.f, dot)), pn);
}

// ---------------- kernel: concat labels into one (832,256) matrix -----------

__global__ void k_concat_labels(const float* __restrict__ mood,
                                const float* __restrict__ genre,
                                const float* __restrict__ sub,
                                float* __restrict__ lbl) {
  int i = blockIdx.x * 256 + threadIdx.x;
  if (i < NMOOD * CDIM) lbl[i] = mood[i];
  else if (i < (NMOOD + NGENRE) * CDIM) lbl[i] = genre[i - NMOOD * CDIM];
  else lbl[i] = sub[i - (NMOOD + NGENRE) * CDIM];
}

// ---------------- kernel: fused bf16-convert + numpy-pairwise norms ---------
// One lane per 128-float half-row: float4x2 coalesced reads, r[i] strided
// accumulators in exact np order, u16x8 bf16 writes, shfl-pair combine.

__device__ __forceinline__ unsigned short f2bf(float x) {
  unsigned u = __float_as_uint(x);
  return (unsigned short)((u + 0x7fffu + ((u >> 16) & 1u)) >> 16);
}

__global__ void k_prep(const float* __restrict__ src, int n,
                       unsigned short* __restrict__ dst,
                       float* __restrict__ norms) {
  int gid = blockIdx.x * blockDim.x + threadIdx.x;
  int stride = gridDim.x * blockDim.x;
  int nh = n * 2;
  for (int hid = gid; hid < nh; hid += stride) {
    int row = hid >> 1, half = hid & 1;
    const float* a = src + (size_t)row * CDIM + half * 128;
    unsigned short* d = dst + (size_t)row * CDIM + half * 128;
    float r[8];
    {
      float4 v0 = *(const float4*)a;
      float4 v1 = *(const float4*)(a + 4);
      r[0] = __fmul_rn(v0.x, v0.x); r[1] = __fmul_rn(v0.y, v0.y);
      r[2] = __fmul_rn(v0.z, v0.z); r[3] = __fmul_rn(v0.w, v0.w);
      r[4] = __fmul_rn(v1.x, v1.x); r[5] = __fmul_rn(v1.y, v1.y);
      r[6] = __fmul_rn(v1.z, v1.z); r[7] = __fmul_rn(v1.w, v1.w);
      u16x8 o;
      o[0] = f2bf(v0.x); o[1] = f2bf(v0.y); o[2] = f2bf(v0.z); o[3] = f2bf(v0.w);
      o[4] = f2bf(v1.x); o[5] = f2bf(v1.y); o[6] = f2bf(v1.z); o[7] = f2bf(v1.w);
      *(u16x8*)d = o;
    }
    for (int j = 1; j < 16; ++j) {
      float4 v0 = *(const float4*)(a + j * 8);
      float4 v1 = *(const float4*)(a + j * 8 + 4);
      r[0] = __fadd_rn(r[0], __fmul_rn(v0.x, v0.x));
      r[1] = __fadd_rn(r[1], __fmul_rn(v0.y, v0.y));
      r[2] = __fadd_rn(r[2], __fmul_rn(v0.z, v0.z));
      r[3] = __fadd_rn(r[3], __fmul_rn(v0.w, v0.w));
      r[4] = __fadd_rn(r[4], __fmul_rn(v1.x, v1.x));
      r[5] = __fadd_rn(r[5], __fmul_rn(v1.y, v1.y));
      r[6] = __fadd_rn(r[6], __fmul_rn(v1.z, v1.z));
      r[7] = __fadd_rn(r[7], __fmul_rn(v1.w, v1.w));
      u16x8 o;
      o[0] = f2bf(v0.x); o[1] = f2bf(v0.y); o[2] = f2bf(v0.z); o[3] = f2bf(v0.w);
      o[4] = f2bf(v1.x); o[5] = f2bf(v1.y); o[6] = f2bf(v1.z); o[7] = f2bf(v1.w);
      *(u16x8*)(d + j * 8) = o;
    }
    float bsum = __fadd_rn(__fadd_rn(__fadd_rn(r[0], r[1]), __fadd_rn(r[2], r[3])),
                           __fadd_rn(__fadd_rn(r[4], r[5]), __fadd_rn(r[6], r[7])));
    float other = __shfl_xor(bsum, 1);
    if (half == 0) norms[row] = __fadd_rn(bsum, other);
  }
}

// ---------------- kernel: numpy-pairwise row norms (fallback path only) -----

__global__ void k_norms_np(const float* __restrict__ m, int n,
                           float* __restrict__ out) {
  int i = blockIdx.x * blockDim.x + threadIdx.x;
  int stride = gridDim.x * blockDim.x;
  for (; i < n; i += stride) out[i] = np_sq256(m + (size_t)i * CDIM);
}

// ---------------- kernel: MFMA bf16 screen (register-pipelined) -------------
// 1D grid 832 blocks (13 label-groups x 64 chunk-slots, bijective XCD swizzle
// so the 13 blocks sharing a chunk land on one XCD's L2). Block = 4 waves;
// wave owns 16 labels (A-frags in registers) and streams its 1600-patch chunk
// in 16-patch groups with a 2-stage register double-buffer (bA/bB). Zero
// barriers and zero LDS traffic in the main loop; pnorm pre-staged to LDS
// (lgkmcnt-tracked -> no vmcnt interference). Keys approximate (bf16);
// selection finalized by exact np-f32 re-rank in k_merge_mfma.

__global__ __launch_bounds__(256, 3) void k_screen_mfma(
    const unsigned short* __restrict__ lblbf,
    const unsigned short* __restrict__ patchbf,
    const float* __restrict__ pnorm,
    float* __restrict__ part_s, int* __restrict__ part_i) {
  __shared__ float pn_lds[PBLK];          // 6.4 KB
  __shared__ float stv[64][16][SL];       // 20 KB
  __shared__ int   sti[64][16][SL];       // 20 KB
  const int tid = threadIdx.x;
  const int w = tid >> 6, l = tid & 63;
  const int col = l & 15, kg = l >> 4;
  // XCD swizzle: b = 8*(13*h + x) + r  <->  chunk = 8h + r, label-group = x.
  const int b = blockIdx.x;
  const int r8 = b & 7, q = b >> 3;
  const int x = q % 13, h = q / 13;
  const int chunk = h * 8 + r8;
  if (chunk >= NCH3) return;              // block-uniform
  const int lab0 = x * 64 + w * 16;
  const int p0 = chunk * PBLK;

  for (int e = tid; e < PBLK; e += 256) {
    int p = p0 + e;
    pn_lds[e] = (p < NPATCH) ? pnorm[p] : INFINITY;
  }

  bf16x8 a[8];
#pragma unroll
  for (int kk = 0; kk < 8; ++kk)
    a[kk] = *(const bf16x8*)&lblbf[(size_t)(lab0 + col) * CDIM + kk * 32 + kg * 8];

  float lv[4][SL]; int li[4][SL];
#pragma unroll
  for (int rr = 0; rr < 4; ++rr)
#pragma unroll
    for (int j = 0; j < SL; ++j) { lv[rr][j] = INFINITY; li[rr][j] = 0x7fffffff; }

  __syncthreads();  // pn_lds ready (only barrier before the end-merge)

#define LOADB(g, bb)                                                        \
  {                                                                         \
    int p_ = p0 + (g) * 16 + col;                                           \
    int pc_ = p_ < NPATCH ? p_ : NPATCH - 1;                                \
    const unsigned short* pr_ = patchbf + (size_t)pc_ * CDIM + kg * 8;      \
    _Pragma("unroll") for (int kk = 0; kk < 8; ++kk)                        \
        bb[kk] = *(const bf16x8*)&pr_[kk * 32];                             \
  }

#define COMPUTE(g, bb)                                                      \
  {                                                                         \
    f32x4 ac0 = {0.f, 0.f, 0.f, 0.f}, ac1 = {0.f, 0.f, 0.f, 0.f};          \
    _Pragma("unroll") for (int kk = 0; kk < 4; ++kk) {                      \
      ac0 = __builtin_amdgcn_mfma_f32_16x16x32_bf16(a[2 * kk], bb[2 * kk],  \
                                                    ac0, 0, 0, 0);          \
      ac1 = __builtin_amdgcn_mfma_f32_16x16x32_bf16(a[2 * kk + 1],          \
                                                    bb[2 * kk + 1], ac1,    \
                                                    0, 0, 0);               \
    }                                                                       \
    int p_ = p0 + (g) * 16 + col;                                           \
    bool ok_ = p_ < NPATCH;                                                 \
    float pn_ = pn_lds[(g) * 16 + col];                                     \
    int pi_ = ok_ ? p_ : 0x7fffffff;                                        \
    _Pragma("unroll") for (int rr = 0; rr < 4; ++rr) {                      \
      float key_ = ok_ ? fmaf(-2.f, ac0[rr] + ac1[rr], pn_) : INFINITY;     \
      tk_insert<SL>(lv[rr], li[rr], key_, pi_);                             \
    }                                                                       \
  }

  bf16x8 bA[8], bB[8];
  LOADB(0, bA);
  for (int g = 0; g < NGRP; g += 2) {
    LOADB(g + 1, bB);
    COMPUTE(g, bA);
    if (g + 2 < NGRP) LOADB(g + 2, bA);
    COMPUTE(g + 1, bB);
  }
#undef LOADB
#undef COMPUTE

  // block-end merge: 64 lists of SL per label -> per-(label,chunk) top-KPS
#pragma unroll
  for (int rr = 0; rr < 4; ++rr) {
    int s = w * 16 + kg * 4 + rr;
#pragma unroll
    for (int j = 0; j < SL; ++j) { stv[s][col][j] = lv[rr][j]; sti[s][col][j] = li[rr][j]; }
  }
  __syncthreads();
  if (tid < 64) {
    float v[KPS]; int ii[KPS];
#pragma unroll
    for (int j = 0; j < KPS; ++j) { v[j] = INFINITY; ii[j] = 0x7fffffff; }
    for (int src = 0; src < 16; ++src)
#pragma unroll
      for (int j = 0; j < SL; ++j)
        tk_insert<KPS>(v, ii, stv[tid][src][j], sti[tid][src][j]);
    size_t base = ((size_t)(x * 64 + tid) * NCH3 + chunk) * KPS;
#pragma unroll
    for (int j = 0; j < KPS; ++j) { part_s[base + j] = v[j]; part_i[base + j] = ii[j]; }
  }
}

// ---------------- kernel: merge + EXACT np-f32 re-rank + max-agg ------------
// tournament depths (12,16,32) all >= 9: a true top-9 entry has <= 8 smaller
// entries globally, so it can never be dropped at any stage.

__global__ void k_merge_mfma(const float* __restrict__ part_s,
                             const int* __restrict__ part_i,
                             const float* __restrict__ patch,
                             const float* __restrict__ lbl,
                             const float* __restrict__ pnorm,
                             const float* __restrict__ lnorm,
                             float* __restrict__ ctx) {
  const int lab = blockIdx.x;
  const int tid = threadIdx.x;
  __shared__ float lsh[CDIM];
  __shared__ float sv[64 * 12];
  __shared__ int   si[64 * 12];
  __shared__ float mv[8][16];
  __shared__ int   mi[8][16];
  __shared__ int   cand[NCAND];
  __shared__ float ckey[NCAND];
  __shared__ int   nb[KTOP];

  lsh[tid] = lbl[(size_t)lab * CDIM + tid];
  const int total = NCH3 * KPS;  // 1008
  if (tid < 64) {
    float v[12]; int ii[12];
#pragma unroll
    for (int j = 0; j < 12; ++j) { v[j] = INFINITY; ii[j] = 0x7fffffff; }
    for (int e = tid; e < total; e += 64)
      tk_insert<12>(v, ii, part_s[(size_t)lab * total + e],
                    part_i[(size_t)lab * total + e]);
#pragma unroll
    for (int j = 0; j < 12; ++j) { sv[tid * 12 + j] = v[j]; si[tid * 12 + j] = ii[j]; }
  }
  __syncthreads();
  if (tid < 8) {
    float v[16]; int ii[16];
#pragma unroll
    for (int j = 0; j < 16; ++j) { v[j] = INFINITY; ii[j] = 0x7fffffff; }
    for (int e = 0; e < 8 * 12; ++e)
      tk_insert<16>(v, ii, sv[tid * 96 + e], si[tid * 96 + e]);
#pragma unroll
    for (int j = 0; j < 16; ++j) { mv[tid][j] = v[j]; mi[tid][j] = ii[j]; }
  }
  __syncthreads();
  if (tid == 0) {
    float v[NCAND]; int ii[NCAND];
#pragma unroll
    for (int j = 0; j < NCAND; ++j) { v[j] = INFINITY; ii[j] = 0x7fffffff; }
    for (int e = 0; e < 128; ++e)
      tk_insert<NCAND>(v, ii, mv[e >> 4][e & 15], mi[e >> 4][e & 15]);
#pragma unroll
    for (int j = 0; j < NCAND; ++j) cand[j] = ii[j];
  }
  __syncthreads();
  // exact np-f32 key per candidate (sequential fmaf chain, BLAS order)
  if (tid < NCAND) {
    int c = cand[tid];
    float key = INFINITY;
    if (c != 0x7fffffff) {
      const float* prow = &patch[(size_t)c * CDIM];
      float dot = 0.f;
      for (int k = 0; k < CDIM; ++k) dot = fmaf(lsh[k], prow[k], dot);
      key = np_key(lnorm[lab], dot, pnorm[c]);
    }
    ckey[tid] = key;
  }
  __syncthreads();
  if (tid == 0) {
    unsigned long long used = 0;
    for (int t = 0; t < KTOP; ++t) {
      float best = INFINITY; int bj = 0, bidx = 0x7fffffff;
      for (int j = 0; j < NCAND; ++j) {
        if (used & (1ull << j)) continue;
        if (ckey[j] < best || (ckey[j] == best && cand[j] < bidx)) {
          best = ckey[j]; bj = j; bidx = cand[j];
        }
      }
      used |= (1ull << bj);
      nb[t] = cand[bj];
    }
  }
  __syncthreads();
  float mx = -INFINITY;
#pragma unroll
  for (int j = 0; j < KTOP; ++j)
    mx = fmaxf(mx, patch[(size_t)nb[j] * CDIM + tid]);
  ctx[(size_t)lab * CDIM + tid] = mx - lsh[tid];
}

// ---------------- FALLBACK: R4 f32 screen + merge (known-green) -------------

__global__ void k_screen_f32(const float* __restrict__ lbl,
                             const float* __restrict__ patch,
                             const float* __restrict__ pnorm,
                             const float* __restrict__ lnorm,
                             float* __restrict__ part_s,
                             int* __restrict__ part_i) {
  __shared__ float Asm[KC][BLK];
  __shared__ float Bsm[KC][BLK];
  __shared__ float sc[BLK][BLK + 1];
  const int tid = threadIdx.x;
  const int tr = tid >> 4, tc = tid & 15;
  const int lbase = blockIdx.y * BLK;
  const int chunk = blockIdx.x;
  const int p0 = chunk * CHUNK;
  const int p1 = (p0 + CHUNK < NPATCH) ? p0 + CHUNK : NPATCH;

  float tv[KP]; int ti[KP];
#pragma unroll
  for (int j = 0; j < KP; ++j) { tv[j] = INFINITY; ti[j] = 0x7fffffff; }
  const float ln = (tid < BLK) ? lnorm[lbase + tid] : 0.f;

  const int sl = tid >> 2;
  const int skq = (tid & 3) * 4;

  for (int pt = p0; pt < p1; pt += BLK) {
    float acc[4][4];
#pragma unroll
    for (int a = 0; a < 4; ++a)
#pragma unroll
      for (int b = 0; b < 4; ++b) acc[a][b] = 0.f;

    for (int kc = 0; kc < CDIM; kc += KC) {
      __syncthreads();
      {
        const float* arow = &lbl[(size_t)(lbase + sl) * CDIM + kc];
        float4 va0 = *(const float4*)(arow + skq);
        float4 va1 = *(const float4*)(arow + 16 + skq);
        Asm[skq + 0][sl] = va0.x; Asm[skq + 1][sl] = va0.y;
        Asm[skq + 2][sl] = va0.z; Asm[skq + 3][sl] = va0.w;
        Asm[16 + skq + 0][sl] = va1.x; Asm[16 + skq + 1][sl] = va1.y;
        Asm[16 + skq + 2][sl] = va1.z; Asm[16 + skq + 3][sl] = va1.w;
        int p = pt + sl;
        float4 vb0 = make_float4(0.f, 0.f, 0.f, 0.f), vb1 = vb0;
        if (p < p1) {
          const float* brow = &patch[(size_t)p * CDIM + kc];
          vb0 = *(const float4*)(brow + skq);
          vb1 = *(const float4*)(brow + 16 + skq);
        }
        Bsm[skq + 0][sl] = vb0.x; Bsm[skq + 1][sl] = vb0.y;
        Bsm[skq + 2][sl] = vb0.z; Bsm[skq + 3][sl] = vb0.w;
        Bsm[16 + skq + 0][sl] = vb1.x; Bsm[16 + skq + 1][sl] = vb1.y;
        Bsm[16 + skq + 2][sl] = vb1.z; Bsm[16 + skq + 3][sl] = vb1.w;
      }
      __syncthreads();
#pragma unroll
      for (int k = 0; k < KC; ++k) {
        float4 a4 = *(const float4*)&Asm[k][tr * 4];
        float4 b4 = *(const float4*)&Bsm[k][tc * 4];
        const float av[4] = {a4.x, a4.y, a4.z, a4.w};
        const float bv[4] = {b4.x, b4.y, b4.z, b4.w};
#pragma unroll
        for (int a = 0; a < 4; ++a)
#pragma unroll
          for (int b = 0; b < 4; ++b) acc[a][b] = fmaf(av[a], bv[b], acc[a][b]);
      }
    }
#pragma unroll
    for (int a = 0; a < 4; ++a)
#pragma unroll
      for (int b = 0; b < 4; ++b) sc[tr * 4 + a][tc * 4 + b] = acc[a][b];
    __syncthreads();
    if (tid < BLK) {
      for (int c = 0; c < BLK; ++c) {
        int p = pt + c;
        if (p < p1) tk_insert<KP>(tv, ti, np_key(ln, sc[tid][c], pnorm[p]), p);
      }
    }
  }

  if (tid < BLK) {
    int lab = lbase + tid;
    size_t base = ((size_t)lab * NCHUNK + chunk) * KP;
#pragma unroll
    for (int j = 0; j < KP; ++j) { part_s[base + j] = tv[j]; part_i[base + j] = ti[j]; }
  }
}

__global__ void k_merge_f32(const float* __restrict__ part_s,
                            const int* __restrict__ part_i,
                            const float* __restrict__ patch,
                            const float* __restrict__ lbl,
                            float* __restrict__ ctx) {
  const int lab = blockIdx.x;
  const int tid = threadIdx.x;
  __shared__ float cv[16][KP];
  __shared__ int ci[16][KP];
  __shared__ int nb[KTOP];

  const int total = NCHUNK * KP;
  if (tid < 16) {
    float v[KP]; int ii[KP];
#pragma unroll
    for (int j = 0; j < KP; ++j) { v[j] = INFINITY; ii[j] = 0x7fffffff; }
    for (int e = tid; e < total; e += 16)
      tk_insert<KP>(v, ii, part_s[(size_t)lab * total + e],
                    part_i[(size_t)lab * total + e]);
#pragma unroll
    for (int j = 0; j < KP; ++j) { cv[tid][j] = v[j]; ci[tid][j] = ii[j]; }
  }
  __syncthreads();
  if (tid == 0) {
    float v[KP]; int ii[KP];
#pragma unroll
    for (int j = 0; j < KP; ++j) { v[j] = INFINITY; ii[j] = 0x7fffffff; }
    for (int t = 0; t < 16; ++t)
      for (int j = 0; j < KP; ++j) tk_insert<KP>(v, ii, cv[t][j], ci[t][j]);
#pragma unroll
    for (int j = 0; j < KTOP; ++j) nb[j] = ii[j];
  }
  __syncthreads();
  float l = lbl[(size_t)lab * CDIM + tid];
  float mx = -INFINITY;
#pragma unroll
  for (int j = 0; j < KTOP; ++j)
    mx = fmaxf(mx, patch[(size_t)nb[j] * CDIM + tid]);
  ctx[(size_t)lab * CDIM + tid] = mx - l;
}

// ---------------- kernel: small label->label agg (np-f32 semantics) ---------

__global__ void k_small_agg(const float* __restrict__ lbl_rows,
                            const float* __restrict__ tgt, int M, int k,
                            float* __restrict__ ctx) {
  const int row = blockIdx.x;
  const int tid = threadIdx.x;
  __shared__ float lsh[CDIM];
  __shared__ float skey[256];
  __shared__ float lns;
  __shared__ int nb[4];
  lsh[tid] = lbl_rows[(size_t)row * CDIM + tid];
  __syncthreads();
  if (tid == 0) lns = np_sq256(lsh);
  __syncthreads();
  float key = INFINITY;
  if (tid < M) {
    const float* trow = &tgt[(size_t)tid * CDIM];
    float tn = np_sq256(trow);
    float dot = 0.f;
    for (int c = 0; c < CDIM; ++c) dot = fmaf(lsh[c], trow[c], dot);
    key = np_key(lns, dot, tn);
  }
  skey[tid] = key;
  __syncthreads();
  if (tid == 0) {
    for (int t = 0; t < k; ++t) {
      float best = INFINITY; int bi = 0;
      for (int j = 0; j < M; ++j)
        if (skey[j] < best) { best = skey[j]; bi = j; }
      nb[t] = bi; skey[bi] = INFINITY;
    }
  }
  __syncthreads();
  float mx = -INFINITY;
  for (int t = 0; t < k; ++t) mx = fmaxf(mx, tgt[(size_t)nb[t] * CDIM + tid]);
  ctx[(size_t)row * CDIM + tid] = mx - lsh[tid];
}

// ---------------- kernel: linear(concat) + residual + LayerNorm (f64) -------

__device__ __forceinline__ double block_sum_256d(double x, double* red) {
#pragma unroll
  for (int m = 32; m >= 1; m >>= 1) x += __shfl_xor(x, m);
  int wid = threadIdx.x >> 6, lane = threadIdx.x & 63;
  if (lane == 0) red[wid] = x;
  __syncthreads();
  double s = red[0] + red[1] + red[2] + red[3];
  __syncthreads();
  return s;
}

__global__ void k_level_out(const float* __restrict__ emb,
                            const float* __restrict__ c1,
                            const float* __restrict__ c2,
                            const float* __restrict__ c3, int nseg,
                            const float* __restrict__ W,
                            const float* __restrict__ bias,
                            const float* __restrict__ gamma,
                            const float* __restrict__ beta,
                            float* __restrict__ out) {
  __shared__ float xs[4 * CDIM];
  __shared__ double red[4];
  const int row = blockIdx.x, ch = threadIdx.x;
  float e = emb[(size_t)row * CDIM + ch];
  xs[ch] = e;
  if (nseg > 1) xs[CDIM + ch] = c1[(size_t)row * CDIM + ch];
  if (nseg > 2) xs[2 * CDIM + ch] = c2[(size_t)row * CDIM + ch];
  if (nseg > 3) xs[3 * CDIM + ch] = c3[(size_t)row * CDIM + ch];
  __syncthreads();
  const int F = nseg * CDIM;
  double y = (double)e + (double)bias[ch];
#pragma unroll 4
  for (int j = 0; j < F; ++j)
    y += (double)xs[j] * (double)W[(size_t)j * CDIM + ch];
  double mu = block_sum_256d(y, red) * (1.0 / 256.0);
  double d = y - mu;
  double var = block_sum_256d(d * d, red) * (1.0 / 256.0);
  out[(size_t)row * CDIM + ch] =
      (float)(d / sqrt(var + 1e-5) * (double)gamma[ch] + (double)beta[ch]);
}

// ---------------- launch ----------------------------------------------------

static void launch_tail(const float* mood_emb, const float* genre_emb,
                        const float* sub_emb, const float* Wm_w, const float* Wm_b,
                        const float* Wg_w, const float* Wg_b, const float* Ws_w,
                        const float* Ws_b, const float* lnm_g, const float* lnm_b,
                        const float* lng_g, const float* lng_b, const float* lns_g,
                        const float* lns_b, const float* ctx_all, float* ctx_gm,
                        float* ctx_sm, float* ctx_sg, float* out,
                        hipStream_t stream) {
  k_level_out<<<NMOOD, 256, 0, stream>>>(mood_emb, ctx_all, nullptr, nullptr, 2,
                                         Wm_w, Wm_b, lnm_g, lnm_b, out);
  k_small_agg<<<NGENRE, 256, 0, stream>>>(genre_emb, out, NMOOD, 4, ctx_gm);
  k_level_out<<<NGENRE, 256, 0, stream>>>(genre_emb, ctx_all + NMOOD * CDIM, ctx_gm,
                                          nullptr, 3, Wg_w, Wg_b, lng_g, lng_b,
                                          out + NMOOD * CDIM);
  k_small_agg<<<NSUB, 256, 0, stream>>>(sub_emb, out, NMOOD, 3, ctx_sm);
  k_small_agg<<<NSUB, 256, 0, stream>>>(sub_emb, out + NMOOD * CDIM, NGENRE, 4, ctx_sg);
  k_level_out<<<NSUB, 256, 0, stream>>>(sub_emb, ctx_all + (NMOOD + NGENRE) * CDIM,
                                        ctx_sm, ctx_sg, 4, Ws_w, Ws_b, lns_g, lns_b,
                                        out + NMOOD * CDIM + NGENRE * CDIM);
}

extern "C" void kernel_launch(void* const* d_in, const int* in_sizes, int n_in,
                              void* d_out, int out_size, void* d_ws, size_t ws_size,
                              hipStream_t stream) {
  const float* patch     = (const float*)d_in[0];
  const float* mood_emb  = (const float*)d_in[1];
  const float* genre_emb = (const float*)d_in[2];
  const float* sub_emb   = (const float*)d_in[3];
  const float* Wm_w = (const float*)d_in[4];
  const float* Wm_b = (const float*)d_in[5];
  const float* Wg_w = (const float*)d_in[6];
  const float* Wg_b = (const float*)d_in[7];
  const float* Ws_w = (const float*)d_in[8];
  const float* Ws_b = (const float*)d_in[9];
  const float* lnm_g = (const float*)d_in[10];
  const float* lnm_b = (const float*)d_in[11];
  const float* lng_g = (const float*)d_in[12];
  const float* lng_b = (const float*)d_in[13];
  const float* lns_g = (const float*)d_in[14];
  const float* lns_b = (const float*)d_in[15];
  float* out = (float*)d_out;
  float* ws = (float*)d_ws;

  const size_t REQ = 15438848ull * 4ull;  // ~61.8 MB

  if (ws_size >= REQ) {
    // ---- MFMA path layout ----
    float* lbl     = ws;                     // 212992
    float* pnorm   = lbl + NLBL * CDIM;      // 100352
    float* lnorm   = pnorm + 100352;         // 1024
    float* ctx_all = lnorm + 1024;           // 212992
    float* ctx_gm  = ctx_all + NLBL * CDIM;  // 65536
    float* ctx_sm  = ctx_gm + NGENRE * CDIM; // 131072
    float* ctx_sg  = ctx_sm + NSUB * CDIM;   // 131072
    float* part_s  = ctx_sg + NSUB * CDIM;   // 832*63*16 = 838656
    int*   part_i  = (int*)(part_s + (size_t)NLBL * NCH3 * KPS);
    unsigned short* patchbf = (unsigned short*)(part_i + (size_t)NLBL * NCH3 * KPS);
    unsigned short* lblbf   = patchbf + (size_t)NPATCH * CDIM;

    k_concat_labels<<<NLBL, 256, 0, stream>>>(mood_emb, genre_emb, sub_emb, lbl);
    k_prep<<<782, 256, 0, stream>>>(patch, NPATCH, patchbf, pnorm);
    k_prep<<<7, 256, 0, stream>>>(lbl, NLBL, lblbf, lnorm);
    k_screen_mfma<<<832, 256, 0, stream>>>(lblbf, patchbf, pnorm, part_s, part_i);
    k_merge_mfma<<<NLBL, 256, 0, stream>>>(part_s, part_i, patch, lbl, pnorm,
                                           lnorm, ctx_all);
    launch_tail(mood_emb, genre_emb, sub_emb, Wm_w, Wm_b, Wg_w, Wg_b, Ws_w, Ws_b,
                lnm_g, lnm_b, lng_g, lng_b, lns_g, lns_b, ctx_all, ctx_gm, ctx_sm,
                ctx_sg, out, stream);
  } else {
    // ---- R4 fallback layout (known to fit) ----
    float* lbl    = ws;
    float* pnorm  = lbl + NLBL * CDIM;
    float* lnorm  = pnorm + 100352;
    float* part_s = lnorm + 1024;
    int*   part_i = (int*)(part_s + NLBL * NCHUNK * KP);
    float* ctx_all = part_s + 2 * NLBL * NCHUNK * KP;
    float* ctx_gm  = ctx_all + NLBL * CDIM;
    float* ctx_sm  = ctx_gm + NGENRE * CDIM;
    float* ctx_sg  = ctx_sm + NSUB * CDIM;

    k_concat_labels<<<NLBL, 256, 0, stream>>>(mood_emb, genre_emb, sub_emb, lbl);
    k_norms_np<<<512, 256, 0, stream>>>(patch, NPATCH, pnorm);
    k_norms_np<<<4, 256, 0, stream>>>(lbl, NLBL, lnorm);
    dim3 gscr(NCHUNK, NLBL / BLK);
    k_screen_f32<<<gscr, 256, 0, stream>>>(lbl, patch, pnorm, lnorm, part_s, part_i);
    k_merge_f32<<<NLBL, 256, 0, stream>>>(part_s, part_i, patch, lbl, ctx_all);
    launch_tail(mood_emb, genre_emb, sub_emb, Wm_w, Wm_b, Wg_w, Wg_b, Ws_w, Ws_b,
                lnm_g, lnm_b, lng_g, lng_b, lns_g, lns_b, ctx_all, ctx_gm, ctx_sm,
                ctx_sg, out, stream);
  }
}

// Round 8
// 1707.672 us; speedup vs baseline: 1.3275x; 1.3275x over previous
//
#include <hip/hip_runtime.h>
#include <math.h>

#define NPATCH 100000
#define CDIM   256
#define NMOOD  64
#define NGENRE 256
#define NSUB   512
#define NLBL   832          // 64+256+512
#define KTOP   9

// ---- f32 fallback screen constants (R4, known-green) ----
#define NCHUNK 39
#define CHUNK  2624
#define BLK    64
#define KC     32
#define KP     12

// ---- MFMA screen constants ----
#define PBLK   1600         // patches per chunk
#define NCH3   63           // 63*1600 = 100800 >= 100000
#define NGRP   100          // PBLK/16
#define KPS    16           // per-(label,chunk) partial size
#define SL     6            // per-lane list depth (single list per lane)
#define NCAND  32           // exact re-rank candidate count

typedef __attribute__((ext_vector_type(8))) short bf16x8;
typedef __attribute__((ext_vector_type(8))) unsigned short u16x8;
typedef __attribute__((ext_vector_type(4))) float f32x4;

// ---------------- serial top-k insert (ascending by (val,idx)) --------------

template <int K>
__device__ __forceinline__ void tk_insert(float (&v)[K], int (&ii)[K],
                                          float s, int idx) {
  if (s < v[K - 1] || (s == v[K - 1] && idx < ii[K - 1])) {
    v[K - 1] = s; ii[K - 1] = idx;
#pragma unroll
    for (int t = K - 1; t > 0; --t) {
      bool sw = (v[t] < v[t - 1]) || (v[t] == v[t - 1] && ii[t] < ii[t - 1]);
      if (sw) {
        float fv = v[t]; v[t] = v[t - 1]; v[t - 1] = fv;
        int fi = ii[t]; ii[t] = ii[t - 1]; ii[t - 1] = fi;
      }
    }
  }
}

// ------ numpy-pairwise sum of squares over 256 contiguous floats ------------

__device__ float np_sq256(const float* a) {
  float b0, b1;
  {
    float r[8];
#pragma unroll
    for (int i = 0; i < 8; ++i) { float x = a[i]; r[i] = __fmul_rn(x, x); }
    for (int j = 8; j < 128; j += 8)
#pragma unroll
      for (int i = 0; i < 8; ++i) {
        float x = a[j + i];
        r[i] = __fadd_rn(r[i], __fmul_rn(x, x));
      }
    b0 = __fadd_rn(__fadd_rn(__fadd_rn(r[0], r[1]), __fadd_rn(r[2], r[3])),
                   __fadd_rn(__fadd_rn(r[4], r[5]), __fadd_rn(r[6], r[7])));
  }
  {
    float r[8];
#pragma unroll
    for (int i = 0; i < 8; ++i) { float x = a[128 + i]; r[i] = __fmul_rn(x, x); }
    for (int j = 8; j < 128; j += 8)
#pragma unroll
      for (int i = 0; i < 8; ++i) {
        float x = a[128 + j + i];
        r[i] = __fadd_rn(r[i], __fmul_rn(x, x));
      }
    b1 = __fadd_rn(__fadd_rn(__fadd_rn(r[0], r[1]), __fadd_rn(r[2], r[3])),
                   __fadd_rn(__fadd_rn(r[4], r[5]), __fadd_rn(r[6], r[7])));
  }
  return __fadd_rn(b0, b1);
}

__device__ __forceinline__ float np_key(float ln, float dot, float pn) {
  return __fadd_rn(__fsub_rn(ln, __fmul_rn(2.f, dot)), pn);
}

// ---------------- kernel: concat labels into one (832,256) matrix -----------

__global__ void k_concat_labels(const float* __restrict__ mood,
                                const float* __restrict__ genre,
                                const float* __restrict__ sub,
                                float* __restrict__ lbl) {
  int i = blockIdx.x * 256 + threadIdx.x;
  if (i < NMOOD * CDIM) lbl[i] = mood[i];
  else if (i < (NMOOD + NGENRE) * CDIM) lbl[i] = genre[i - NMOOD * CDIM];
  else lbl[i] = sub[i - (NMOOD + NGENRE) * CDIM];
}

// ---------------- fused bf16-convert + np-exact norms (coalesced) -----------
// Wave handles 4 rows/iter: coalesced float4 stage -> LDS (bank-skewed rows)
// + bf16 stores from registers; norm pass = 8-class strided accumulators in
// exact np order + shfl combine tree (commutative swaps only; proven green
// pattern from k_norms_wave R5-R7).

__device__ __forceinline__ unsigned short f2bf(float x) {
  unsigned u = __float_as_uint(x);
  return (unsigned short)((u + 0x7fffu + ((u >> 16) & 1u)) >> 16);
}

__global__ __launch_bounds__(256) void k_prep2(const float* __restrict__ src,
                                               int n,
                                               unsigned short* __restrict__ dst,
                                               float* __restrict__ norms) {
  __shared__ float lds[4][4][260];   // [wave][row][pos] (+4 pad -> bank skew)
  const int tid = threadIdx.x;
  const int w = tid >> 6, l = tid & 63;
  const int rr = l >> 4;            // row within wave quad
  const int h = (l >> 3) & 1;       // 128-half
  const int i = l & 7;              // np accumulator class
  for (int base = blockIdx.x * 16; base < n; base += gridDim.x * 16) {
    int row = base + w * 4;
    __syncthreads();                 // protect lds reuse across iterations
#pragma unroll
    for (int q = 0; q < 4; ++q) {
      int r = row + q;
      if (r < n) {
        float4 v = *(const float4*)&src[(size_t)r * CDIM + l * 4];
        ushort4 o = make_ushort4(f2bf(v.x), f2bf(v.y), f2bf(v.z), f2bf(v.w));
        *(ushort4*)&dst[(size_t)r * CDIM + l * 4] = o;
        lds[w][q][l * 4 + 0] = v.x; lds[w][q][l * 4 + 1] = v.y;
        lds[w][q][l * 4 + 2] = v.z; lds[w][q][l * 4 + 3] = v.w;
      }
    }
    __syncthreads();
    int r = row + rr;
    if (r < n) {
      const float* a = &lds[w][rr][h * 128];
      float x = a[i];
      float acc = __fmul_rn(x, x);
#pragma unroll
      for (int j = 1; j < 16; ++j) {
        float y = a[j * 8 + i];
        acc = __fadd_rn(acc, __fmul_rn(y, y));
      }
      float t = __fadd_rn(acc, __shfl_xor(acc, 1));
      t = __fadd_rn(t, __shfl_xor(t, 2));
      t = __fadd_rn(t, __shfl_xor(t, 4));
      float o = __shfl_xor(t, 8);
      if (h == 0 && i == 0) norms[r] = __fadd_rn(t, o);
    }
  }
}

// ---------------- kernel: numpy-pairwise row norms (fallback path only) -----

__global__ void k_norms_np(const float* __restrict__ m, int n,
                           float* __restrict__ out) {
  int i = blockIdx.x * blockDim.x + threadIdx.x;
  int stride = gridDim.x * blockDim.x;
  for (; i < n; i += stride) out[i] = np_sq256(m + (size_t)i * CDIM);
}

// ---------------- kernel: MFMA bf16 screen (register-pipelined) -------------
// 1D grid 832 blocks (13 label-groups x 64 chunk-slots, XCD swizzle so the 13
// blocks sharing a chunk land on one XCD's L2). Block = 4 waves; wave owns 16
// labels. Operand order mfma(B_patch, A_label): output col = LABEL (lane&15),
// rows = 4 patches -> ONE top-list per lane (12 regs vs 40). 2-stage register
// double-buffer, zero barriers/LDS in the main loop, pnorm pre-staged to LDS.
// Plain launch_bounds: NO occupancy demand -> no spill (R7 lesson: (256,3)
// forced VGPR=84 and 2.3 GB scratch writes). Keys approximate (bf16);
// selection finalized by exact np-f32 re-rank in k_merge_mfma.

__global__ __launch_bounds__(256) void k_screen_mfma(
    const unsigned short* __restrict__ lblbf,
    const unsigned short* __restrict__ patchbf,
    const float* __restrict__ pnorm,
    float* __restrict__ part_s, int* __restrict__ part_i) {
  __shared__ float pn_lds[PBLK];          // 6.4 KB
  __shared__ float stv[64][4][SL];        // 6 KB
  __shared__ int   sti[64][4][SL];        // 6 KB
  const int tid = threadIdx.x;
  const int w = tid >> 6, l = tid & 63;
  const int col = l & 15, kg = l >> 4;
  // XCD swizzle: b = 8*(13*h + x) + r  <->  chunk = 8h + r, label-group = x.
  const int b = blockIdx.x;
  const int r8 = b & 7, q = b >> 3;
  const int x = q % 13, h = q / 13;
  const int chunk = h * 8 + r8;
  if (chunk >= NCH3) return;              // block-uniform
  const int lab0 = x * 64 + w * 16;
  const int p0 = chunk * PBLK;

  for (int e = tid; e < PBLK; e += 256) {
    int p = p0 + e;
    pn_lds[e] = (p < NPATCH) ? pnorm[p] : INFINITY;
  }

  bf16x8 a[8];
#pragma unroll
  for (int kk = 0; kk < 8; ++kk)
    a[kk] = *(const bf16x8*)&lblbf[(size_t)(lab0 + col) * CDIM + kk * 32 + kg * 8];

  float lv[SL]; int li[SL];
#pragma unroll
  for (int j = 0; j < SL; ++j) { lv[j] = INFINITY; li[j] = 0x7fffffff; }

  __syncthreads();  // pn_lds ready (only barrier before the end-merge)

#define LOADB(g, bb)                                                        \
  {                                                                         \
    int p_ = p0 + (g) * 16 + col;                                           \
    int pc_ = p_ < NPATCH ? p_ : NPATCH - 1;                                \
    const unsigned short* pr_ = patchbf + (size_t)pc_ * CDIM + kg * 8;      \
    _Pragma("unroll") for (int kk = 0; kk < 8; ++kk)                        \
        bb[kk] = *(const bf16x8*)&pr_[kk * 32];                             \
  }

  // D[row=patch (kg*4+r)][col=label (lane&15)]
#define COMPUTE(g, bb)                                                      \
  {                                                                         \
    f32x4 ac0 = {0.f, 0.f, 0.f, 0.f}, ac1 = {0.f, 0.f, 0.f, 0.f};          \
    _Pragma("unroll") for (int kk = 0; kk < 4; ++kk) {                      \
      ac0 = __builtin_amdgcn_mfma_f32_16x16x32_bf16(bb[2 * kk], a[2 * kk],  \
                                                    ac0, 0, 0, 0);          \
      ac1 = __builtin_amdgcn_mfma_f32_16x16x32_bf16(bb[2 * kk + 1],         \
                                                    a[2 * kk + 1], ac1,     \
                                                    0, 0, 0);               \
    }                                                                       \
    _Pragma("unroll") for (int rr = 0; rr < 4; ++rr) {                      \
      int p_ = p0 + (g) * 16 + kg * 4 + rr;                                 \
      bool ok_ = p_ < NPATCH;                                               \
      float pn_ = pn_lds[(g) * 16 + kg * 4 + rr];                           \
      float key_ = ok_ ? fmaf(-2.f, ac0[rr] + ac1[rr], pn_) : INFINITY;     \
      tk_insert<SL>(lv, li, key_, ok_ ? p_ : 0x7fffffff);                   \
    }                                                                       \
  }

  bf16x8 bA[8], bB[8];
  LOADB(0, bA);
  for (int g = 0; g < NGRP; g += 2) {
    LOADB(g + 1, bB);
    COMPUTE(g, bA);
    if (g + 2 < NGRP) LOADB(g + 2, bA);
    COMPUTE(g + 1, bB);
  }
#undef LOADB
#undef COMPUTE

  // block-end merge: 4 lists of SL per label -> per-(label,chunk) top-KPS
  {
    int s = w * 16 + col;
#pragma unroll
    for (int j = 0; j < SL; ++j) { stv[s][kg][j] = lv[j]; sti[s][kg][j] = li[j]; }
  }
  __syncthreads();
  if (tid < 64) {
    float v[KPS]; int ii[KPS];
#pragma unroll
    for (int j = 0; j < KPS; ++j) { v[j] = INFINITY; ii[j] = 0x7fffffff; }
    for (int src = 0; src < 4; ++src)
#pragma unroll
      for (int j = 0; j < SL; ++j)
        tk_insert<KPS>(v, ii, stv[tid][src][j], sti[tid][src][j]);
    size_t base = ((size_t)(x * 64 + tid) * NCH3 + chunk) * KPS;
#pragma unroll
    for (int j = 0; j < KPS; ++j) { part_s[base + j] = v[j]; part_i[base + j] = ii[j]; }
  }
}

// ---------------- kernel: merge + EXACT np-f32 re-rank + max-agg ------------
// tournament depths (12,16,32) all >= 9: a true top-9 entry has <= 8 smaller
// entries globally, so it can never be dropped at any stage.

__global__ void k_merge_mfma(const float* __restrict__ part_s,
                             const int* __restrict__ part_i,
                             const float* __restrict__ patch,
                             const float* __restrict__ lbl,
                             const float* __restrict__ pnorm,
                             const float* __restrict__ lnorm,
                             float* __restrict__ ctx) {
  const int lab = blockIdx.x;
  const int tid = threadIdx.x;
  __shared__ float lsh[CDIM];
  __shared__ float sv[64 * 12];
  __shared__ int   si[64 * 12];
  __shared__ float mv[8][16];
  __shared__ int   mi[8][16];
  __shared__ int   cand[NCAND];
  __shared__ float ckey[NCAND];
  __shared__ int   nb[KTOP];

  lsh[tid] = lbl[(size_t)lab * CDIM + tid];
  const int total = NCH3 * KPS;  // 1008
  if (tid < 64) {
    float v[12]; int ii[12];
#pragma unroll
    for (int j = 0; j < 12; ++j) { v[j] = INFINITY; ii[j] = 0x7fffffff; }
    for (int e = tid; e < total; e += 64)
      tk_insert<12>(v, ii, part_s[(size_t)lab * total + e],
                    part_i[(size_t)lab * total + e]);
#pragma unroll
    for (int j = 0; j < 12; ++j) { sv[tid * 12 + j] = v[j]; si[tid * 12 + j] = ii[j]; }
  }
  __syncthreads();
  if (tid < 8) {
    float v[16]; int ii[16];
#pragma unroll
    for (int j = 0; j < 16; ++j) { v[j] = INFINITY; ii[j] = 0x7fffffff; }
    for (int e = 0; e < 8 * 12; ++e)
      tk_insert<16>(v, ii, sv[tid * 96 + e], si[tid * 96 + e]);
#pragma unroll
    for (int j = 0; j < 16; ++j) { mv[tid][j] = v[j]; mi[tid][j] = ii[j]; }
  }
  __syncthreads();
  if (tid == 0) {
    float v[NCAND]; int ii[NCAND];
#pragma unroll
    for (int j = 0; j < NCAND; ++j) { v[j] = INFINITY; ii[j] = 0x7fffffff; }
    for (int e = 0; e < 128; ++e)
      tk_insert<NCAND>(v, ii, mv[e >> 4][e & 15], mi[e >> 4][e & 15]);
#pragma unroll
    for (int j = 0; j < NCAND; ++j) cand[j] = ii[j];
  }
  __syncthreads();
  // exact np-f32 key per candidate (sequential fmaf chain, BLAS order)
  if (tid < NCAND) {
    int c = cand[tid];
    float key = INFINITY;
    if (c != 0x7fffffff) {
      const float* prow = &patch[(size_t)c * CDIM];
      float dot = 0.f;
      for (int k = 0; k < CDIM; ++k) dot = fmaf(lsh[k], prow[k], dot);
      key = np_key(lnorm[lab], dot, pnorm[c]);
    }
    ckey[tid] = key;
  }
  __syncthreads();
  if (tid == 0) {
    unsigned long long used = 0;
    for (int t = 0; t < KTOP; ++t) {
      float best = INFINITY; int bj = 0, bidx = 0x7fffffff;
      for (int j = 0; j < NCAND; ++j) {
        if (used & (1ull << j)) continue;
        if (ckey[j] < best || (ckey[j] == best && cand[j] < bidx)) {
          best = ckey[j]; bj = j; bidx = cand[j];
        }
      }
      used |= (1ull << bj);
      nb[t] = cand[bj];
    }
  }
  __syncthreads();
  float mx = -INFINITY;
#pragma unroll
  for (int j = 0; j < KTOP; ++j)
    mx = fmaxf(mx, patch[(size_t)nb[j] * CDIM + tid]);
  ctx[(size_t)lab * CDIM + tid] = mx - lsh[tid];
}

// ---------------- FALLBACK: R4 f32 screen + merge (known-green) -------------

__global__ void k_screen_f32(const float* __restrict__ lbl,
                             const float* __restrict__ patch,
                             const float* __restrict__ pnorm,
                             const float* __restrict__ lnorm,
                             float* __restrict__ part_s,
                             int* __restrict__ part_i) {
  __shared__ float Asm[KC][BLK];
  __shared__ float Bsm[KC][BLK];
  __shared__ float sc[BLK][BLK + 1];
  const int tid = threadIdx.x;
  const int tr = tid >> 4, tc = tid & 15;
  const int lbase = blockIdx.y * BLK;
  const int chunk = blockIdx.x;
  const int p0 = chunk * CHUNK;
  const int p1 = (p0 + CHUNK < NPATCH) ? p0 + CHUNK : NPATCH;

  float tv[KP]; int ti[KP];
#pragma unroll
  for (int j = 0; j < KP; ++j) { tv[j] = INFINITY; ti[j] = 0x7fffffff; }
  const float ln = (tid < BLK) ? lnorm[lbase + tid] : 0.f;

  const int sl = tid >> 2;
  const int skq = (tid & 3) * 4;

  for (int pt = p0; pt < p1; pt += BLK) {
    float acc[4][4];
#pragma unroll
    for (int a = 0; a < 4; ++a)
#pragma unroll
      for (int b = 0; b < 4; ++b) acc[a][b] = 0.f;

    for (int kc = 0; kc < CDIM; kc += KC) {
      __syncthreads();
      {
        const float* arow = &lbl[(size_t)(lbase + sl) * CDIM + kc];
        float4 va0 = *(const float4*)(arow + skq);
        float4 va1 = *(const float4*)(arow + 16 + skq);
        Asm[skq + 0][sl] = va0.x; Asm[skq + 1][sl] = va0.y;
        Asm[skq + 2][sl] = va0.z; Asm[skq + 3][sl] = va0.w;
        Asm[16 + skq + 0][sl] = va1.x; Asm[16 + skq + 1][sl] = va1.y;
        Asm[16 + skq + 2][sl] = va1.z; Asm[16 + skq + 3][sl] = va1.w;
        int p = pt + sl;
        float4 vb0 = make_float4(0.f, 0.f, 0.f, 0.f), vb1 = vb0;
        if (p < p1) {
          const float* brow = &patch[(size_t)p * CDIM + kc];
          vb0 = *(const float4*)(brow + skq);
          vb1 = *(const float4*)(brow + 16 + skq);
        }
        Bsm[skq + 0][sl] = vb0.x; Bsm[skq + 1][sl] = vb0.y;
        Bsm[skq + 2][sl] = vb0.z; Bsm[skq + 3][sl] = vb0.w;
        Bsm[16 + skq + 0][sl] = vb1.x; Bsm[16 + skq + 1][sl] = vb1.y;
        Bsm[16 + skq + 2][sl] = vb1.z; Bsm[16 + skq + 3][sl] = vb1.w;
      }
      __syncthreads();
#pragma unroll
      for (int k = 0; k < KC; ++k) {
        float4 a4 = *(const float4*)&Asm[k][tr * 4];
        float4 b4 = *(const float4*)&Bsm[k][tc * 4];
        const float av[4] = {a4.x, a4.y, a4.z, a4.w};
        const float bv[4] = {b4.x, b4.y, b4.z, b4.w};
#pragma unroll
        for (int a = 0; a < 4; ++a)
#pragma unroll
          for (int b = 0; b < 4; ++b) acc[a][b] = fmaf(av[a], bv[b], acc[a][b]);
      }
    }
#pragma unroll
    for (int a = 0; a < 4; ++a)
#pragma unroll
      for (int b = 0; b < 4; ++b) sc[tr * 4 + a][tc * 4 + b] = acc[a][b];
    __syncthreads();
    if (tid < BLK) {
      for (int c = 0; c < BLK; ++c) {
        int p = pt + c;
        if (p < p1) tk_insert<KP>(tv, ti, np_key(ln, sc[tid][c], pnorm[p]), p);
      }
    }
  }

  if (tid < BLK) {
    int lab = lbase + tid;
    size_t base = ((size_t)lab * NCHUNK + chunk) * KP;
#pragma unroll
    for (int j = 0; j < KP; ++j) { part_s[base + j] = tv[j]; part_i[base + j] = ti[j]; }
  }
}

__global__ void k_merge_f32(const float* __restrict__ part_s,
                            const int* __restrict__ part_i,
                            const float* __restrict__ patch,
                            const float* __restrict__ lbl,
                            float* __restrict__ ctx) {
  const int lab = blockIdx.x;
  const int tid = threadIdx.x;
  __shared__ float cv[16][KP];
  __shared__ int ci[16][KP];
  __shared__ int nb[KTOP];

  const int total = NCHUNK * KP;
  if (tid < 16) {
    float v[KP]; int ii[KP];
#pragma unroll
    for (int j = 0; j < KP; ++j) { v[j] = INFINITY; ii[j] = 0x7fffffff; }
    for (int e = tid; e < total; e += 16)
      tk_insert<KP>(v, ii, part_s[(size_t)lab * total + e],
                    part_i[(size_t)lab * total + e]);
#pragma unroll
    for (int j = 0; j < KP; ++j) { cv[tid][j] = v[j]; ci[tid][j] = ii[j]; }
  }
  __syncthreads();
  if (tid == 0) {
    float v[KP]; int ii[KP];
#pragma unroll
    for (int j = 0; j < KP; ++j) { v[j] = INFINITY; ii[j] = 0x7fffffff; }
    for (int t = 0; t < 16; ++t)
      for (int j = 0; j < KP; ++j) tk_insert<KP>(v, ii, cv[t][j], ci[t][j]);
#pragma unroll
    for (int j = 0; j < KTOP; ++j) nb[j] = ii[j];
  }
  __syncthreads();
  float l = lbl[(size_t)lab * CDIM + tid];
  float mx = -INFINITY;
#pragma unroll
  for (int j = 0; j < KTOP; ++j)
    mx = fmaxf(mx, patch[(size_t)nb[j] * CDIM + tid]);
  ctx[(size_t)lab * CDIM + tid] = mx - l;
}

// ---------------- kernel: small label->label agg (np-f32 semantics) ---------

__global__ void k_small_agg(const float* __restrict__ lbl_rows,
                            const float* __restrict__ tgt, int M, int k,
                            float* __restrict__ ctx) {
  const int row = blockIdx.x;
  const int tid = threadIdx.x;
  __shared__ float lsh[CDIM];
  __shared__ float skey[256];
  __shared__ float lns;
  __shared__ int nb[4];
  lsh[tid] = lbl_rows[(size_t)row * CDIM + tid];
  __syncthreads();
  if (tid == 0) lns = np_sq256(lsh);
  __syncthreads();
  float key = INFINITY;
  if (tid < M) {
    const float* trow = &tgt[(size_t)tid * CDIM];
    float tn = np_sq256(trow);
    float dot = 0.f;
    for (int c = 0; c < CDIM; ++c) dot = fmaf(lsh[c], trow[c], dot);
    key = np_key(lns, dot, tn);
  }
  skey[tid] = key;
  __syncthreads();
  if (tid == 0) {
    for (int t = 0; t < k; ++t) {
      float best = INFINITY; int bi = 0;
      for (int j = 0; j < M; ++j)
        if (skey[j] < best) { best = skey[j]; bi = j; }
      nb[t] = bi; skey[bi] = INFINITY;
    }
  }
  __syncthreads();
  float mx = -INFINITY;
  for (int t = 0; t < k; ++t) mx = fmaxf(mx, tgt[(size_t)nb[t] * CDIM + tid]);
  ctx[(size_t)row * CDIM + tid] = mx - lsh[tid];
}

// ---------------- kernel: linear(concat) + residual + LayerNorm (f64) -------

__device__ __forceinline__ double block_sum_256d(double x, double* red) {
#pragma unroll
  for (int m = 32; m >= 1; m >>= 1) x += __shfl_xor(x, m);
  int wid = threadIdx.x >> 6, lane = threadIdx.x & 63;
  if (lane == 0) red[wid] = x;
  __syncthreads();
  double s = red[0] + red[1] + red[2] + red[3];
  __syncthreads();
  return s;
}

__global__ void k_level_out(const float* __restrict__ emb,
                            const float* __restrict__ c1,
                            const float* __restrict__ c2,
                            const float* __restrict__ c3, int nseg,
                            const float* __restrict__ W,
                            const float* __restrict__ bias,
                            const float* __restrict__ gamma,
                            const float* __restrict__ beta,
                            float* __restrict__ out) {
  __shared__ float xs[4 * CDIM];
  __shared__ double red[4];
  const int row = blockIdx.x, ch = threadIdx.x;
  float e = emb[(size_t)row * CDIM + ch];
  xs[ch] = e;
  if (nseg > 1) xs[CDIM + ch] = c1[(size_t)row * CDIM + ch];
  if (nseg > 2) xs[2 * CDIM + ch] = c2[(size_t)row * CDIM + ch];
  if (nseg > 3) xs[3 * CDIM + ch] = c3[(size_t)row * CDIM + ch];
  __syncthreads();
  const int F = nseg * CDIM;
  double y = (double)e + (double)bias[ch];
#pragma unroll 4
  for (int j = 0; j < F; ++j)
    y += (double)xs[j] * (double)W[(size_t)j * CDIM + ch];
  double mu = block_sum_256d(y, red) * (1.0 / 256.0);
  double d = y - mu;
  double var = block_sum_256d(d * d, red) * (1.0 / 256.0);
  out[(size_t)row * CDIM + ch] =
      (float)(d / sqrt(var + 1e-5) * (double)gamma[ch] + (double)beta[ch]);
}

// ---------------- launch ----------------------------------------------------

static void launch_tail(const float* mood_emb, const float* genre_emb,
                        const float* sub_emb, const float* Wm_w, const float* Wm_b,
                        const float* Wg_w, const float* Wg_b, const float* Ws_w,
                        const float* Ws_b, const float* lnm_g, const float* lnm_b,
                        const float* lng_g, const float* lng_b, const float* lns_g,
                        const float* lns_b, const float* ctx_all, float* ctx_gm,
                        float* ctx_sm, float* ctx_sg, float* out,
                        hipStream_t stream) {
  k_level_out<<<NMOOD, 256, 0, stream>>>(mood_emb, ctx_all, nullptr, nullptr, 2,
                                         Wm_w, Wm_b, lnm_g, lnm_b, out);
  k_small_agg<<<NGENRE, 256, 0, stream>>>(genre_emb, out, NMOOD, 4, ctx_gm);
  k_level_out<<<NGENRE, 256, 0, stream>>>(genre_emb, ctx_all + NMOOD * CDIM, ctx_gm,
                                          nullptr, 3, Wg_w, Wg_b, lng_g, lng_b,
                                          out + NMOOD * CDIM);
  k_small_agg<<<NSUB, 256, 0, stream>>>(sub_emb, out, NMOOD, 3, ctx_sm);
  k_small_agg<<<NSUB, 256, 0, stream>>>(sub_emb, out + NMOOD * CDIM, NGENRE, 4, ctx_sg);
  k_level_out<<<NSUB, 256, 0, stream>>>(sub_emb, ctx_all + (NMOOD + NGENRE) * CDIM,
                                        ctx_sm, ctx_sg, 4, Ws_w, Ws_b, lns_g, lns_b,
                                        out + NMOOD * CDIM + NGENRE * CDIM);
}

extern "C" void kernel_launch(void* const* d_in, const int* in_sizes, int n_in,
                              void* d_out, int out_size, void* d_ws, size_t ws_size,
                              hipStream_t stream) {
  const float* patch     = (const float*)d_in[0];
  const float* mood_emb  = (const float*)d_in[1];
  const float* genre_emb = (const float*)d_in[2];
  const float* sub_emb   = (const float*)d_in[3];
  const float* Wm_w = (const float*)d_in[4];
  const float* Wm_b = (const float*)d_in[5];
  const float* Wg_w = (const float*)d_in[6];
  const float* Wg_b = (const float*)d_in[7];
  const float* Ws_w = (const float*)d_in[8];
  const float* Ws_b = (const float*)d_in[9];
  const float* lnm_g = (const float*)d_in[10];
  const float* lnm_b = (const float*)d_in[11];
  const float* lng_g = (const float*)d_in[12];
  const float* lng_b = (const float*)d_in[13];
  const float* lns_g = (const float*)d_in[14];
  const float* lns_b = (const float*)d_in[15];
  float* out = (float*)d_out;
  float* ws = (float*)d_ws;

  const size_t REQ = 15438848ull * 4ull;  // ~61.8 MB

  if (ws_size >= REQ) {
    // ---- MFMA path layout ----
    float* lbl     = ws;                     // 212992
    float* pnorm   = lbl + NLBL * CDIM;      // 100352
    float* lnorm   = pnorm + 100352;         // 1024
    float* ctx_all = lnorm + 1024;           // 212992
    float* ctx_gm  = ctx_all + NLBL * CDIM;  // 65536
    float* ctx_sm  = ctx_gm + NGENRE * CDIM; // 131072
    float* ctx_sg  = ctx_sm + NSUB * CDIM;   // 131072
    float* part_s  = ctx_sg + NSUB * CDIM;   // 832*63*16 = 838656
    int*   part_i  = (int*)(part_s + (size_t)NLBL * NCH3 * KPS);
    unsigned short* patchbf = (unsigned short*)(part_i + (size_t)NLBL * NCH3 * KPS);
    unsigned short* lblbf   = patchbf + (size_t)NPATCH * CDIM;

    k_concat_labels<<<NLBL, 256, 0, stream>>>(mood_emb, genre_emb, sub_emb, lbl);
    k_prep2<<<2048, 256, 0, stream>>>(patch, NPATCH, patchbf, pnorm);
    k_prep2<<<52, 256, 0, stream>>>(lbl, NLBL, lblbf, lnorm);
    k_screen_mfma<<<832, 256, 0, stream>>>(lblbf, patchbf, pnorm, part_s, part_i);
    k_merge_mfma<<<NLBL, 256, 0, stream>>>(part_s, part_i, patch, lbl, pnorm,
                                           lnorm, ctx_all);
    launch_tail(mood_emb, genre_emb, sub_emb, Wm_w, Wm_b, Wg_w, Wg_b, Ws_w, Ws_b,
                lnm_g, lnm_b, lng_g, lng_b, lns_g, lns_b, ctx_all, ctx_gm, ctx_sm,
                ctx_sg, out, stream);
  } else {
    // ---- R4 fallback layout (known to fit) ----
    float* lbl    = ws;
    float* pnorm  = lbl + NLBL * CDIM;
    float* lnorm  = pnorm + 100352;
    float* part_s = lnorm + 1024;
    int*   part_i = (int*)(part_s + NLBL * NCHUNK * KP);
    float* ctx_all = part_s + 2 * NLBL * NCHUNK * KP;
    float* ctx_gm  = ctx_all + NLBL * CDIM;
    float* ctx_sm  = ctx_gm + NGENRE * CDIM;
    float* ctx_sg  = ctx_sm + NSUB * CDIM;

    k_concat_labels<<<NLBL, 256, 0, stream>>>(mood_emb, genre_emb, sub_emb, lbl);
    k_norms_np<<<512, 256, 0, stream>>>(patch, NPATCH, pnorm);
    k_norms_np<<<4, 256, 0, stream>>>(lbl, NLBL, lnorm);
    dim3 gscr(NCHUNK, NLBL / BLK);
    k_screen_f32<<<gscr, 256, 0, stream>>>(lbl, patch, pnorm, lnorm, part_s, part_i);
    k_merge_f32<<<NLBL, 256, 0, stream>>>(part_s, part_i, patch, lbl, ctx_all);
    launch_tail(mood_emb, genre_emb, sub_emb, Wm_w, Wm_b, Wg_w, Wg_b, Ws_w, Ws_b,
                lnm_g, lnm_b, lng_g, lng_b, lns_g, lns_b, ctx_all, ctx_gm, ctx_sm,
                ctx_sg, out, stream);
  }
}

// Round 9
// 1624.691 us; speedup vs baseline: 1.3953x; 1.0511x over previous
//
#include <hip/hip_runtime.h>
#include <math.h>

#define NPATCH 100000
#define CDIM   256
#define NMOOD  64
#define NGENRE 256
#define NSUB   512
#define NLBL   832          // 64+256+512
#define KTOP   9
#define NGRPTOT 6250        // NPATCH/16

// ---- f32 fallback screen constants (R4, known-green) ----
#define NCHUNK 39
#define CHUNK  2624
#define BLK    64
#define KC     32
#define KP     12

// ---- MFMA screen constants ----
#define PBLK   1600         // patches per chunk
#define NCH3   63           // 63*1600 = 100800 >= 100000
#define NGRP   100          // PBLK/16
#define KPS    16           // per-(label,chunk) partial size
#define SL     6            // per-lane list depth (single list per lane)

typedef __attribute__((ext_vector_type(8))) short bf16x8;
typedef __attribute__((ext_vector_type(8))) unsigned short u16x8;
typedef __attribute__((ext_vector_type(4))) float f32x4;

// ---------------- serial top-k insert (ascending by (val,idx)) --------------

template <int K>
__device__ __forceinline__ void tk_insert(float (&v)[K], int (&ii)[K],
                                          float s, int idx) {
  if (s < v[K - 1] || (s == v[K - 1] && idx < ii[K - 1])) {
    v[K - 1] = s; ii[K - 1] = idx;
#pragma unroll
    for (int t = K - 1; t > 0; --t) {
      bool sw = (v[t] < v[t - 1]) || (v[t] == v[t - 1] && ii[t] < ii[t - 1]);
      if (sw) {
        float fv = v[t]; v[t] = v[t - 1]; v[t - 1] = fv;
        int fi = ii[t]; ii[t] = ii[t - 1]; ii[t - 1] = fi;
      }
    }
  }
}

// ------ numpy-pairwise sum of squares over 256 contiguous floats ------------

__device__ float np_sq256(const float* a) {
  float b0, b1;
  {
    float r[8];
#pragma unroll
    for (int i = 0; i < 8; ++i) { float x = a[i]; r[i] = __fmul_rn(x, x); }
    for (int j = 8; j < 128; j += 8)
#pragma unroll
      for (int i = 0; i < 8; ++i) {
        float x = a[j + i];
        r[i] = __fadd_rn(r[i], __fmul_rn(x, x));
      }
    b0 = __fadd_rn(__fadd_rn(__fadd_rn(r[0], r[1]), __fadd_rn(r[2], r[3])),
                   __fadd_rn(__fadd_rn(r[4], r[5]), __fadd_rn(r[6], r[7])));
  }
  {
    float r[8];
#pragma unroll
    for (int i = 0; i < 8; ++i) { float x = a[128 + i]; r[i] = __fmul_rn(x, x); }
    for (int j = 8; j < 128; j += 8)
#pragma unroll
      for (int i = 0; i < 8; ++i) {
        float x = a[128 + j + i];
        r[i] = __fadd_rn(r[i], __fmul_rn(x, x));
      }
    b1 = __fadd_rn(__fadd_rn(__fadd_rn(r[0], r[1]), __fadd_rn(r[2], r[3])),
                   __fadd_rn(__fadd_rn(r[4], r[5]), __fadd_rn(r[6], r[7])));
  }
  return __fadd_rn(b0, b1);
}

__device__ __forceinline__ float np_key(float ln, float dot, float pn) {
  return __fadd_rn(__fsub_rn(ln, __fmul_rn(2.f, dot)), pn);
}

// ---------------- kernel: concat labels into one (832,256) matrix -----------

__global__ void k_concat_labels(const float* __restrict__ mood,
                                const float* __restrict__ genre,
                                const float* __restrict__ sub,
                                float* __restrict__ lbl) {
  int i = blockIdx.x * 256 + threadIdx.x;
  if (i < NMOOD * CDIM) lbl[i] = mood[i];
  else if (i < (NMOOD + NGENRE) * CDIM) lbl[i] = genre[i - NMOOD * CDIM];
  else lbl[i] = sub[i - (NMOOD + NGENRE) * CDIM];
}

// ---------------- kernel: wave-parallel numpy-pairwise row norms ------------
// (R5-green) 8 rows x 8 accumulators per wave; bit-identical to np_sq256.

__global__ void k_norms_wave(const float* __restrict__ m, int n,
                             float* __restrict__ out) {
  int gw = (blockIdx.x * blockDim.x + threadIdx.x) >> 6;
  int lane = threadIdx.x & 63;
  int rsub = lane >> 3, i = lane & 7;
  int nw = (gridDim.x * blockDim.x) >> 6;
  for (int row0 = gw * 8; row0 < n; row0 += nw * 8) {
    int row = row0 + rsub;
    const float* a = m + (size_t)row * CDIM;
    float b[2];
#pragma unroll
    for (int blk = 0; blk < 2; ++blk) {
      const float* ab = a + blk * 128;
      float x = ab[i];
      float r = __fmul_rn(x, x);
      for (int j = 1; j < 16; ++j) {
        float y = ab[j * 8 + i];
        r = __fadd_rn(r, __fmul_rn(y, y));
      }
      float t = __fadd_rn(r, __shfl_xor(r, 1));
      t = __fadd_rn(t, __shfl_xor(t, 2));
      t = __fadd_rn(t, __shfl_xor(t, 4));
      b[blk] = t;
    }
    if (i == 0) out[row] = __fadd_rn(b[0], b[1]);
  }
}

// ---------------- kernel: f32 -> bf16 (RNE) row-major (labels) --------------

__device__ __forceinline__ unsigned short f2bf(float x) {
  unsigned u = __float_as_uint(x);
  return (unsigned short)((u + 0x7fffu + ((u >> 16) & 1u)) >> 16);
}

__global__ void k_tobf16(const float* __restrict__ src, size_t n8,
                         unsigned short* __restrict__ dst) {
  size_t i = (size_t)blockIdx.x * blockDim.x + threadIdx.x;
  size_t stride = (size_t)gridDim.x * blockDim.x;
  for (; i < n8; i += stride) {
    const float4* s = (const float4*)(src + i * 8);
    float4 x = s[0], y = s[1];
    u16x8 o;
    o[0] = f2bf(x.x); o[1] = f2bf(x.y); o[2] = f2bf(x.z); o[3] = f2bf(x.w);
    o[4] = f2bf(y.x); o[5] = f2bf(y.y); o[6] = f2bf(y.z); o[7] = f2bf(y.w);
    *(u16x8*)(dst + i * 8) = o;
  }
}

// ---------------- kernel: pack patches into MFMA B-fragment order -----------
// packed[(gg*8+kk)*512 + l*8 + j] = bf16(src[(gg*16 + (l&15))*256 + (l>>4)*8
// + kk*32 + j]) — exactly the per-lane values R8's screen loaded, stored so
// the screen's loads become lane-contiguous (1 KB/instruction). Divergence
// cost is paid HERE, once (100K wave-loads total vs 2.6M in the screen).

__global__ void k_pack(const float* __restrict__ src,
                       unsigned short* __restrict__ packed) {
  int gw = (blockIdx.x * blockDim.x + threadIdx.x) >> 6;
  int l = threadIdx.x & 63;
  int col = l & 15, kg = l >> 4;
  int nw = (gridDim.x * blockDim.x) >> 6;
  for (int gg = gw; gg < NGRPTOT; gg += nw) {
    const float* base = src + ((size_t)gg * 16 + col) * CDIM + kg * 8;
#pragma unroll
    for (int kk = 0; kk < 8; ++kk) {
      float4 v0 = *(const float4*)(base + kk * 32);
      float4 v1 = *(const float4*)(base + kk * 32 + 4);
      u16x8 o;
      o[0] = f2bf(v0.x); o[1] = f2bf(v0.y); o[2] = f2bf(v0.z); o[3] = f2bf(v0.w);
      o[4] = f2bf(v1.x); o[5] = f2bf(v1.y); o[6] = f2bf(v1.z); o[7] = f2bf(v1.w);
      *(u16x8*)&packed[((size_t)gg * 8 + kk) * 512 + l * 8] = o;
    }
  }
}

// ---------------- kernel: MFMA bf16 screen (coalesced, reg-pipelined) -------
// 832 blocks (XCD swizzle); block = 4 waves; wave owns 16 labels (A in regs),
// streams its chunk in 16-patch groups from the PACKED layout: every load is
// base + lane*16B (fully coalesced). 2-stage register double-buffer, zero
// barriers/LDS in main loop. Keys approximate (bf16); exact re-rank after.

__global__ __launch_bounds__(256) void k_screen_mfma(
    const unsigned short* __restrict__ lblbf,
    const unsigned short* __restrict__ packed,
    const float* __restrict__ pnorm,
    float* __restrict__ part_s, int* __restrict__ part_i) {
  __shared__ float pn_lds[PBLK];          // 6.4 KB
  __shared__ float stv[64][4][SL];        // 6 KB
  __shared__ int   sti[64][4][SL];        // 6 KB
  const int tid = threadIdx.x;
  const int w = tid >> 6, l = tid & 63;
  const int col = l & 15, kg = l >> 4;
  const int b = blockIdx.x;
  const int r8 = b & 7, q = b >> 3;
  const int x = q % 13, h = q / 13;
  const int chunk = h * 8 + r8;
  if (chunk >= NCH3) return;
  const int lab0 = x * 64 + w * 16;
  const int p0 = chunk * PBLK;
  const int grp0 = p0 >> 4;
  const int ng = min(NGRP, (NPATCH - p0 + 15) >> 4);  // trim dead tail groups

  for (int e = tid; e < PBLK; e += 256) {
    int p = p0 + e;
    pn_lds[e] = (p < NPATCH) ? pnorm[p] : INFINITY;
  }

  bf16x8 a[8];
#pragma unroll
  for (int kk = 0; kk < 8; ++kk)
    a[kk] = *(const bf16x8*)&lblbf[(size_t)(lab0 + col) * CDIM + kk * 32 + kg * 8];

  float lv[SL]; int li[SL];
#pragma unroll
  for (int j = 0; j < SL; ++j) { lv[j] = INFINITY; li[j] = 0x7fffffff; }

  __syncthreads();  // pn_lds ready

#define LOADB(g, bb)                                                        \
  {                                                                         \
    int gg_ = grp0 + (g);                                                   \
    if (gg_ > NGRPTOT - 1) gg_ = NGRPTOT - 1;                               \
    const unsigned short* pr_ = packed + ((size_t)gg_ * 8) * 512 + l * 8;   \
    _Pragma("unroll") for (int kk = 0; kk < 8; ++kk)                        \
        bb[kk] = *(const bf16x8*)&pr_[kk * 512];                            \
  }

  // D[row=patch (kg*4+rr)][col=label (lane&15)]
#define COMPUTE(g, bb)                                                      \
  {                                                                         \
    f32x4 ac0 = {0.f, 0.f, 0.f, 0.f}, ac1 = {0.f, 0.f, 0.f, 0.f};          \
    _Pragma("unroll") for (int kk = 0; kk < 4; ++kk) {                      \
      ac0 = __builtin_amdgcn_mfma_f32_16x16x32_bf16(bb[2 * kk], a[2 * kk],  \
                                                    ac0, 0, 0, 0);          \
      ac1 = __builtin_amdgcn_mfma_f32_16x16x32_bf16(bb[2 * kk + 1],         \
                                                    a[2 * kk + 1], ac1,     \
                                                    0, 0, 0);               \
    }                                                                       \
    _Pragma("unroll") for (int rr = 0; rr < 4; ++rr) {                      \
      int p_ = p0 + (g) * 16 + kg * 4 + rr;                                 \
      bool ok_ = p_ < NPATCH;                                               \
      float pn_ = pn_lds[(g) * 16 + kg * 4 + rr];                           \
      float key_ = ok_ ? fmaf(-2.f, ac0[rr] + ac1[rr], pn_) : INFINITY;     \
      tk_insert<SL>(lv, li, key_, ok_ ? p_ : 0x7fffffff);                   \
    }                                                                       \
  }

  bf16x8 bA[8], bB[8];
  LOADB(0, bA);
  for (int g = 0; g < ng; g += 2) {
    if (g + 1 < ng) LOADB(g + 1, bB);
    COMPUTE(g, bA);
    if (g + 2 < ng) LOADB(g + 2, bA);
    if (g + 1 < ng) COMPUTE(g + 1, bB);
  }
#undef LOADB
#undef COMPUTE

  {
    int s = w * 16 + col;
#pragma unroll
    for (int j = 0; j < SL; ++j) { stv[s][kg][j] = lv[j]; sti[s][kg][j] = li[j]; }
  }
  __syncthreads();
  if (tid < 64) {
    float v[KPS]; int ii[KPS];
#pragma unroll
    for (int j = 0; j < KPS; ++j) { v[j] = INFINITY; ii[j] = 0x7fffffff; }
    for (int src = 0; src < 4; ++src)
#pragma unroll
      for (int j = 0; j < SL; ++j)
        tk_insert<KPS>(v, ii, stv[tid][src][j], sti[tid][src][j]);
    size_t base = ((size_t)(x * 64 + tid) * NCH3 + chunk) * KPS;
#pragma unroll
    for (int j = 0; j < KPS; ++j) { part_s[base + j] = v[j]; part_i[base + j] = ii[j]; }
  }
}

// ---------------- kernel: merge + EXACT np-f32 re-rank + max-agg ------------
// funnel 64x12 -> 8x16 -> ALL 128 candidates re-ranked exactly in parallel
// (strictly more conservative than the old 32-candidate funnel; depths >= 9
// so a true top-9 entry can never be dropped).

__global__ void k_merge_mfma(const float* __restrict__ part_s,
                             const int* __restrict__ part_i,
                             const float* __restrict__ patch,
                             const float* __restrict__ lbl,
                             const float* __restrict__ pnorm,
                             const float* __restrict__ lnorm,
                             float* __restrict__ ctx) {
  const int lab = blockIdx.x;
  const int tid = threadIdx.x;
  __shared__ float lsh[CDIM];
  __shared__ float sv[64 * 12];
  __shared__ int   si[64 * 12];
  __shared__ float mv[128];
  __shared__ int   mi[128];
  __shared__ float ckey[128];
  __shared__ int   nb[KTOP];

  lsh[tid] = lbl[(size_t)lab * CDIM + tid];
  const int total = NCH3 * KPS;  // 1008
  if (tid < 64) {
    float v[12]; int ii[12];
#pragma unroll
    for (int j = 0; j < 12; ++j) { v[j] = INFINITY; ii[j] = 0x7fffffff; }
    for (int e = tid; e < total; e += 64)
      tk_insert<12>(v, ii, part_s[(size_t)lab * total + e],
                    part_i[(size_t)lab * total + e]);
#pragma unroll
    for (int j = 0; j < 12; ++j) { sv[tid * 12 + j] = v[j]; si[tid * 12 + j] = ii[j]; }
  }
  __syncthreads();
  if (tid < 8) {
    float v[16]; int ii[16];
#pragma unroll
    for (int j = 0; j < 16; ++j) { v[j] = INFINITY; ii[j] = 0x7fffffff; }
    for (int e = 0; e < 8 * 12; ++e)
      tk_insert<16>(v, ii, sv[tid * 96 + e], si[tid * 96 + e]);
#pragma unroll
    for (int j = 0; j < 16; ++j) { mv[tid * 16 + j] = v[j]; mi[tid * 16 + j] = ii[j]; }
  }
  __syncthreads();
  // exact np-f32 key for all 128 funnel candidates (sequential fmaf chain)
  if (tid < 128) {
    int c = mi[tid];
    float key = INFINITY;
    if (c != 0x7fffffff) {
      const float* prow = &patch[(size_t)c * CDIM];
      float dot = 0.f;
      for (int k = 0; k < CDIM; ++k) dot = fmaf(lsh[k], prow[k], dot);
      key = np_key(lnorm[lab], dot, pnorm[c]);
    }
    ckey[tid] = key;
  }
  __syncthreads();
  if (tid == 0) {
    for (int t = 0; t < KTOP; ++t) {
      float best = INFINITY; int bj = 0, bidx = 0x7fffffff;
      for (int j = 0; j < 128; ++j) {
        if (ckey[j] < best || (ckey[j] == best && mi[j] < bidx)) {
          best = ckey[j]; bj = j; bidx = mi[j];
        }
      }
      nb[t] = mi[bj];
      ckey[bj] = INFINITY;
    }
  }
  __syncthreads();
  float mx = -INFINITY;
#pragma unroll
  for (int j = 0; j < KTOP; ++j)
    mx = fmaxf(mx, patch[(size_t)nb[j] * CDIM + tid]);
  ctx[(size_t)lab * CDIM + tid] = mx - lsh[tid];
}

// ---------------- FALLBACK: R4 f32 screen + merge (known-green) -------------

__global__ void k_norms_np(const float* __restrict__ m, int n,
                           float* __restrict__ out) {
  int i = blockIdx.x * blockDim.x + threadIdx.x;
  int stride = gridDim.x * blockDim.x;
  for (; i < n; i += stride) out[i] = np_sq256(m + (size_t)i * CDIM);
}

__global__ void k_screen_f32(const float* __restrict__ lbl,
                             const float* __restrict__ patch,
                             const float* __restrict__ pnorm,
                             const float* __restrict__ lnorm,
                             float* __restrict__ part_s,
                             int* __restrict__ part_i) {
  __shared__ float Asm[KC][BLK];
  __shared__ float Bsm[KC][BLK];
  __shared__ float sc[BLK][BLK + 1];
  const int tid = threadIdx.x;
  const int tr = tid >> 4, tc = tid & 15;
  const int lbase = blockIdx.y * BLK;
  const int chunk = blockIdx.x;
  const int p0 = chunk * CHUNK;
  const int p1 = (p0 + CHUNK < NPATCH) ? p0 + CHUNK : NPATCH;

  float tv[KP]; int ti[KP];
#pragma unroll
  for (int j = 0; j < KP; ++j) { tv[j] = INFINITY; ti[j] = 0x7fffffff; }
  const float ln = (tid < BLK) ? lnorm[lbase + tid] : 0.f;

  const int sl = tid >> 2;
  const int skq = (tid & 3) * 4;

  for (int pt = p0; pt < p1; pt += BLK) {
    float acc[4][4];
#pragma unroll
    for (int a = 0; a < 4; ++a)
#pragma unroll
      for (int b = 0; b < 4; ++b) acc[a][b] = 0.f;

    for (int kc = 0; kc < CDIM; kc += KC) {
      __syncthreads();
      {
        const float* arow = &lbl[(size_t)(lbase + sl) * CDIM + kc];
        float4 va0 = *(const float4*)(arow + skq);
        float4 va1 = *(const float4*)(arow + 16 + skq);
        Asm[skq + 0][sl] = va0.x; Asm[skq + 1][sl] = va0.y;
        Asm[skq + 2][sl] = va0.z; Asm[skq + 3][sl] = va0.w;
        Asm[16 + skq + 0][sl] = va1.x; Asm[16 + skq + 1][sl] = va1.y;
        Asm[16 + skq + 2][sl] = va1.z; Asm[16 + skq + 3][sl] = va1.w;
        int p = pt + sl;
        float4 vb0 = make_float4(0.f, 0.f, 0.f, 0.f), vb1 = vb0;
        if (p < p1) {
          const float* brow = &patch[(size_t)p * CDIM + kc];
          vb0 = *(const float4*)(brow + skq);
          vb1 = *(const float4*)(brow + 16 + skq);
        }
        Bsm[skq + 0][sl] = vb0.x; Bsm[skq + 1][sl] = vb0.y;
        Bsm[skq + 2][sl] = vb0.z; Bsm[skq + 3][sl] = vb0.w;
        Bsm[16 + skq + 0][sl] = vb1.x; Bsm[16 + skq + 1][sl] = vb1.y;
        Bsm[16 + skq + 2][sl] = vb1.z; Bsm[16 + skq + 3][sl] = vb1.w;
      }
      __syncthreads();
#pragma unroll
      for (int k = 0; k < KC; ++k) {
        float4 a4 = *(const float4*)&Asm[k][tr * 4];
        float4 b4 = *(const float4*)&Bsm[k][tc * 4];
        const float av[4] = {a4.x, a4.y, a4.z, a4.w};
        const float bv[4] = {b4.x, b4.y, b4.z, b4.w};
#pragma unroll
        for (int a = 0; a < 4; ++a)
#pragma unroll
          for (int b = 0; b < 4; ++b) acc[a][b] = fmaf(av[a], bv[b], acc[a][b]);
      }
    }
#pragma unroll
    for (int a = 0; a < 4; ++a)
#pragma unroll
      for (int b = 0; b < 4; ++b) sc[tr * 4 + a][tc * 4 + b] = acc[a][b];
    __syncthreads();
    if (tid < BLK) {
      for (int c = 0; c < BLK; ++c) {
        int p = pt + c;
        if (p < p1) tk_insert<KP>(tv, ti, np_key(ln, sc[tid][c], pnorm[p]), p);
      }
    }
  }

  if (tid < BLK) {
    int lab = lbase + tid;
    size_t base = ((size_t)lab * NCHUNK + chunk) * KP;
#pragma unroll
    for (int j = 0; j < KP; ++j) { part_s[base + j] = tv[j]; part_i[base + j] = ti[j]; }
  }
}

__global__ void k_merge_f32(const float* __restrict__ part_s,
                            const int* __restrict__ part_i,
                            const float* __restrict__ patch,
                            const float* __restrict__ lbl,
                            float* __restrict__ ctx) {
  const int lab = blockIdx.x;
  const int tid = threadIdx.x;
  __shared__ float cv[16][KP];
  __shared__ int ci[16][KP];
  __shared__ int nb[KTOP];

  const int total = NCHUNK * KP;
  if (tid < 16) {
    float v[KP]; int ii[KP];
#pragma unroll
    for (int j = 0; j < KP; ++j) { v[j] = INFINITY; ii[j] = 0x7fffffff; }
    for (int e = tid; e < total; e += 16)
      tk_insert<KP>(v, ii, part_s[(size_t)lab * total + e],
                    part_i[(size_t)lab * total + e]);
#pragma unroll
    for (int j = 0; j < KP; ++j) { cv[tid][j] = v[j]; ci[tid][j] = ii[j]; }
  }
  __syncthreads();
  if (tid == 0) {
    float v[KP]; int ii[KP];
#pragma unroll
    for (int j = 0; j < KP; ++j) { v[j] = INFINITY; ii[j] = 0x7fffffff; }
    for (int t = 0; t < 16; ++t)
      for (int j = 0; j < KP; ++j) tk_insert<KP>(v, ii, cv[t][j], ci[t][j]);
#pragma unroll
    for (int j = 0; j < KTOP; ++j) nb[j] = ii[j];
  }
  __syncthreads();
  float l = lbl[(size_t)lab * CDIM + tid];
  float mx = -INFINITY;
#pragma unroll
  for (int j = 0; j < KTOP; ++j)
    mx = fmaxf(mx, patch[(size_t)nb[j] * CDIM + tid]);
  ctx[(size_t)lab * CDIM + tid] = mx - l;
}

// ---------------- kernel: small label->label agg (np-f32 semantics) ---------

__global__ void k_small_agg(const float* __restrict__ lbl_rows,
                            const float* __restrict__ tgt, int M, int k,
                            float* __restrict__ ctx) {
  const int row = blockIdx.x;
  const int tid = threadIdx.x;
  __shared__ float lsh[CDIM];
  __shared__ float skey[256];
  __shared__ float lns;
  __shared__ int nb[4];
  lsh[tid] = lbl_rows[(size_t)row * CDIM + tid];
  __syncthreads();
  if (tid == 0) lns = np_sq256(lsh);
  __syncthreads();
  float key = INFINITY;
  if (tid < M) {
    const float* trow = &tgt[(size_t)tid * CDIM];
    float tn = np_sq256(trow);
    float dot = 0.f;
    for (int c = 0; c < CDIM; ++c) dot = fmaf(lsh[c], trow[c], dot);
    key = np_key(lns, dot, tn);
  }
  skey[tid] = key;
  __syncthreads();
  if (tid == 0) {
    for (int t = 0; t < k; ++t) {
      float best = INFINITY; int bi = 0;
      for (int j = 0; j < M; ++j)
        if (skey[j] < best) { best = skey[j]; bi = j; }
      nb[t] = bi; skey[bi] = INFINITY;
    }
  }
  __syncthreads();
  float mx = -INFINITY;
  for (int t = 0; t < k; ++t) mx = fmaxf(mx, tgt[(size_t)nb[t] * CDIM + tid]);
  ctx[(size_t)row * CDIM + tid] = mx - lsh[tid];
}

// ---------------- kernel: linear(concat) + residual + LayerNorm (f64) -------

__device__ __forceinline__ double block_sum_256d(double x, double* red) {
#pragma unroll
  for (int m = 32; m >= 1; m >>= 1) x += __shfl_xor(x, m);
  int wid = threadIdx.x >> 6, lane = threadIdx.x & 63;
  if (lane == 0) red[wid] = x;
  __syncthreads();
  double s = red[0] + red[1] + red[2] + red[3];
  __syncthreads();
  return s;
}

__global__ void k_level_out(const float* __restrict__ emb,
                            const float* __restrict__ c1,
                            const float* __restrict__ c2,
                            const float* __restrict__ c3, int nseg,
                            const float* __restrict__ W,
                            const float* __restrict__ bias,
                            const float* __restrict__ gamma,
                            const float* __restrict__ beta,
                            float* __restrict__ out) {
  __shared__ float xs[4 * CDIM];
  __shared__ double red[4];
  const int row = blockIdx.x, ch = threadIdx.x;
  float e = emb[(size_t)row * CDIM + ch];
  xs[ch] = e;
  if (nseg > 1) xs[CDIM + ch] = c1[(size_t)row * CDIM + ch];
  if (nseg > 2) xs[2 * CDIM + ch] = c2[(size_t)row * CDIM + ch];
  if (nseg > 3) xs[3 * CDIM + ch] = c3[(size_t)row * CDIM + ch];
  __syncthreads();
  const int F = nseg * CDIM;
  double y = (double)e + (double)bias[ch];
#pragma unroll 4
  for (int j = 0; j < F; ++j)
    y += (double)xs[j] * (double)W[(size_t)j * CDIM + ch];
  double mu = block_sum_256d(y, red) * (1.0 / 256.0);
  double d = y - mu;
  double var = block_sum_256d(d * d, red) * (1.0 / 256.0);
  out[(size_t)row * CDIM + ch] =
      (float)(d / sqrt(var + 1e-5) * (double)gamma[ch] + (double)beta[ch]);
}

// ---------------- launch ----------------------------------------------------

static void launch_tail(const float* mood_emb, const float* genre_emb,
                        const float* sub_emb, const float* Wm_w, const float* Wm_b,
                        const float* Wg_w, const float* Wg_b, const float* Ws_w,
                        const float* Ws_b, const float* lnm_g, const float* lnm_b,
                        const float* lng_g, const float* lng_b, const float* lns_g,
                        const float* lns_b, const float* ctx_all, float* ctx_gm,
                        float* ctx_sm, float* ctx_sg, float* out,
                        hipStream_t stream) {
  k_level_out<<<NMOOD, 256, 0, stream>>>(mood_emb, ctx_all, nullptr, nullptr, 2,
                                         Wm_w, Wm_b, lnm_g, lnm_b, out);
  k_small_agg<<<NGENRE, 256, 0, stream>>>(genre_emb, out, NMOOD, 4, ctx_gm);
  k_level_out<<<NGENRE, 256, 0, stream>>>(genre_emb, ctx_all + NMOOD * CDIM, ctx_gm,
                                          nullptr, 3, Wg_w, Wg_b, lng_g, lng_b,
                                          out + NMOOD * CDIM);
  k_small_agg<<<NSUB, 256, 0, stream>>>(sub_emb, out, NMOOD, 3, ctx_sm);
  k_small_agg<<<NSUB, 256, 0, stream>>>(sub_emb, out + NMOOD * CDIM, NGENRE, 4, ctx_sg);
  k_level_out<<<NSUB, 256, 0, stream>>>(sub_emb, ctx_all + (NMOOD + NGENRE) * CDIM,
                                        ctx_sm, ctx_sg, 4, Ws_w, Ws_b, lns_g, lns_b,
                                        out + NMOOD * CDIM + NGENRE * CDIM);
}

extern "C" void kernel_launch(void* const* d_in, const int* in_sizes, int n_in,
                              void* d_out, int out_size, void* d_ws, size_t ws_size,
                              hipStream_t stream) {
  const float* patch     = (const float*)d_in[0];
  const float* mood_emb  = (const float*)d_in[1];
  const float* genre_emb = (const float*)d_in[2];
  const float* sub_emb   = (const float*)d_in[3];
  const float* Wm_w = (const float*)d_in[4];
  const float* Wm_b = (const float*)d_in[5];
  const float* Wg_w = (const float*)d_in[6];
  const float* Wg_b = (const float*)d_in[7];
  const float* Ws_w = (const float*)d_in[8];
  const float* Ws_b = (const float*)d_in[9];
  const float* lnm_g = (const float*)d_in[10];
  const float* lnm_b = (const float*)d_in[11];
  const float* lng_g = (const float*)d_in[12];
  const float* lng_b = (const float*)d_in[13];
  const float* lns_g = (const float*)d_in[14];
  const float* lns_b = (const float*)d_in[15];
  float* out = (float*)d_out;
  float* ws = (float*)d_ws;

  const size_t REQ = 15438848ull * 4ull;  // ~61.8 MB

  if (ws_size >= REQ) {
    // ---- MFMA path layout ----
    float* lbl     = ws;                     // 212992
    float* pnorm   = lbl + NLBL * CDIM;      // 100352
    float* lnorm   = pnorm + 100352;         // 1024
    float* ctx_all = lnorm + 1024;           // 212992
    float* ctx_gm  = ctx_all + NLBL * CDIM;  // 65536
    float* ctx_sm  = ctx_gm + NGENRE * CDIM; // 131072
    float* ctx_sg  = ctx_sm + NSUB * CDIM;   // 131072
    float* part_s  = ctx_sg + NSUB * CDIM;   // 832*63*16 = 838656
    int*   part_i  = (int*)(part_s + (size_t)NLBL * NCH3 * KPS);
    unsigned short* packed = (unsigned short*)(part_i + (size_t)NLBL * NCH3 * KPS);
    unsigned short* lblbf  = packed + (size_t)NPATCH * CDIM;  // same elem count

    k_concat_labels<<<NLBL, 256, 0, stream>>>(mood_emb, genre_emb, sub_emb, lbl);
    k_norms_wave<<<512, 256, 0, stream>>>(patch, NPATCH, pnorm);
    k_norms_wave<<<16, 256, 0, stream>>>(lbl, NLBL, lnorm);
    k_tobf16<<<128, 256, 0, stream>>>(lbl, (size_t)NLBL * CDIM / 8, lblbf);
    k_pack<<<1024, 256, 0, stream>>>(patch, packed);
    k_screen_mfma<<<832, 256, 0, stream>>>(lblbf, packed, pnorm, part_s, part_i);
    k_merge_mfma<<<NLBL, 256, 0, stream>>>(part_s, part_i, patch, lbl, pnorm,
                                           lnorm, ctx_all);
    launch_tail(mood_emb, genre_emb, sub_emb, Wm_w, Wm_b, Wg_w, Wg_b, Ws_w, Ws_b,
                lnm_g, lnm_b, lng_g, lng_b, lns_g, lns_b, ctx_all, ctx_gm, ctx_sm,
                ctx_sg, out, stream);
  } else {
    // ---- R4 fallback layout (known to fit) ----
    float* lbl    = ws;
    float* pnorm  = lbl + NLBL * CDIM;
    float* lnorm  = pnorm + 100352;
    float* part_s = lnorm + 1024;
    int*   part_i = (int*)(part_s + NLBL * NCHUNK * KP);
    float* ctx_all = part_s + 2 * NLBL * NCHUNK * KP;
    float* ctx_gm  = ctx_all + NLBL * CDIM;
    float* ctx_sm  = ctx_gm + NGENRE * CDIM;
    float* ctx_sg  = ctx_sm + NSUB * CDIM;

    k_concat_labels<<<NLBL, 256, 0, stream>>>(mood_emb, genre_emb, sub_emb, lbl);
    k_norms_np<<<512, 256, 0, stream>>>(patch, NPATCH, pnorm);
    k_norms_np<<<4, 256, 0, stream>>>(lbl, NLBL, lnorm);
    dim3 gscr(NCHUNK, NLBL / BLK);
    k_screen_f32<<<gscr, 256, 0, stream>>>(lbl, patch, pnorm, lnorm, part_s, part_i);
    k_merge_f32<<<NLBL, 256, 0, stream>>>(part_s, part_i, patch, lbl, ctx_all);
    launch_tail(mood_emb, genre_emb, sub_emb, Wm_w, Wm_b, Wg_w, Wg_b, Ws_w, Ws_b,
                lnm_g, lnm_b, lng_g, lng_b, lns_g, lns_b, ctx_all, ctx_gm, ctx_sm,
                ctx_sg, out, stream);
  }
}

// Round 10
// 893.962 us; speedup vs baseline: 2.5358x; 1.8174x over previous
//
#include <hip/hip_runtime.h>
#include <math.h>

#define NPATCH 100000
#define CDIM   256
#define NMOOD  64
#define NGENRE 256
#define NSUB   512
#define NLBL   832          // 64+256+512
#define KTOP   9
#define NGRPTOT 6250        // NPATCH/16

// ---- f32 fallback screen constants (R4, known-green) ----
#define NCHUNK 39
#define CHUNK  2624
#define BLK    64
#define KC     32
#define KP     12

// ---- MFMA screen constants ----
#define PBLK4  992          // patches per chunk (62 groups)
#define NCH4   101          // 101*992 = 100192 >= 100000
#define TGRP   2            // groups per LDS tile (32 patches, 16 KB)
#define SL4    4            // per-lane list depth
#define KPS4   9            // per-(label,chunk) stored candidates

typedef __attribute__((ext_vector_type(8))) short bf16x8;
typedef __attribute__((ext_vector_type(8))) unsigned short u16x8;
typedef __attribute__((ext_vector_type(4))) float f32x4;

// ---------------- serial top-k insert (ascending by (val,idx)) --------------

template <int K>
__device__ __forceinline__ void tk_insert(float (&v)[K], int (&ii)[K],
                                          float s, int idx) {
  if (s < v[K - 1] || (s == v[K - 1] && idx < ii[K - 1])) {
    v[K - 1] = s; ii[K - 1] = idx;
#pragma unroll
    for (int t = K - 1; t > 0; --t) {
      bool sw = (v[t] < v[t - 1]) || (v[t] == v[t - 1] && ii[t] < ii[t - 1]);
      if (sw) {
        float fv = v[t]; v[t] = v[t - 1]; v[t - 1] = fv;
        int fi = ii[t]; ii[t] = ii[t - 1]; ii[t - 1] = fi;
      }
    }
  }
}

// branch-free variant: identical comparisons -> identical resulting list
// (swap network no-ops when nothing was inserted; list stays sorted).

template <int K>
__device__ __forceinline__ void tk_insert_nb(float (&v)[K], int (&ii)[K],
                                             float s, int idx) {
  bool ins = (s < v[K - 1]) || (s == v[K - 1] && idx < ii[K - 1]);
  v[K - 1] = ins ? s : v[K - 1];
  ii[K - 1] = ins ? idx : ii[K - 1];
#pragma unroll
  for (int t = K - 1; t > 0; --t) {
    bool sw = (v[t] < v[t - 1]) || (v[t] == v[t - 1] && ii[t] < ii[t - 1]);
    float a0 = sw ? v[t] : v[t - 1];
    float a1 = sw ? v[t - 1] : v[t];
    int b0 = sw ? ii[t] : ii[t - 1];
    int b1 = sw ? ii[t - 1] : ii[t];
    v[t - 1] = a0; v[t] = a1; ii[t - 1] = b0; ii[t] = b1;
  }
}

// ------ numpy-pairwise sum of squares over 256 contiguous floats ------------

__device__ float np_sq256(const float* a) {
  float b0, b1;
  {
    float r[8];
#pragma unroll
    for (int i = 0; i < 8; ++i) { float x = a[i]; r[i] = __fmul_rn(x, x); }
    for (int j = 8; j < 128; j += 8)
#pragma unroll
      for (int i = 0; i < 8; ++i) {
        float x = a[j + i];
        r[i] = __fadd_rn(r[i], __fmul_rn(x, x));
      }
    b0 = __fadd_rn(__fadd_rn(__fadd_rn(r[0], r[1]), __fadd_rn(r[2], r[3])),
                   __fadd_rn(__fadd_rn(r[4], r[5]), __fadd_rn(r[6], r[7])));
  }
  {
    float r[8];
#pragma unroll
    for (int i = 0; i < 8; ++i) { float x = a[128 + i]; r[i] = __fmul_rn(x, x); }
    for (int j = 8; j < 128; j += 8)
#pragma unroll
      for (int i = 0; i < 8; ++i) {
        float x = a[128 + j + i];
        r[i] = __fadd_rn(r[i], __fmul_rn(x, x));
      }
    b1 = __fadd_rn(__fadd_rn(__fadd_rn(r[0], r[1]), __fadd_rn(r[2], r[3])),
                   __fadd_rn(__fadd_rn(r[4], r[5]), __fadd_rn(r[6], r[7])));
  }
  return __fadd_rn(b0, b1);
}

__device__ __forceinline__ float np_key(float ln, float dot, float pn) {
  return __fadd_rn(__fsub_rn(ln, __fmul_rn(2.f, dot)), pn);
}

// ---------------- kernel: concat labels into one (832,256) matrix -----------

__global__ void k_concat_labels(const float* __restrict__ mood,
                                const float* __restrict__ genre,
                                const float* __restrict__ sub,
                                float* __restrict__ lbl) {
  int i = blockIdx.x * 256 + threadIdx.x;
  if (i < NMOOD * CDIM) lbl[i] = mood[i];
  else if (i < (NMOOD + NGENRE) * CDIM) lbl[i] = genre[i - NMOOD * CDIM];
  else lbl[i] = sub[i - (NMOOD + NGENRE) * CDIM];
}

// ---------------- kernel: wave-parallel numpy-pairwise row norms ------------

__global__ void k_norms_wave(const float* __restrict__ m, int n,
                             float* __restrict__ out) {
  int gw = (blockIdx.x * blockDim.x + threadIdx.x) >> 6;
  int lane = threadIdx.x & 63;
  int rsub = lane >> 3, i = lane & 7;
  int nw = (gridDim.x * blockDim.x) >> 6;
  for (int row0 = gw * 8; row0 < n; row0 += nw * 8) {
    int row = row0 + rsub;
    const float* a = m + (size_t)row * CDIM;
    float b[2];
#pragma unroll
    for (int blk = 0; blk < 2; ++blk) {
      const float* ab = a + blk * 128;
      float x = ab[i];
      float r = __fmul_rn(x, x);
      for (int j = 1; j < 16; ++j) {
        float y = ab[j * 8 + i];
        r = __fadd_rn(r, __fmul_rn(y, y));
      }
      float t = __fadd_rn(r, __shfl_xor(r, 1));
      t = __fadd_rn(t, __shfl_xor(t, 2));
      t = __fadd_rn(t, __shfl_xor(t, 4));
      b[blk] = t;
    }
    if (i == 0) out[row] = __fadd_rn(b[0], b[1]);
  }
}

// ---------------- kernel: f32 -> bf16 (RNE) row-major (labels) --------------

__device__ __forceinline__ unsigned short f2bf(float x) {
  unsigned u = __float_as_uint(x);
  return (unsigned short)((u + 0x7fffu + ((u >> 16) & 1u)) >> 16);
}

__global__ void k_tobf16(const float* __restrict__ src, size_t n8,
                         unsigned short* __restrict__ dst) {
  size_t i = (size_t)blockIdx.x * blockDim.x + threadIdx.x;
  size_t stride = (size_t)gridDim.x * blockDim.x;
  for (; i < n8; i += stride) {
    const float4* s = (const float4*)(src + i * 8);
    float4 x = s[0], y = s[1];
    u16x8 o;
    o[0] = f2bf(x.x); o[1] = f2bf(x.y); o[2] = f2bf(x.z); o[3] = f2bf(x.w);
    o[4] = f2bf(y.x); o[5] = f2bf(y.y); o[6] = f2bf(y.z); o[7] = f2bf(y.w);
    *(u16x8*)(dst + i * 8) = o;
  }
}

// ---------------- kernel: pack patches into MFMA B-fragment order -----------
// group gg occupies bytes [gg*8192, (gg+1)*8192): [kk][lane] 16B chunks.

__global__ void k_pack(const float* __restrict__ src,
                       unsigned short* __restrict__ packed) {
  int gw = (blockIdx.x * blockDim.x + threadIdx.x) >> 6;
  int l = threadIdx.x & 63;
  int col = l & 15, kg = l >> 4;
  int nw = (gridDim.x * blockDim.x) >> 6;
  for (int gg = gw; gg < NGRPTOT; gg += nw) {
    const float* base = src + ((size_t)gg * 16 + col) * CDIM + kg * 8;
#pragma unroll
    for (int kk = 0; kk < 8; ++kk) {
      float4 v0 = *(const float4*)(base + kk * 32);
      float4 v1 = *(const float4*)(base + kk * 32 + 4);
      u16x8 o;
      o[0] = f2bf(v0.x); o[1] = f2bf(v0.y); o[2] = f2bf(v0.z); o[3] = f2bf(v0.w);
      o[4] = f2bf(v1.x); o[5] = f2bf(v1.y); o[6] = f2bf(v1.z); o[7] = f2bf(v1.w);
      *(u16x8*)&packed[((size_t)gg * 8 + kk) * 512 + l * 8] = o;
    }
  }
}

// ---------------- async global->LDS helper ----------------------------------

__device__ __forceinline__ void gload_lds16(const void* g, void* l) {
  __builtin_amdgcn_global_load_lds(
      (const __attribute__((address_space(1))) unsigned int*)g,
      (__attribute__((address_space(3))) unsigned int*)l, 16, 0, 0);
}

// ---------------- kernel: MFMA bf16 screen (2-phase LDS-DMA, high-occ) ------
// 1313 blocks (13 lgroups x 101 chunks of 992 patches). Block = 4 waves; wave
// owns 16 labels (A in regs). B-tiles (2 groups = 16 KB, packed-fragment
// layout) staged by global_load_lds (LINEAR src+dst); 2-phase: stage(t+1)
// issued BEFORE compute(t), one __syncthreads per tile (its vmcnt0 drain
// happens AFTER compute covered the DMA latency). ds_read at lane*16 ->
// conflict-free. Branch-free inserts; per-lane top-4, in-wave shfl merge
// (xor16, xor32) -> per-(label,chunk) top-9 stored straight to global.
// Keys approximate (bf16); selection finalized by exact np-f32 re-rank.

__global__ __launch_bounds__(256) void k_screen_mfma(
    const unsigned short* __restrict__ lblbf,
    const unsigned short* __restrict__ packed,
    const float* __restrict__ pnorm,
    float* __restrict__ part_s, int* __restrict__ part_i) {
  __shared__ float pn_lds[PBLK4];                    // 3.97 KB
  __shared__ __align__(16) char smem[2][TGRP * 8192];  // 32 KB
  const int tid = threadIdx.x;
  const int w = tid >> 6, l = tid & 63;
  const int col = l & 15, kg = l >> 4;
  const int lgrp = blockIdx.x % 13;
  const int chunk = blockIdx.x / 13;
  const int lab0 = lgrp * 64 + w * 16;
  const int p0 = chunk * PBLK4;
  const int grp0 = p0 >> 4;
  const int ngrp = min(PBLK4 / 16, (NPATCH - p0 + 15) >> 4);
  const int ntile = (ngrp + TGRP - 1) / TGRP;

  for (int e = tid; e < PBLK4; e += 256) {
    int p = p0 + e;
    pn_lds[e] = (p < NPATCH) ? pnorm[p] : INFINITY;
  }

  bf16x8 a[8];
#pragma unroll
  for (int kk = 0; kk < 8; ++kk)
    a[kk] = *(const bf16x8*)&lblbf[(size_t)(lab0 + col) * CDIM + kk * 32 + kg * 8];

  float lv[SL4]; int li[SL4];
#pragma unroll
  for (int j = 0; j < SL4; ++j) { lv[j] = INFINITY; li[j] = 0x7fffffff; }

  auto stage = [&](int buf, int t) {
#pragma unroll
    for (int q = 0; q < TGRP; ++q) {
      int gg = grp0 + t * TGRP + q;
      if (gg > NGRPTOT - 1) gg = NGRPTOT - 1;
      const char* gsrc = (const char*)packed + (size_t)gg * 8192;
#pragma unroll
      for (int r = 0; r < 2; ++r) {
        int c = tid + r * 256;  // 16B chunk 0..511 within the 8 KB group
        gload_lds16(gsrc + c * 16, &smem[buf][q * 8192 + c * 16]);
      }
    }
  };

  stage(0, 0);
  __syncthreads();  // drains tile0 DMA + pn_lds
  for (int t = 0; t < ntile; ++t) {
    const int cb = t & 1;
    if (t + 1 < ntile) stage(cb ^ 1, t + 1);   // issue BEFORE compute
#pragma unroll
    for (int q = 0; q < TGRP; ++q) {
      int gl = t * TGRP + q;
      if (gl >= ngrp) break;  // uniform
      const char* gb = &smem[cb][q * 8192];
      bf16x8 bb[8];
#pragma unroll
      for (int kk = 0; kk < 8; ++kk)
        bb[kk] = *(const bf16x8*)(gb + kk * 1024 + l * 16);
      f32x4 ac0 = {0.f, 0.f, 0.f, 0.f}, ac1 = {0.f, 0.f, 0.f, 0.f};
#pragma unroll
      for (int kk = 0; kk < 4; ++kk) {
        ac0 = __builtin_amdgcn_mfma_f32_16x16x32_bf16(bb[2 * kk], a[2 * kk],
                                                      ac0, 0, 0, 0);
        ac1 = __builtin_amdgcn_mfma_f32_16x16x32_bf16(bb[2 * kk + 1],
                                                      a[2 * kk + 1], ac1,
                                                      0, 0, 0);
      }
#pragma unroll
      for (int rr = 0; rr < 4; ++rr) {
        int pi = gl * 16 + kg * 4 + rr;
        int p = p0 + pi;
        bool ok = p < NPATCH;
        float key = ok ? fmaf(-2.f, ac0[rr] + ac1[rr], pn_lds[pi]) : INFINITY;
        tk_insert_nb<SL4>(lv, li, key, ok ? p : 0x7fffffff);
      }
    }
    __syncthreads();  // vmcnt0: stage(t+1) landed; buffers swap race-free
  }

  // in-wave merge: lanes {l, l^16, l^32, l^48} share col -> merge 4 lists.
  float v9[KPS4]; int i9[KPS4];
#pragma unroll
  for (int j = 0; j < KPS4; ++j) {
    v9[j] = (j < SL4) ? lv[j] : INFINITY;
    i9[j] = (j < SL4) ? li[j] : 0x7fffffff;
  }
#pragma unroll
  for (int j = 0; j < SL4; ++j) {  // round 1: partner's original lv (xor 16)
    float rv = __shfl_xor(lv[j], 16);
    int ri = __shfl_xor(li[j], 16);
    tk_insert_nb<KPS4>(v9, i9, rv, ri);
  }
  {  // round 2: snapshot then exchange merged lists (xor 32)
    float tv[KPS4]; int ti[KPS4];
#pragma unroll
    for (int j = 0; j < KPS4; ++j) { tv[j] = v9[j]; ti[j] = i9[j]; }
#pragma unroll
    for (int j = 0; j < KPS4; ++j) {
      float rv = __shfl_xor(tv[j], 32);
      int ri = __shfl_xor(ti[j], 32);
      tk_insert_nb<KPS4>(v9, i9, rv, ri);
    }
  }
  if (kg == 0) {
    int lab = lab0 + col;
    size_t base = ((size_t)lab * NCH4 + chunk) * KPS4;
#pragma unroll
    for (int j = 0; j < KPS4; ++j) { part_s[base + j] = v9[j]; part_i[base + j] = i9[j]; }
  }
}

// ---------------- kernel: merge + EXACT np-f32 re-rank + max-agg ------------
// funnel 64x12 -> 8x16 -> all 128 candidates re-ranked exactly in parallel.

__global__ void k_merge_mfma(const float* __restrict__ part_s,
                             const int* __restrict__ part_i,
                             const float* __restrict__ patch,
                             const float* __restrict__ lbl,
                             const float* __restrict__ pnorm,
                             const float* __restrict__ lnorm,
                             float* __restrict__ ctx) {
  const int lab = blockIdx.x;
  const int tid = threadIdx.x;
  __shared__ float lsh[CDIM];
  __shared__ float sv[64 * 12];
  __shared__ int   si[64 * 12];
  __shared__ float mv[128];
  __shared__ int   mi[128];
  __shared__ float ckey[128];
  __shared__ int   nb[KTOP];

  lsh[tid] = lbl[(size_t)lab * CDIM + tid];
  const int total = NCH4 * KPS4;  // 909
  if (tid < 64) {
    float v[12]; int ii[12];
#pragma unroll
    for (int j = 0; j < 12; ++j) { v[j] = INFINITY; ii[j] = 0x7fffffff; }
    for (int e = tid; e < total; e += 64)
      tk_insert<12>(v, ii, part_s[(size_t)lab * total + e],
                    part_i[(size_t)lab * total + e]);
#pragma unroll
    for (int j = 0; j < 12; ++j) { sv[tid * 12 + j] = v[j]; si[tid * 12 + j] = ii[j]; }
  }
  __syncthreads();
  if (tid < 8) {
    float v[16]; int ii[16];
#pragma unroll
    for (int j = 0; j < 16; ++j) { v[j] = INFINITY; ii[j] = 0x7fffffff; }
    for (int e = 0; e < 8 * 12; ++e)
      tk_insert<16>(v, ii, sv[tid * 96 + e], si[tid * 96 + e]);
#pragma unroll
    for (int j = 0; j < 16; ++j) { mv[tid * 16 + j] = v[j]; mi[tid * 16 + j] = ii[j]; }
  }
  __syncthreads();
  if (tid < 128) {
    int c = mi[tid];
    float key = INFINITY;
    if (c != 0x7fffffff) {
      const float* prow = &patch[(size_t)c * CDIM];
      float dot = 0.f;
      for (int k = 0; k < CDIM; ++k) dot = fmaf(lsh[k], prow[k], dot);
      key = np_key(lnorm[lab], dot, pnorm[c]);
    }
    ckey[tid] = key;
  }
  __syncthreads();
  if (tid == 0) {
    for (int t = 0; t < KTOP; ++t) {
      float best = INFINITY; int bj = 0, bidx = 0x7fffffff;
      for (int j = 0; j < 128; ++j) {
        if (ckey[j] < best || (ckey[j] == best && mi[j] < bidx)) {
          best = ckey[j]; bj = j; bidx = mi[j];
        }
      }
      nb[t] = mi[bj];
      ckey[bj] = INFINITY;
    }
  }
  __syncthreads();
  float mx = -INFINITY;
#pragma unroll
  for (int j = 0; j < KTOP; ++j)
    mx = fmaxf(mx, patch[(size_t)nb[j] * CDIM + tid]);
  ctx[(size_t)lab * CDIM + tid] = mx - lsh[tid];
}

// ---------------- FALLBACK: R4 f32 screen + merge (known-green) -------------

__global__ void k_norms_np(const float* __restrict__ m, int n,
                           float* __restrict__ out) {
  int i = blockIdx.x * blockDim.x + threadIdx.x;
  int stride = gridDim.x * blockDim.x;
  for (; i < n; i += stride) out[i] = np_sq256(m + (size_t)i * CDIM);
}

__global__ void k_screen_f32(const float* __restrict__ lbl,
                             const float* __restrict__ patch,
                             const float* __restrict__ pnorm,
                             const float* __restrict__ lnorm,
                             float* __restrict__ part_s,
                             int* __restrict__ part_i) {
  __shared__ float Asm[KC][BLK];
  __shared__ float Bsm[KC][BLK];
  __shared__ float sc[BLK][BLK + 1];
  const int tid = threadIdx.x;
  const int tr = tid >> 4, tc = tid & 15;
  const int lbase = blockIdx.y * BLK;
  const int chunk = blockIdx.x;
  const int p0 = chunk * CHUNK;
  const int p1 = (p0 + CHUNK < NPATCH) ? p0 + CHUNK : NPATCH;

  float tv[KP]; int ti[KP];
#pragma unroll
  for (int j = 0; j < KP; ++j) { tv[j] = INFINITY; ti[j] = 0x7fffffff; }
  const float ln = (tid < BLK) ? lnorm[lbase + tid] : 0.f;

  const int sl = tid >> 2;
  const int skq = (tid & 3) * 4;

  for (int pt = p0; pt < p1; pt += BLK) {
    float acc[4][4];
#pragma unroll
    for (int a = 0; a < 4; ++a)
#pragma unroll
      for (int b = 0; b < 4; ++b) acc[a][b] = 0.f;

    for (int kc = 0; kc < CDIM; kc += KC) {
      __syncthreads();
      {
        const float* arow = &lbl[(size_t)(lbase + sl) * CDIM + kc];
        float4 va0 = *(const float4*)(arow + skq);
        float4 va1 = *(const float4*)(arow + 16 + skq);
        Asm[skq + 0][sl] = va0.x; Asm[skq + 1][sl] = va0.y;
        Asm[skq + 2][sl] = va0.z; Asm[skq + 3][sl] = va0.w;
        Asm[16 + skq + 0][sl] = va1.x; Asm[16 + skq + 1][sl] = va1.y;
        Asm[16 + skq + 2][sl] = va1.z; Asm[16 + skq + 3][sl] = va1.w;
        int p = pt + sl;
        float4 vb0 = make_float4(0.f, 0.f, 0.f, 0.f), vb1 = vb0;
        if (p < p1) {
          const float* brow = &patch[(size_t)p * CDIM + kc];
          vb0 = *(const float4*)(brow + skq);
          vb1 = *(const float4*)(brow + 16 + skq);
        }
        Bsm[skq + 0][sl] = vb0.x; Bsm[skq + 1][sl] = vb0.y;
        Bsm[skq + 2][sl] = vb0.z; Bsm[skq + 3][sl] = vb0.w;
        Bsm[16 + skq + 0][sl] = vb1.x; Bsm[16 + skq + 1][sl] = vb1.y;
        Bsm[16 + skq + 2][sl] = vb1.z; Bsm[16 + skq + 3][sl] = vb1.w;
      }
      __syncthreads();
#pragma unroll
      for (int k = 0; k < KC; ++k) {
        float4 a4 = *(const float4*)&Asm[k][tr * 4];
        float4 b4 = *(const float4*)&Bsm[k][tc * 4];
        const float av[4] = {a4.x, a4.y, a4.z, a4.w};
        const float bv[4] = {b4.x, b4.y, b4.z, b4.w};
#pragma unroll
        for (int a = 0; a < 4; ++a)
#pragma unroll
          for (int b = 0; b < 4; ++b) acc[a][b] = fmaf(av[a], bv[b], acc[a][b]);
      }
    }
#pragma unroll
    for (int a = 0; a < 4; ++a)
#pragma unroll
      for (int b = 0; b < 4; ++b) sc[tr * 4 + a][tc * 4 + b] = acc[a][b];
    __syncthreads();
    if (tid < BLK) {
      for (int c = 0; c < BLK; ++c) {
        int p = pt + c;
        if (p < p1) tk_insert<KP>(tv, ti, np_key(ln, sc[tid][c], pnorm[p]), p);
      }
    }
  }

  if (tid < BLK) {
    int lab = lbase + tid;
    size_t base = ((size_t)lab * NCHUNK + chunk) * KP;
#pragma unroll
    for (int j = 0; j < KP; ++j) { part_s[base + j] = tv[j]; part_i[base + j] = ti[j]; }
  }
}

__global__ void k_merge_f32(const float* __restrict__ part_s,
                            const int* __restrict__ part_i,
                            const float* __restrict__ patch,
                            const float* __restrict__ lbl,
                            float* __restrict__ ctx) {
  const int lab = blockIdx.x;
  const int tid = threadIdx.x;
  __shared__ float cv[16][KP];
  __shared__ int ci[16][KP];
  __shared__ int nb[KTOP];

  const int total = NCHUNK * KP;
  if (tid < 16) {
    float v[KP]; int ii[KP];
#pragma unroll
    for (int j = 0; j < KP; ++j) { v[j] = INFINITY; ii[j] = 0x7fffffff; }
    for (int e = tid; e < total; e += 16)
      tk_insert<KP>(v, ii, part_s[(size_t)lab * total + e],
                    part_i[(size_t)lab * total + e]);
#pragma unroll
    for (int j = 0; j < KP; ++j) { cv[tid][j] = v[j]; ci[tid][j] = ii[j]; }
  }
  __syncthreads();
  if (tid == 0) {
    float v[KP]; int ii[KP];
#pragma unroll
    for (int j = 0; j < KP; ++j) { v[j] = INFINITY; ii[j] = 0x7fffffff; }
    for (int t = 0; t < 16; ++t)
      for (int j = 0; j < KP; ++j) tk_insert<KP>(v, ii, cv[t][j], ci[t][j]);
#pragma unroll
    for (int j = 0; j < KTOP; ++j) nb[j] = ii[j];
  }
  __syncthreads();
  float l = lbl[(size_t)lab * CDIM + tid];
  float mx = -INFINITY;
#pragma unroll
  for (int j = 0; j < KTOP; ++j)
    mx = fmaxf(mx, patch[(size_t)nb[j] * CDIM + tid]);
  ctx[(size_t)lab * CDIM + tid] = mx - l;
}

// ---------------- kernel: small label->label agg (np-f32 semantics) ---------

__global__ void k_small_agg(const float* __restrict__ lbl_rows,
                            const float* __restrict__ tgt, int M, int k,
                            float* __restrict__ ctx) {
  const int row = blockIdx.x;
  const int tid = threadIdx.x;
  __shared__ float lsh[CDIM];
  __shared__ float skey[256];
  __shared__ float lns;
  __shared__ int nb[4];
  lsh[tid] = lbl_rows[(size_t)row * CDIM + tid];
  __syncthreads();
  if (tid == 0) lns = np_sq256(lsh);
  __syncthreads();
  float key = INFINITY;
  if (tid < M) {
    const float* trow = &tgt[(size_t)tid * CDIM];
    float tn = np_sq256(trow);
    float dot = 0.f;
    for (int c = 0; c < CDIM; ++c) dot = fmaf(lsh[c], trow[c], dot);
    key = np_key(lns, dot, tn);
  }
  skey[tid] = key;
  __syncthreads();
  if (tid == 0) {
    for (int t = 0; t < k; ++t) {
      float best = INFINITY; int bi = 0;
      for (int j = 0; j < M; ++j)
        if (skey[j] < best) { best = skey[j]; bi = j; }
      nb[t] = bi; skey[bi] = INFINITY;
    }
  }
  __syncthreads();
  float mx = -INFINITY;
  for (int t = 0; t < k; ++t) mx = fmaxf(mx, tgt[(size_t)nb[t] * CDIM + tid]);
  ctx[(size_t)row * CDIM + tid] = mx - lsh[tid];
}

// ---------------- kernel: linear(concat) + residual + LayerNorm (f64) -------

__device__ __forceinline__ double block_sum_256d(double x, double* red) {
#pragma unroll
  for (int m = 32; m >= 1; m >>= 1) x += __shfl_xor(x, m);
  int wid = threadIdx.x >> 6, lane = threadIdx.x & 63;
  if (lane == 0) red[wid] = x;
  __syncthreads();
  double s = red[0] + red[1] + red[2] + red[3];
  __syncthreads();
  return s;
}

__global__ void k_level_out(const float* __restrict__ emb,
                            const float* __restrict__ c1,
                            const float* __restrict__ c2,
                            const float* __restrict__ c3, int nseg,
                            const float* __restrict__ W,
                            const float* __restrict__ bias,
                            const float* __restrict__ gamma,
                            const float* __restrict__ beta,
                            float* __restrict__ out) {
  __shared__ float xs[4 * CDIM];
  __shared__ double red[4];
  const int row = blockIdx.x, ch = threadIdx.x;
  float e = emb[(size_t)row * CDIM + ch];
  xs[ch] = e;
  if (nseg > 1) xs[CDIM + ch] = c1[(size_t)row * CDIM + ch];
  if (nseg > 2) xs[2 * CDIM + ch] = c2[(size_t)row * CDIM + ch];
  if (nseg > 3) xs[3 * CDIM + ch] = c3[(size_t)row * CDIM + ch];
  __syncthreads();
  const int F = nseg * CDIM;
  double y = (double)e + (double)bias[ch];
#pragma unroll 4
  for (int j = 0; j < F; ++j)
    y += (double)xs[j] * (double)W[(size_t)j * CDIM + ch];
  double mu = block_sum_256d(y, red) * (1.0 / 256.0);
  double d = y - mu;
  double var = block_sum_256d(d * d, red) * (1.0 / 256.0);
  out[(size_t)row * CDIM + ch] =
      (float)(d / sqrt(var + 1e-5) * (double)gamma[ch] + (double)beta[ch]);
}

// ---------------- launch ----------------------------------------------------

static void launch_tail(const float* mood_emb, const float* genre_emb,
                        const float* sub_emb, const float* Wm_w, const float* Wm_b,
                        const float* Wg_w, const float* Wg_b, const float* Ws_w,
                        const float* Ws_b, const float* lnm_g, const float* lnm_b,
                        const float* lng_g, const float* lng_b, const float* lns_g,
                        const float* lns_b, const float* ctx_all, float* ctx_gm,
                        float* ctx_sm, float* ctx_sg, float* out,
                        hipStream_t stream) {
  k_level_out<<<NMOOD, 256, 0, stream>>>(mood_emb, ctx_all, nullptr, nullptr, 2,
                                         Wm_w, Wm_b, lnm_g, lnm_b, out);
  k_small_agg<<<NGENRE, 256, 0, stream>>>(genre_emb, out, NMOOD, 4, ctx_gm);
  k_level_out<<<NGENRE, 256, 0, stream>>>(genre_emb, ctx_all + NMOOD * CDIM, ctx_gm,
                                          nullptr, 3, Wg_w, Wg_b, lng_g, lng_b,
                                          out + NMOOD * CDIM);
  k_small_agg<<<NSUB, 256, 0, stream>>>(sub_emb, out, NMOOD, 3, ctx_sm);
  k_small_agg<<<NSUB, 256, 0, stream>>>(sub_emb, out + NMOOD * CDIM, NGENRE, 4, ctx_sg);
  k_level_out<<<NSUB, 256, 0, stream>>>(sub_emb, ctx_all + (NMOOD + NGENRE) * CDIM,
                                        ctx_sm, ctx_sg, 4, Ws_w, Ws_b, lns_g, lns_b,
                                        out + NMOOD * CDIM + NGENRE * CDIM);
}

extern "C" void kernel_launch(void* const* d_in, const int* in_sizes, int n_in,
                              void* d_out, int out_size, void* d_ws, size_t ws_size,
                              hipStream_t stream) {
  const float* patch     = (const float*)d_in[0];
  const float* mood_emb  = (const float*)d_in[1];
  const float* genre_emb = (const float*)d_in[2];
  const float* sub_emb   = (const float*)d_in[3];
  const float* Wm_w = (const float*)d_in[4];
  const float* Wm_b = (const float*)d_in[5];
  const float* Wg_w = (const float*)d_in[6];
  const float* Wg_b = (const float*)d_in[7];
  const float* Ws_w = (const float*)d_in[8];
  const float* Ws_b = (const float*)d_in[9];
  const float* lnm_g = (const float*)d_in[10];
  const float* lnm_b = (const float*)d_in[11];
  const float* lng_g = (const float*)d_in[12];
  const float* lng_b = (const float*)d_in[13];
  const float* lns_g = (const float*)d_in[14];
  const float* lns_b = (const float*)d_in[15];
  float* out = (float*)d_out;
  float* ws = (float*)d_ws;

  const size_t REQ = 15274112ull * 4ull;  // ~61.1 MB (< R9's proven 61.8)

  if (ws_size >= REQ) {
    // ---- MFMA path layout ----
    float* lbl     = ws;                     // 212992
    float* pnorm   = lbl + NLBL * CDIM;      // 100352
    float* lnorm   = pnorm + 100352;         // 1024
    float* ctx_all = lnorm + 1024;           // 212992
    float* ctx_gm  = ctx_all + NLBL * CDIM;  // 65536
    float* ctx_sm  = ctx_gm + NGENRE * CDIM; // 131072
    float* ctx_sg  = ctx_sm + NSUB * CDIM;   // 131072
    float* part_s  = ctx_sg + NSUB * CDIM;   // 832*101*9 = 756288
    int*   part_i  = (int*)(part_s + (size_t)NLBL * NCH4 * KPS4);
    unsigned short* packed = (unsigned short*)(part_i + (size_t)NLBL * NCH4 * KPS4);
    unsigned short* lblbf  = packed + (size_t)NPATCH * CDIM;

    k_concat_labels<<<NLBL, 256, 0, stream>>>(mood_emb, genre_emb, sub_emb, lbl);
    k_norms_wave<<<512, 256, 0, stream>>>(patch, NPATCH, pnorm);
    k_norms_wave<<<16, 256, 0, stream>>>(lbl, NLBL, lnorm);
    k_tobf16<<<128, 256, 0, stream>>>(lbl, (size_t)NLBL * CDIM / 8, lblbf);
    k_pack<<<1024, 256, 0, stream>>>(patch, packed);
    k_screen_mfma<<<13 * NCH4, 256, 0, stream>>>(lblbf, packed, pnorm,
                                                 part_s, part_i);
    k_merge_mfma<<<NLBL, 256, 0, stream>>>(part_s, part_i, patch, lbl, pnorm,
                                           lnorm, ctx_all);
    launch_tail(mood_emb, genre_emb, sub_emb, Wm_w, Wm_b, Wg_w, Wg_b, Ws_w, Ws_b,
                lnm_g, lnm_b, lng_g, lng_b, lns_g, lns_b, ctx_all, ctx_gm, ctx_sm,
                ctx_sg, out, stream);
  } else {
    // ---- R4 fallback layout (known to fit) ----
    float* lbl    = ws;
    float* pnorm  = lbl + NLBL * CDIM;
    float* lnorm  = pnorm + 100352;
    float* part_s = lnorm + 1024;
    int*   part_i = (int*)(part_s + NLBL * NCHUNK * KP);
    float* ctx_all = part_s + 2 * NLBL * NCHUNK * KP;
    float* ctx_gm  = ctx_all + NLBL * CDIM;
    float* ctx_sm  = ctx_gm + NGENRE * CDIM;
    float* ctx_sg  = ctx_sm + NSUB * CDIM;

    k_concat_labels<<<NLBL, 256, 0, stream>>>(mood_emb, genre_emb, sub_emb, lbl);
    k_norms_np<<<512, 256, 0, stream>>>(patch, NPATCH, pnorm);
    k_norms_np<<<4, 256, 0, stream>>>(lbl, NLBL, lnorm);
    dim3 gscr(NCHUNK, NLBL / BLK);
    k_screen_f32<<<gscr, 256, 0, stream>>>(lbl, patch, pnorm, lnorm, part_s, part_i);
    k_merge_f32<<<NLBL, 256, 0, stream>>>(part_s, part_i, patch, lbl, ctx_all);
    launch_tail(mood_emb, genre_emb, sub_emb, Wm_w, Wm_b, Wg_w, Wg_b, Ws_w, Ws_b,
                lnm_g, lnm_b, lng_g, lng_b, lns_g, lns_b, ctx_all, ctx_gm, ctx_sm,
                ctx_sg, out, stream);
  }
}

// Round 11
// 611.920 us; speedup vs baseline: 3.7045x; 1.4609x over previous
//
#include <hip/hip_runtime.h>
#include <math.h>

#define NPATCH 100000
#define CDIM   256
#define NMOOD  64
#define NGENRE 256
#define NSUB   512
#define NLBL   832          // 64+256+512
#define KTOP   9
#define NGRPTOT 6250        // NPATCH/16

// ---- f32 fallback screen constants (R4, known-green) ----
#define NCHUNK 39
#define CHUNK  2624
#define BLK    64
#define KC     32
#define KP     12

// ---- MFMA screen constants ----
#define PBLK4  992          // patches per chunk (62 groups)
#define NCH4   101          // 101*992 = 100192 >= 100000
#define SL4    4            // per-lane list depth
#define KPS4   9            // per-(label,chunk) stored candidates

typedef __attribute__((ext_vector_type(8))) short bf16x8;
typedef __attribute__((ext_vector_type(8))) unsigned short u16x8;
typedef __attribute__((ext_vector_type(4))) float f32x4;

// ---------------- serial top-k insert (ascending by (val,idx)) --------------

template <int K>
__device__ __forceinline__ void tk_insert(float (&v)[K], int (&ii)[K],
                                          float s, int idx) {
  if (s < v[K - 1] || (s == v[K - 1] && idx < ii[K - 1])) {
    v[K - 1] = s; ii[K - 1] = idx;
#pragma unroll
    for (int t = K - 1; t > 0; --t) {
      bool sw = (v[t] < v[t - 1]) || (v[t] == v[t - 1] && ii[t] < ii[t - 1]);
      if (sw) {
        float fv = v[t]; v[t] = v[t - 1]; v[t - 1] = fv;
        int fi = ii[t]; ii[t] = ii[t - 1]; ii[t - 1] = fi;
      }
    }
  }
}

// fast screen insert: branch-free, NO idx tie-break (screen keys are
// approximate; inserts processed in ascending idx so equal keys keep the
// lower idx; exact re-rank downstream finalizes ordering). Strict < means
// INFINITY sentinels never insert.

template <int K>
__device__ __forceinline__ void tk_fast(float (&v)[K], int (&ii)[K],
                                        float s, int idx) {
  bool ins = s < v[K - 1];
  v[K - 1] = ins ? s : v[K - 1];
  ii[K - 1] = ins ? idx : ii[K - 1];
#pragma unroll
  for (int t = K - 1; t > 0; --t) {
    bool sw = v[t] < v[t - 1];
    float a0 = sw ? v[t] : v[t - 1];
    float a1 = sw ? v[t - 1] : v[t];
    int b0 = sw ? ii[t] : ii[t - 1];
    int b1 = sw ? ii[t - 1] : ii[t];
    v[t - 1] = a0; v[t] = a1; ii[t - 1] = b0; ii[t] = b1;
  }
}

// ------ numpy-pairwise sum of squares over 256 contiguous floats ------------

__device__ float np_sq256(const float* a) {
  float b0, b1;
  {
    float r[8];
#pragma unroll
    for (int i = 0; i < 8; ++i) { float x = a[i]; r[i] = __fmul_rn(x, x); }
    for (int j = 8; j < 128; j += 8)
#pragma unroll
      for (int i = 0; i < 8; ++i) {
        float x = a[j + i];
        r[i] = __fadd_rn(r[i], __fmul_rn(x, x));
      }
    b0 = __fadd_rn(__fadd_rn(__fadd_rn(r[0], r[1]), __fadd_rn(r[2], r[3])),
                   __fadd_rn(__fadd_rn(r[4], r[5]), __fadd_rn(r[6], r[7])));
  }
  {
    float r[8];
#pragma unroll
    for (int i = 0; i < 8; ++i) { float x = a[128 + i]; r[i] = __fmul_rn(x, x); }
    for (int j = 8; j < 128; j += 8)
#pragma unroll
      for (int i = 0; i < 8; ++i) {
        float x = a[128 + j + i];
        r[i] = __fadd_rn(r[i], __fmul_rn(x, x));
      }
    b1 = __fadd_rn(__fadd_rn(__fadd_rn(r[0], r[1]), __fadd_rn(r[2], r[3])),
                   __fadd_rn(__fadd_rn(r[4], r[5]), __fadd_rn(r[6], r[7])));
  }
  return __fadd_rn(b0, b1);
}

__device__ __forceinline__ float np_key(float ln, float dot, float pn) {
  return __fadd_rn(__fsub_rn(ln, __fmul_rn(2.f, dot)), pn);
}

// ---------------- kernel: concat labels into one (832,256) matrix -----------

__global__ void k_concat_labels(const float* __restrict__ mood,
                                const float* __restrict__ genre,
                                const float* __restrict__ sub,
                                float* __restrict__ lbl) {
  int i = blockIdx.x * 256 + threadIdx.x;
  if (i < NMOOD * CDIM) lbl[i] = mood[i];
  else if (i < (NMOOD + NGENRE) * CDIM) lbl[i] = genre[i - NMOOD * CDIM];
  else lbl[i] = sub[i - (NMOOD + NGENRE) * CDIM];
}

// ---------------- kernel: wave-parallel numpy-pairwise row norms ------------

__global__ void k_norms_wave(const float* __restrict__ m, int n,
                             float* __restrict__ out) {
  int gw = (blockIdx.x * blockDim.x + threadIdx.x) >> 6;
  int lane = threadIdx.x & 63;
  int rsub = lane >> 3, i = lane & 7;
  int nw = (gridDim.x * blockDim.x) >> 6;
  for (int row0 = gw * 8; row0 < n; row0 += nw * 8) {
    int row = row0 + rsub;
    const float* a = m + (size_t)row * CDIM;
    float b[2];
#pragma unroll
    for (int blk = 0; blk < 2; ++blk) {
      const float* ab = a + blk * 128;
      float x = ab[i];
      float r = __fmul_rn(x, x);
      for (int j = 1; j < 16; ++j) {
        float y = ab[j * 8 + i];
        r = __fadd_rn(r, __fmul_rn(y, y));
      }
      float t = __fadd_rn(r, __shfl_xor(r, 1));
      t = __fadd_rn(t, __shfl_xor(t, 2));
      t = __fadd_rn(t, __shfl_xor(t, 4));
      b[blk] = t;
    }
    if (i == 0) out[row] = __fadd_rn(b[0], b[1]);
  }
}

// ---------------- kernel: f32 -> bf16 (RNE) row-major (labels) --------------

__device__ __forceinline__ unsigned short f2bf(float x) {
  unsigned u = __float_as_uint(x);
  return (unsigned short)((u + 0x7fffu + ((u >> 16) & 1u)) >> 16);
}

__global__ void k_tobf16(const float* __restrict__ src, size_t n8,
                         unsigned short* __restrict__ dst) {
  size_t i = (size_t)blockIdx.x * blockDim.x + threadIdx.x;
  size_t stride = (size_t)gridDim.x * blockDim.x;
  for (; i < n8; i += stride) {
    const float4* s = (const float4*)(src + i * 8);
    float4 x = s[0], y = s[1];
    u16x8 o;
    o[0] = f2bf(x.x); o[1] = f2bf(x.y); o[2] = f2bf(x.z); o[3] = f2bf(x.w);
    o[4] = f2bf(y.x); o[5] = f2bf(y.y); o[6] = f2bf(y.z); o[7] = f2bf(y.w);
    *(u16x8*)(dst + i * 8) = o;
  }
}

// ---------------- kernel: pack patches into MFMA B-fragment order -----------

__global__ void k_pack(const float* __restrict__ src,
                       unsigned short* __restrict__ packed) {
  int gw = (blockIdx.x * blockDim.x + threadIdx.x) >> 6;
  int l = threadIdx.x & 63;
  int col = l & 15, kg = l >> 4;
  int nw = (gridDim.x * blockDim.x) >> 6;
  for (int gg = gw; gg < NGRPTOT; gg += nw) {
    const float* base = src + ((size_t)gg * 16 + col) * CDIM + kg * 8;
#pragma unroll
    for (int kk = 0; kk < 8; ++kk) {
      float4 v0 = *(const float4*)(base + kk * 32);
      float4 v1 = *(const float4*)(base + kk * 32 + 4);
      u16x8 o;
      o[0] = f2bf(v0.x); o[1] = f2bf(v0.y); o[2] = f2bf(v0.z); o[3] = f2bf(v0.w);
      o[4] = f2bf(v1.x); o[5] = f2bf(v1.y); o[6] = f2bf(v1.z); o[7] = f2bf(v1.w);
      *(u16x8*)&packed[((size_t)gg * 8 + kk) * 512 + l * 8] = o;
    }
  }
}

// ---------------- async global->LDS helper ----------------------------------

__device__ __forceinline__ void gload_lds16(const void* g, void* l) {
  __builtin_amdgcn_global_load_lds(
      (const __attribute__((address_space(1))) unsigned int*)g,
      (__attribute__((address_space(3))) unsigned int*)l, 16, 0, 0);
}

// ---------------- kernel: MFMA bf16 screen (1-group pipeline, high occ) -----
// 1313 blocks (13 lgroups x 101 chunks). Block = 4 waves; wave owns 16 labels
// (A in regs). One 8 KB group staged per phase via global_load_lds (LINEAR
// src+dst), double-buffered, stage(g+1) issued BEFORE compute(g), one barrier
// per group. LDS ~20 KB -> ~8 blocks/CU. Inserts: no tie-break (ascending-idx
// processing keeps lower idx on ties) + batched min4 pre-test. pn_lds=INF
// sentinel makes the partial chunk take the same branchless path. Keys
// approximate (bf16); selection finalized by exact np-f32 re-rank.

__global__ __launch_bounds__(256) void k_screen_mfma(
    const unsigned short* __restrict__ lblbf,
    const unsigned short* __restrict__ packed,
    const float* __restrict__ pnorm,
    float* __restrict__ part_s, int* __restrict__ part_i) {
  __shared__ float pn_lds[PBLK4];                  // 3.97 KB
  __shared__ __align__(16) char smem[2][8192];     // 16 KB
  const int tid = threadIdx.x;
  const int w = tid >> 6, l = tid & 63;
  const int col = l & 15, kg = l >> 4;
  const int lgrp = blockIdx.x % 13;
  const int chunk = blockIdx.x / 13;
  const int lab0 = lgrp * 64 + w * 16;
  const int p0 = chunk * PBLK4;
  const int grp0 = p0 >> 4;
  const int ngrp = min(PBLK4 / 16, (NPATCH - p0 + 15) >> 4);

  for (int e = tid; e < PBLK4; e += 256) {
    int p = p0 + e;
    pn_lds[e] = (p < NPATCH) ? pnorm[p] : INFINITY;  // INF -> key INF -> no insert
  }

  bf16x8 a[8];
#pragma unroll
  for (int kk = 0; kk < 8; ++kk)
    a[kk] = *(const bf16x8*)&lblbf[(size_t)(lab0 + col) * CDIM + kk * 32 + kg * 8];

  float lv[SL4]; int li[SL4];
#pragma unroll
  for (int j = 0; j < SL4; ++j) { lv[j] = INFINITY; li[j] = 0x7fffffff; }

  auto stage = [&](int buf, int g) {
    int gg = grp0 + g;
    if (gg > NGRPTOT - 1) gg = NGRPTOT - 1;
    const char* gsrc = (const char*)packed + (size_t)gg * 8192;
    gload_lds16(gsrc + tid * 16, &smem[buf][tid * 16]);
    gload_lds16(gsrc + (tid + 256) * 16, &smem[buf][(tid + 256) * 16]);
  };

  stage(0, 0);
  __syncthreads();  // tile0 DMA + pn_lds ready
  for (int g = 0; g < ngrp; ++g) {
    const int cb = g & 1;
    if (g + 1 < ngrp) stage(cb ^ 1, g + 1);  // issue BEFORE compute
    const char* gb = smem[cb];
    bf16x8 bb[8];
#pragma unroll
    for (int kk = 0; kk < 8; ++kk)
      bb[kk] = *(const bf16x8*)(gb + kk * 1024 + l * 16);
    f32x4 ac0 = {0.f, 0.f, 0.f, 0.f}, ac1 = {0.f, 0.f, 0.f, 0.f};
#pragma unroll
    for (int kk = 0; kk < 4; ++kk) {
      ac0 = __builtin_amdgcn_mfma_f32_16x16x32_bf16(bb[2 * kk], a[2 * kk],
                                                    ac0, 0, 0, 0);
      ac1 = __builtin_amdgcn_mfma_f32_16x16x32_bf16(bb[2 * kk + 1],
                                                    a[2 * kk + 1], ac1,
                                                    0, 0, 0);
    }
    const int pib = g * 16 + kg * 4;
    float k0 = fmaf(-2.f, ac0[0] + ac1[0], pn_lds[pib + 0]);
    float k1 = fmaf(-2.f, ac0[1] + ac1[1], pn_lds[pib + 1]);
    float k2 = fmaf(-2.f, ac0[2] + ac1[2], pn_lds[pib + 2]);
    float k3 = fmaf(-2.f, ac0[3] + ac1[3], pn_lds[pib + 3]);
    if (fminf(fminf(k0, k1), fminf(k2, k3)) < lv[SL4 - 1]) {
      tk_fast<SL4>(lv, li, k0, p0 + pib + 0);
      tk_fast<SL4>(lv, li, k1, p0 + pib + 1);
      tk_fast<SL4>(lv, li, k2, p0 + pib + 2);
      tk_fast<SL4>(lv, li, k3, p0 + pib + 3);
    }
    __syncthreads();  // waves done with smem[cb]; stage(g+1) DMA drained
  }

  // in-wave merge: lanes {l, l^16, l^32, l^48} share col -> merge 4 lists.
  float v9[KPS4]; int i9[KPS4];
#pragma unroll
  for (int j = 0; j < KPS4; ++j) {
    v9[j] = (j < SL4) ? lv[j] : INFINITY;
    i9[j] = (j < SL4) ? li[j] : 0x7fffffff;
  }
#pragma unroll
  for (int j = 0; j < SL4; ++j) {  // round 1: partner's original lv (xor 16)
    float rv = __shfl_xor(lv[j], 16);
    int ri = __shfl_xor(li[j], 16);
    tk_fast<KPS4>(v9, i9, rv, ri);
  }
  {  // round 2: snapshot then exchange merged lists (xor 32)
    float tv[KPS4]; int ti[KPS4];
#pragma unroll
    for (int j = 0; j < KPS4; ++j) { tv[j] = v9[j]; ti[j] = i9[j]; }
#pragma unroll
    for (int j = 0; j < KPS4; ++j) {
      float rv = __shfl_xor(tv[j], 32);
      int ri = __shfl_xor(ti[j], 32);
      tk_fast<KPS4>(v9, i9, rv, ri);
    }
  }
  if (kg == 0) {
    int lab = lab0 + col;
    size_t base = ((size_t)lab * NCH4 + chunk) * KPS4;
#pragma unroll
    for (int j = 0; j < KPS4; ++j) { part_s[base + j] = v9[j]; part_i[base + j] = i9[j]; }
  }
}

// ---------------- kernel: merge + EXACT np-f32 re-rank + max-agg ------------
// funnel 64x12 -> 32x8 = 256 candidates, exact np-f32 keys in parallel, then
// PARALLEL rank computation (lexicographic (key,idx) — identical order to a
// strict-< serial scan). All candidates distinct (one chunk each), so ranks
// are unique; rank<9 writes nb[rank].

__global__ void k_merge_mfma(const float* __restrict__ part_s,
                             const int* __restrict__ part_i,
                             const float* __restrict__ patch,
                             const float* __restrict__ lbl,
                             const float* __restrict__ pnorm,
                             const float* __restrict__ lnorm,
                             float* __restrict__ ctx) {
  const int lab = blockIdx.x;
  const int tid = threadIdx.x;
  __shared__ float lsh[CDIM];
  __shared__ float sv[64 * 12];
  __shared__ int   si[64 * 12];
  __shared__ int   cidx[256];
  __shared__ float ckey[256];
  __shared__ int   nb[KTOP];

  lsh[tid] = lbl[(size_t)lab * CDIM + tid];
  const int total = NCH4 * KPS4;  // 909
  if (tid < 64) {
    float v[12]; int ii[12];
#pragma unroll
    for (int j = 0; j < 12; ++j) { v[j] = INFINITY; ii[j] = 0x7fffffff; }
    for (int e = tid; e < total; e += 64)
      tk_insert<12>(v, ii, part_s[(size_t)lab * total + e],
                    part_i[(size_t)lab * total + e]);
#pragma unroll
    for (int j = 0; j < 12; ++j) { sv[tid * 12 + j] = v[j]; si[tid * 12 + j] = ii[j]; }
  }
  __syncthreads();
  if (tid < 32) {
    float v[8]; int ii[8];
#pragma unroll
    for (int j = 0; j < 8; ++j) { v[j] = INFINITY; ii[j] = 0x7fffffff; }
    for (int e = 0; e < 24; ++e)
      tk_insert<8>(v, ii, sv[tid * 24 + e], si[tid * 24 + e]);
#pragma unroll
    for (int j = 0; j < 8; ++j) cidx[tid * 8 + j] = ii[j];
  }
  __syncthreads();
  // exact np-f32 key per candidate (sequential fmaf chain, BLAS k-order)
  {
    int c = cidx[tid];
    float key = INFINITY;
    if (c != 0x7fffffff) {
      const float* prow = &patch[(size_t)c * CDIM];
      float dot = 0.f;
      for (int k = 0; k < CDIM; ++k) dot = fmaf(lsh[k], prow[k], dot);
      key = np_key(lnorm[lab], dot, pnorm[c]);
    }
    ckey[tid] = key;
  }
  __syncthreads();
  {
    float myk = ckey[tid]; int myc = cidx[tid];
    int rank = 0;
    for (int j = 0; j < 256; ++j) {
      float kj = ckey[j]; int cj = cidx[j];
      rank += (kj < myk || (kj == myk && cj < myc)) ? 1 : 0;
    }
    if (myc != 0x7fffffff && rank < KTOP) nb[rank] = myc;
  }
  __syncthreads();
  float mx = -INFINITY;
#pragma unroll
  for (int j = 0; j < KTOP; ++j)
    mx = fmaxf(mx, patch[(size_t)nb[j] * CDIM + tid]);
  ctx[(size_t)lab * CDIM + tid] = mx - lsh[tid];
}

// ---------------- FALLBACK: R4 f32 screen + merge (known-green) -------------

__global__ void k_norms_np(const float* __restrict__ m, int n,
                           float* __restrict__ out) {
  int i = blockIdx.x * blockDim.x + threadIdx.x;
  int stride = gridDim.x * blockDim.x;
  for (; i < n; i += stride) out[i] = np_sq256(m + (size_t)i * CDIM);
}

__global__ void k_screen_f32(const float* __restrict__ lbl,
                             const float* __restrict__ patch,
                             const float* __restrict__ pnorm,
                             const float* __restrict__ lnorm,
                             float* __restrict__ part_s,
                             int* __restrict__ part_i) {
  __shared__ float Asm[KC][BLK];
  __shared__ float Bsm[KC][BLK];
  __shared__ float sc[BLK][BLK + 1];
  const int tid = threadIdx.x;
  const int tr = tid >> 4, tc = tid & 15;
  const int lbase = blockIdx.y * BLK;
  const int chunk = blockIdx.x;
  const int p0 = chunk * CHUNK;
  const int p1 = (p0 + CHUNK < NPATCH) ? p0 + CHUNK : NPATCH;

  float tv[KP]; int ti[KP];
#pragma unroll
  for (int j = 0; j < KP; ++j) { tv[j] = INFINITY; ti[j] = 0x7fffffff; }
  const float ln = (tid < BLK) ? lnorm[lbase + tid] : 0.f;

  const int sl = tid >> 2;
  const int skq = (tid & 3) * 4;

  for (int pt = p0; pt < p1; pt += BLK) {
    float acc[4][4];
#pragma unroll
    for (int a = 0; a < 4; ++a)
#pragma unroll
      for (int b = 0; b < 4; ++b) acc[a][b] = 0.f;

    for (int kc = 0; kc < CDIM; kc += KC) {
      __syncthreads();
      {
        const float* arow = &lbl[(size_t)(lbase + sl) * CDIM + kc];
        float4 va0 = *(const float4*)(arow + skq);
        float4 va1 = *(const float4*)(arow + 16 + skq);
        Asm[skq + 0][sl] = va0.x; Asm[skq + 1][sl] = va0.y;
        Asm[skq + 2][sl] = va0.z; Asm[skq + 3][sl] = va0.w;
        Asm[16 + skq + 0][sl] = va1.x; Asm[16 + skq + 1][sl] = va1.y;
        Asm[16 + skq + 2][sl] = va1.z; Asm[16 + skq + 3][sl] = va1.w;
        int p = pt + sl;
        float4 vb0 = make_float4(0.f, 0.f, 0.f, 0.f), vb1 = vb0;
        if (p < p1) {
          const float* brow = &patch[(size_t)p * CDIM + kc];
          vb0 = *(const float4*)(brow + skq);
          vb1 = *(const float4*)(brow + 16 + skq);
        }
        Bsm[skq + 0][sl] = vb0.x; Bsm[skq + 1][sl] = vb0.y;
        Bsm[skq + 2][sl] = vb0.z; Bsm[skq + 3][sl] = vb0.w;
        Bsm[16 + skq + 0][sl] = vb1.x; Bsm[16 + skq + 1][sl] = vb1.y;
        Bsm[16 + skq + 2][sl] = vb1.z; Bsm[16 + skq + 3][sl] = vb1.w;
      }
      __syncthreads();
#pragma unroll
      for (int k = 0; k < KC; ++k) {
        float4 a4 = *(const float4*)&Asm[k][tr * 4];
        float4 b4 = *(const float4*)&Bsm[k][tc * 4];
        const float av[4] = {a4.x, a4.y, a4.z, a4.w};
        const float bv[4] = {b4.x, b4.y, b4.z, b4.w};
#pragma unroll
        for (int a = 0; a < 4; ++a)
#pragma unroll
          for (int b = 0; b < 4; ++b) acc[a][b] = fmaf(av[a], bv[b], acc[a][b]);
      }
    }
#pragma unroll
    for (int a = 0; a < 4; ++a)
#pragma unroll
      for (int b = 0; b < 4; ++b) sc[tr * 4 + a][tc * 4 + b] = acc[a][b];
    __syncthreads();
    if (tid < BLK) {
      for (int c = 0; c < BLK; ++c) {
        int p = pt + c;
        if (p < p1) tk_insert<KP>(tv, ti, np_key(ln, sc[tid][c], pnorm[p]), p);
      }
    }
  }

  if (tid < BLK) {
    int lab = lbase + tid;
    size_t base = ((size_t)lab * NCHUNK + chunk) * KP;
#pragma unroll
    for (int j = 0; j < KP; ++j) { part_s[base + j] = tv[j]; part_i[base + j] = ti[j]; }
  }
}

__global__ void k_merge_f32(const float* __restrict__ part_s,
                            const int* __restrict__ part_i,
                            const float* __restrict__ patch,
                            const float* __restrict__ lbl,
                            float* __restrict__ ctx) {
  const int lab = blockIdx.x;
  const int tid = threadIdx.x;
  __shared__ float cv[16][KP];
  __shared__ int ci[16][KP];
  __shared__ int nb[KTOP];

  const int total = NCHUNK * KP;
  if (tid < 16) {
    float v[KP]; int ii[KP];
#pragma unroll
    for (int j = 0; j < KP; ++j) { v[j] = INFINITY; ii[j] = 0x7fffffff; }
    for (int e = tid; e < total; e += 16)
      tk_insert<KP>(v, ii, part_s[(size_t)lab * total + e],
                    part_i[(size_t)lab * total + e]);
#pragma unroll
    for (int j = 0; j < KP; ++j) { cv[tid][j] = v[j]; ci[tid][j] = ii[j]; }
  }
  __syncthreads();
  if (tid == 0) {
    float v[KP]; int ii[KP];
#pragma unroll
    for (int j = 0; j < KP; ++j) { v[j] = INFINITY; ii[j] = 0x7fffffff; }
    for (int t = 0; t < 16; ++t)
      for (int j = 0; j < KP; ++j) tk_insert<KP>(v, ii, cv[t][j], ci[t][j]);
#pragma unroll
    for (int j = 0; j < KTOP; ++j) nb[j] = ii[j];
  }
  __syncthreads();
  float l = lbl[(size_t)lab * CDIM + tid];
  float mx = -INFINITY;
#pragma unroll
  for (int j = 0; j < KTOP; ++j)
    mx = fmaxf(mx, patch[(size_t)nb[j] * CDIM + tid]);
  ctx[(size_t)lab * CDIM + tid] = mx - l;
}

// ---------------- kernel: small label->label agg (np-f32 semantics) ---------
// selection via parallel rank (lexicographic (key, idx) == reference's
// strict-< serial scan with lowest-idx-on-tie).

__global__ void k_small_agg(const float* __restrict__ lbl_rows,
                            const float* __restrict__ tgt, int M, int k,
                            float* __restrict__ ctx) {
  const int row = blockIdx.x;
  const int tid = threadIdx.x;
  __shared__ float lsh[CDIM];
  __shared__ float skey[256];
  __shared__ float lns;
  __shared__ int nb[4];
  lsh[tid] = lbl_rows[(size_t)row * CDIM + tid];
  __syncthreads();
  if (tid == 0) lns = np_sq256(lsh);
  __syncthreads();
  float key = INFINITY;
  if (tid < M) {
    const float* trow = &tgt[(size_t)tid * CDIM];
    float tn = np_sq256(trow);
    float dot = 0.f;
    for (int c = 0; c < CDIM; ++c) dot = fmaf(lsh[c], trow[c], dot);
    key = np_key(lns, dot, tn);
  }
  skey[tid] = key;
  __syncthreads();
  {
    int rank = 0;
    for (int j = 0; j < M; ++j) {
      float kj = skey[j];
      rank += (kj < key || (kj == key && j < tid)) ? 1 : 0;
    }
    if (tid < M && rank < k) nb[rank] = tid;
  }
  __syncthreads();
  float mx = -INFINITY;
  for (int t = 0; t < k; ++t) mx = fmaxf(mx, tgt[(size_t)nb[t] * CDIM + tid]);
  ctx[(size_t)row * CDIM + tid] = mx - lsh[tid];
}

// ---------------- kernel: linear(concat) + residual + LayerNorm (f64) -------

__device__ __forceinline__ double block_sum_256d(double x, double* red) {
#pragma unroll
  for (int m = 32; m >= 1; m >>= 1) x += __shfl_xor(x, m);
  int wid = threadIdx.x >> 6, lane = threadIdx.x & 63;
  if (lane == 0) red[wid] = x;
  __syncthreads();
  double s = red[0] + red[1] + red[2] + red[3];
  __syncthreads();
  return s;
}

__global__ void k_level_out(const float* __restrict__ emb,
                            const float* __restrict__ c1,
                            const float* __restrict__ c2,
                            const float* __restrict__ c3, int nseg,
                            const float* __restrict__ W,
                            const float* __restrict__ bias,
                            const float* __restrict__ gamma,
                            const float* __restrict__ beta,
                            float* __restrict__ out) {
  __shared__ float xs[4 * CDIM];
  __shared__ double red[4];
  const int row = blockIdx.x, ch = threadIdx.x;
  float e = emb[(size_t)row * CDIM + ch];
  xs[ch] = e;
  if (nseg > 1) xs[CDIM + ch] = c1[(size_t)row * CDIM + ch];
  if (nseg > 2) xs[2 * CDIM + ch] = c2[(size_t)row * CDIM + ch];
  if (nseg > 3) xs[3 * CDIM + ch] = c3[(size_t)row * CDIM + ch];
  __syncthreads();
  const int F = nseg * CDIM;
  double y = (double)e + (double)bias[ch];
#pragma unroll 4
  for (int j = 0; j < F; ++j)
    y += (double)xs[j] * (double)W[(size_t)j * CDIM + ch];
  double mu = block_sum_256d(y, red) * (1.0 / 256.0);
  double d = y - mu;
  double var = block_sum_256d(d * d, red) * (1.0 / 256.0);
  out[(size_t)row * CDIM + ch] =
      (float)(d / sqrt(var + 1e-5) * (double)gamma[ch] + (double)beta[ch]);
}

// ---------------- launch ----------------------------------------------------

static void launch_tail(const float* mood_emb, const float* genre_emb,
                        const float* sub_emb, const float* Wm_w, const float* Wm_b,
                        const float* Wg_w, const float* Wg_b, const float* Ws_w,
                        const float* Ws_b, const float* lnm_g, const float* lnm_b,
                        const float* lng_g, const float* lng_b, const float* lns_g,
                        const float* lns_b, const float* ctx_all, float* ctx_gm,
                        float* ctx_sm, float* ctx_sg, float* out,
                        hipStream_t stream) {
  k_level_out<<<NMOOD, 256, 0, stream>>>(mood_emb, ctx_all, nullptr, nullptr, 2,
                                         Wm_w, Wm_b, lnm_g, lnm_b, out);
  k_small_agg<<<NGENRE, 256, 0, stream>>>(genre_emb, out, NMOOD, 4, ctx_gm);
  k_level_out<<<NGENRE, 256, 0, stream>>>(genre_emb, ctx_all + NMOOD * CDIM, ctx_gm,
                                          nullptr, 3, Wg_w, Wg_b, lng_g, lng_b,
                                          out + NMOOD * CDIM);
  k_small_agg<<<NSUB, 256, 0, stream>>>(sub_emb, out, NMOOD, 3, ctx_sm);
  k_small_agg<<<NSUB, 256, 0, stream>>>(sub_emb, out + NMOOD * CDIM, NGENRE, 4, ctx_sg);
  k_level_out<<<NSUB, 256, 0, stream>>>(sub_emb, ctx_all + (NMOOD + NGENRE) * CDIM,
                                        ctx_sm, ctx_sg, 4, Ws_w, Ws_b, lns_g, lns_b,
                                        out + NMOOD * CDIM + NGENRE * CDIM);
}

extern "C" void kernel_launch(void* const* d_in, const int* in_sizes, int n_in,
                              void* d_out, int out_size, void* d_ws, size_t ws_size,
                              hipStream_t stream) {
  const float* patch     = (const float*)d_in[0];
  const float* mood_emb  = (const float*)d_in[1];
  const float* genre_emb = (const float*)d_in[2];
  const float* sub_emb   = (const float*)d_in[3];
  const float* Wm_w = (const float*)d_in[4];
  const float* Wm_b = (const float*)d_in[5];
  const float* Wg_w = (const float*)d_in[6];
  const float* Wg_b = (const float*)d_in[7];
  const float* Ws_w = (const float*)d_in[8];
  const float* Ws_b = (const float*)d_in[9];
  const float* lnm_g = (const float*)d_in[10];
  const float* lnm_b = (const float*)d_in[11];
  const float* lng_g = (const float*)d_in[12];
  const float* lng_b = (const float*)d_in[13];
  const float* lns_g = (const float*)d_in[14];
  const float* lns_b = (const float*)d_in[15];
  float* out = (float*)d_out;
  float* ws = (float*)d_ws;

  const size_t REQ = 15274112ull * 4ull;  // ~61.1 MB (proven fits, R10)

  if (ws_size >= REQ) {
    // ---- MFMA path layout ----
    float* lbl     = ws;                     // 212992
    float* pnorm   = lbl + NLBL * CDIM;      // 100352
    float* lnorm   = pnorm + 100352;         // 1024
    float* ctx_all = lnorm + 1024;           // 212992
    float* ctx_gm  = ctx_all + NLBL * CDIM;  // 65536
    float* ctx_sm  = ctx_gm + NGENRE * CDIM; // 131072
    float* ctx_sg  = ctx_sm + NSUB * CDIM;   // 131072
    float* part_s  = ctx_sg + NSUB * CDIM;   // 832*101*9 = 756288
    int*   part_i  = (int*)(part_s + (size_t)NLBL * NCH4 * KPS4);
    unsigned short* packed = (unsigned short*)(part_i + (size_t)NLBL * NCH4 * KPS4);
    unsigned short* lblbf  = packed + (size_t)NPATCH * CDIM;

    k_concat_labels<<<NLBL, 256, 0, stream>>>(mood_emb, genre_emb, sub_emb, lbl);
    k_norms_wave<<<512, 256, 0, stream>>>(patch, NPATCH, pnorm);
    k_norms_wave<<<16, 256, 0, stream>>>(lbl, NLBL, lnorm);
    k_tobf16<<<128, 256, 0, stream>>>(lbl, (size_t)NLBL * CDIM / 8, lblbf);
    k_pack<<<1024, 256, 0, stream>>>(patch, packed);
    k_screen_mfma<<<13 * NCH4, 256, 0, stream>>>(lblbf, packed, pnorm,
                                                 part_s, part_i);
    k_merge_mfma<<<NLBL, 256, 0, stream>>>(part_s, part_i, patch, lbl, pnorm,
                                           lnorm, ctx_all);
    launch_tail(mood_emb, genre_emb, sub_emb, Wm_w, Wm_b, Wg_w, Wg_b, Ws_w, Ws_b,
                lnm_g, lnm_b, lng_g, lng_b, lns_g, lns_b, ctx_all, ctx_gm, ctx_sm,
                ctx_sg, out, stream);
  } else {
    // ---- R4 fallback layout (known to fit) ----
    float* lbl    = ws;
    float* pnorm  = lbl + NLBL * CDIM;
    float* lnorm  = pnorm + 100352;
    float* part_s = lnorm + 1024;
    int*   part_i = (int*)(part_s + NLBL * NCHUNK * KP);
    float* ctx_all = part_s + 2 * NLBL * NCHUNK * KP;
    float* ctx_gm  = ctx_all + NLBL * CDIM;
    float* ctx_sm  = ctx_gm + NGENRE * CDIM;
    float* ctx_sg  = ctx_sm + NSUB * CDIM;

    k_concat_labels<<<NLBL, 256, 0, stream>>>(mood_emb, genre_emb, sub_emb, lbl);
    k_norms_np<<<512, 256, 0, stream>>>(patch, NPATCH, pnorm);
    k_norms_np<<<4, 256, 0, stream>>>(lbl, NLBL, lnorm);
    dim3 gscr(NCHUNK, NLBL / BLK);
    k_screen_f32<<<gscr, 256, 0, stream>>>(lbl, patch, pnorm, lnorm, part_s, part_i);
    k_merge_f32<<<NLBL, 256, 0, stream>>>(part_s, part_i, patch, lbl, ctx_all);
    launch_tail(mood_emb, genre_emb, sub_emb, Wm_w, Wm_b, Wg_w, Wg_b, Ws_w, Ws_b,
                lnm_g, lnm_b, lng_g, lng_b, lns_g, lns_b, ctx_all, ctx_gm, ctx_sm,
                ctx_sg, out, stream);
  }
}

// Round 12
// 572.528 us; speedup vs baseline: 3.9594x; 1.0688x over previous
//
#include <hip/hip_runtime.h>
#include <math.h>

#define NPATCH 100000
#define CDIM   256
#define NMOOD  64
#define NGENRE 256
#define NSUB   512
#define NLBL   832          // 64+256+512
#define KTOP   9
#define NGRPTOT 6250        // NPATCH/16

// ---- f32 fallback screen constants (R4, known-green) ----
#define NCHUNK 39
#define CHUNK  2624
#define BLK    64
#define KC     32
#define KP     12

// ---- MFMA screen constants ----
#define PBLK4  992          // patches per chunk (62 groups)
#define NCH4   101          // 101*992 = 100192 >= 100000
#define SL4    4            // per-lane list depth
#define KPS4   9            // per-(label,chunk) stored candidates
#define NCAND  192          // merge candidates (64x12 -> 16x12)

typedef __attribute__((ext_vector_type(8))) short bf16x8;
typedef __attribute__((ext_vector_type(8))) unsigned short u16x8;
typedef __attribute__((ext_vector_type(4))) float f32x4;

// ---------------- serial top-k insert (ascending by (val,idx)) --------------

template <int K>
__device__ __forceinline__ void tk_insert(float (&v)[K], int (&ii)[K],
                                          float s, int idx) {
  if (s < v[K - 1] || (s == v[K - 1] && idx < ii[K - 1])) {
    v[K - 1] = s; ii[K - 1] = idx;
#pragma unroll
    for (int t = K - 1; t > 0; --t) {
      bool sw = (v[t] < v[t - 1]) || (v[t] == v[t - 1] && ii[t] < ii[t - 1]);
      if (sw) {
        float fv = v[t]; v[t] = v[t - 1]; v[t - 1] = fv;
        int fi = ii[t]; ii[t] = ii[t - 1]; ii[t - 1] = fi;
      }
    }
  }
}

// fast screen insert: branch-free, NO idx tie-break (ascending-idx processing
// keeps lower idx on equal keys; exact re-rank downstream finalizes order).

template <int K>
__device__ __forceinline__ void tk_fast(float (&v)[K], int (&ii)[K],
                                        float s, int idx) {
  bool ins = s < v[K - 1];
  v[K - 1] = ins ? s : v[K - 1];
  ii[K - 1] = ins ? idx : ii[K - 1];
#pragma unroll
  for (int t = K - 1; t > 0; --t) {
    bool sw = v[t] < v[t - 1];
    float a0 = sw ? v[t] : v[t - 1];
    float a1 = sw ? v[t - 1] : v[t];
    int b0 = sw ? ii[t] : ii[t - 1];
    int b1 = sw ? ii[t - 1] : ii[t];
    v[t - 1] = a0; v[t] = a1; ii[t - 1] = b0; ii[t] = b1;
  }
}

// ------ numpy-pairwise sum of squares over 256 contiguous floats ------------

__device__ float np_sq256(const float* a) {
  float b0, b1;
  {
    float r[8];
#pragma unroll
    for (int i = 0; i < 8; ++i) { float x = a[i]; r[i] = __fmul_rn(x, x); }
    for (int j = 8; j < 128; j += 8)
#pragma unroll
      for (int i = 0; i < 8; ++i) {
        float x = a[j + i];
        r[i] = __fadd_rn(r[i], __fmul_rn(x, x));
      }
    b0 = __fadd_rn(__fadd_rn(__fadd_rn(r[0], r[1]), __fadd_rn(r[2], r[3])),
                   __fadd_rn(__fadd_rn(r[4], r[5]), __fadd_rn(r[6], r[7])));
  }
  {
    float r[8];
#pragma unroll
    for (int i = 0; i < 8; ++i) { float x = a[128 + i]; r[i] = __fmul_rn(x, x); }
    for (int j = 8; j < 128; j += 8)
#pragma unroll
      for (int i = 0; i < 8; ++i) {
        float x = a[128 + j + i];
        r[i] = __fadd_rn(r[i], __fmul_rn(x, x));
      }
    b1 = __fadd_rn(__fadd_rn(__fadd_rn(r[0], r[1]), __fadd_rn(r[2], r[3])),
                   __fadd_rn(__fadd_rn(r[4], r[5]), __fadd_rn(r[6], r[7])));
  }
  return __fadd_rn(b0, b1);
}

// float4-load variant: identical arithmetic order (loads only are vectorized).

__device__ float np_sq256_v4(const float* a) {
  const float4* a4 = (const float4*)a;
  float b[2];
#pragma unroll
  for (int blk = 0; blk < 2; ++blk) {
    float r[8];
    float4 v0 = a4[blk * 32], v1 = a4[blk * 32 + 1];
    r[0] = __fmul_rn(v0.x, v0.x); r[1] = __fmul_rn(v0.y, v0.y);
    r[2] = __fmul_rn(v0.z, v0.z); r[3] = __fmul_rn(v0.w, v0.w);
    r[4] = __fmul_rn(v1.x, v1.x); r[5] = __fmul_rn(v1.y, v1.y);
    r[6] = __fmul_rn(v1.z, v1.z); r[7] = __fmul_rn(v1.w, v1.w);
    for (int j = 1; j < 16; ++j) {
      v0 = a4[blk * 32 + j * 2]; v1 = a4[blk * 32 + j * 2 + 1];
      r[0] = __fadd_rn(r[0], __fmul_rn(v0.x, v0.x));
      r[1] = __fadd_rn(r[1], __fmul_rn(v0.y, v0.y));
      r[2] = __fadd_rn(r[2], __fmul_rn(v0.z, v0.z));
      r[3] = __fadd_rn(r[3], __fmul_rn(v0.w, v0.w));
      r[4] = __fadd_rn(r[4], __fmul_rn(v1.x, v1.x));
      r[5] = __fadd_rn(r[5], __fmul_rn(v1.y, v1.y));
      r[6] = __fadd_rn(r[6], __fmul_rn(v1.z, v1.z));
      r[7] = __fadd_rn(r[7], __fmul_rn(v1.w, v1.w));
    }
    b[blk] = __fadd_rn(__fadd_rn(__fadd_rn(r[0], r[1]), __fadd_rn(r[2], r[3])),
                       __fadd_rn(__fadd_rn(r[4], r[5]), __fadd_rn(r[6], r[7])));
  }
  return __fadd_rn(b[0], b[1]);
}

__device__ __forceinline__ float np_key(float ln, float dot, float pn) {
  return __fadd_rn(__fsub_rn(ln, __fmul_rn(2.f, dot)), pn);
}

// exact sequential fmaf dot chain (BLAS k-order) with float4 loads.

__device__ __forceinline__ float dot_chain_v4(const float* a, const float* b) {
  const float4* a4 = (const float4*)a;
  const float4* b4 = (const float4*)b;
  float dot = 0.f;
  for (int j = 0; j < 64; ++j) {
    float4 x = a4[j], y = b4[j];
    dot = fmaf(x.x, y.x, dot);
    dot = fmaf(x.y, y.y, dot);
    dot = fmaf(x.z, y.z, dot);
    dot = fmaf(x.w, y.w, dot);
  }
  return dot;
}

__device__ __forceinline__ unsigned short f2bf(float x) {
  unsigned u = __float_as_uint(x);
  return (unsigned short)((u + 0x7fffu + ((u >> 16) & 1u)) >> 16);
}

// ---------------- kernel: fused patch prep: packed bf16 + np-exact norms ----
// 16 rows per block-iter (4 rows/wave). Coalesced float4 read; bf16 packed
// store straight from registers (k_pack's proven layout); norms via the R8
// prep2 class-accumulator tree (bit-identical to np_sq256).

__global__ __launch_bounds__(256) void k_prep3(const float* __restrict__ src,
                                               unsigned short* __restrict__ packed,
                                               float* __restrict__ norms) {
  __shared__ float lds[4][4][260];
  const int tid = threadIdx.x;
  const int w = tid >> 6, l = tid & 63;
  const int rr = l >> 4;            // row within wave quad
  const int h = (l >> 3) & 1;       // 128-half
  const int i = l & 7;              // np accumulator class
  const int kk = l >> 3, kg = (l >> 1) & 3, e = (l & 1) * 4;  // pack coords (j=4l)
  for (int base = blockIdx.x * 16; base < NPATCH; base += gridDim.x * 16) {
    int row = base + w * 4;
    __syncthreads();                 // protect lds reuse across iterations
#pragma unroll
    for (int q = 0; q < 4; ++q) {
      int r = row + q;
      if (r < NPATCH) {
        float4 v = *(const float4*)&src[(size_t)r * CDIM + l * 4];
        ushort4 o = make_ushort4(f2bf(v.x), f2bf(v.y), f2bf(v.z), f2bf(v.w));
        int gg = r >> 4, col = r & 15;
        *(ushort4*)&packed[((size_t)(gg * 8 + kk)) * 512 + (col + 16 * kg) * 8 + e] = o;
        lds[w][q][l * 4 + 0] = v.x; lds[w][q][l * 4 + 1] = v.y;
        lds[w][q][l * 4 + 2] = v.z; lds[w][q][l * 4 + 3] = v.w;
      }
    }
    __syncthreads();
    int r = row + rr;
    if (r < NPATCH) {
      const float* a = &lds[w][rr][h * 128];
      float x = a[i];
      float acc = __fmul_rn(x, x);
#pragma unroll
      for (int j = 1; j < 16; ++j) {
        float y = a[j * 8 + i];
        acc = __fadd_rn(acc, __fmul_rn(y, y));
      }
      float t = __fadd_rn(acc, __shfl_xor(acc, 1));
      t = __fadd_rn(t, __shfl_xor(t, 2));
      t = __fadd_rn(t, __shfl_xor(t, 4));
      float o = __shfl_xor(t, 8);
      if (h == 0 && i == 0) norms[r] = __fadd_rn(t, o);
    }
  }
}

// ---------------- kernel: fused label prep: concat + f32 + bf16 + norms -----
// grid = 52 blocks exactly (832/16 rows).

__global__ __launch_bounds__(256) void k_lbl_prep(
    const float* __restrict__ mood, const float* __restrict__ genre,
    const float* __restrict__ sub, float* __restrict__ lbl,
    unsigned short* __restrict__ lblbf, float* __restrict__ lnorm) {
  __shared__ float lds[4][4][260];
  const int tid = threadIdx.x;
  const int w = tid >> 6, l = tid & 63;
  const int rr = l >> 4, h = (l >> 3) & 1, i = l & 7;
  const int row = blockIdx.x * 16 + w * 4;
#pragma unroll
  for (int q = 0; q < 4; ++q) {
    int r = row + q;
    const float* srcr = (r < NMOOD) ? &mood[(size_t)r * CDIM]
                      : (r < NMOOD + NGENRE) ? &genre[(size_t)(r - NMOOD) * CDIM]
                      : &sub[(size_t)(r - NMOOD - NGENRE) * CDIM];
    float4 v = *(const float4*)&srcr[l * 4];
    *(float4*)&lbl[(size_t)r * CDIM + l * 4] = v;
    ushort4 o = make_ushort4(f2bf(v.x), f2bf(v.y), f2bf(v.z), f2bf(v.w));
    *(ushort4*)&lblbf[(size_t)r * CDIM + l * 4] = o;
    lds[w][q][l * 4 + 0] = v.x; lds[w][q][l * 4 + 1] = v.y;
    lds[w][q][l * 4 + 2] = v.z; lds[w][q][l * 4 + 3] = v.w;
  }
  __syncthreads();
  {
    int r = row + rr;
    const float* a = &lds[w][rr][h * 128];
    float x = a[i];
    float acc = __fmul_rn(x, x);
#pragma unroll
    for (int j = 1; j < 16; ++j) {
      float y = a[j * 8 + i];
      acc = __fadd_rn(acc, __fmul_rn(y, y));
    }
    float t = __fadd_rn(acc, __shfl_xor(acc, 1));
    t = __fadd_rn(t, __shfl_xor(t, 2));
    t = __fadd_rn(t, __shfl_xor(t, 4));
    float o = __shfl_xor(t, 8);
    if (h == 0 && i == 0) lnorm[r] = __fadd_rn(t, o);
  }
}

// ---------------- async global->LDS helper ----------------------------------

__device__ __forceinline__ void gload_lds16(const void* g, void* l) {
  __builtin_amdgcn_global_load_lds(
      (const __attribute__((address_space(1))) unsigned int*)g,
      (__attribute__((address_space(3))) unsigned int*)l, 16, 0, 0);
}

// ---------------- kernel: MFMA bf16 screen (R11, unchanged — proven) --------

__global__ __launch_bounds__(256) void k_screen_mfma(
    const unsigned short* __restrict__ lblbf,
    const unsigned short* __restrict__ packed,
    const float* __restrict__ pnorm,
    float* __restrict__ part_s, int* __restrict__ part_i) {
  __shared__ float pn_lds[PBLK4];                  // 3.97 KB
  __shared__ __align__(16) char smem[2][8192];     // 16 KB
  const int tid = threadIdx.x;
  const int w = tid >> 6, l = tid & 63;
  const int col = l & 15, kg = l >> 4;
  const int lgrp = blockIdx.x % 13;
  const int chunk = blockIdx.x / 13;
  const int lab0 = lgrp * 64 + w * 16;
  const int p0 = chunk * PBLK4;
  const int grp0 = p0 >> 4;
  const int ngrp = min(PBLK4 / 16, (NPATCH - p0 + 15) >> 4);

  for (int e = tid; e < PBLK4; e += 256) {
    int p = p0 + e;
    pn_lds[e] = (p < NPATCH) ? pnorm[p] : INFINITY;
  }

  bf16x8 a[8];
#pragma unroll
  for (int kk = 0; kk < 8; ++kk)
    a[kk] = *(const bf16x8*)&lblbf[(size_t)(lab0 + col) * CDIM + kk * 32 + kg * 8];

  float lv[SL4]; int li[SL4];
#pragma unroll
  for (int j = 0; j < SL4; ++j) { lv[j] = INFINITY; li[j] = 0x7fffffff; }

  auto stage = [&](int buf, int g) {
    int gg = grp0 + g;
    if (gg > NGRPTOT - 1) gg = NGRPTOT - 1;
    const char* gsrc = (const char*)packed + (size_t)gg * 8192;
    gload_lds16(gsrc + tid * 16, &smem[buf][tid * 16]);
    gload_lds16(gsrc + (tid + 256) * 16, &smem[buf][(tid + 256) * 16]);
  };

  stage(0, 0);
  __syncthreads();
  for (int g = 0; g < ngrp; ++g) {
    const int cb = g & 1;
    if (g + 1 < ngrp) stage(cb ^ 1, g + 1);
    const char* gb = smem[cb];
    bf16x8 bb[8];
#pragma unroll
    for (int kk = 0; kk < 8; ++kk)
      bb[kk] = *(const bf16x8*)(gb + kk * 1024 + l * 16);
    f32x4 ac0 = {0.f, 0.f, 0.f, 0.f}, ac1 = {0.f, 0.f, 0.f, 0.f};
#pragma unroll
    for (int kk = 0; kk < 4; ++kk) {
      ac0 = __builtin_amdgcn_mfma_f32_16x16x32_bf16(bb[2 * kk], a[2 * kk],
                                                    ac0, 0, 0, 0);
      ac1 = __builtin_amdgcn_mfma_f32_16x16x32_bf16(bb[2 * kk + 1],
                                                    a[2 * kk + 1], ac1,
                                                    0, 0, 0);
    }
    const int pib = g * 16 + kg * 4;
    float k0 = fmaf(-2.f, ac0[0] + ac1[0], pn_lds[pib + 0]);
    float k1 = fmaf(-2.f, ac0[1] + ac1[1], pn_lds[pib + 1]);
    float k2 = fmaf(-2.f, ac0[2] + ac1[2], pn_lds[pib + 2]);
    float k3 = fmaf(-2.f, ac0[3] + ac1[3], pn_lds[pib + 3]);
    if (fminf(fminf(k0, k1), fminf(k2, k3)) < lv[SL4 - 1]) {
      tk_fast<SL4>(lv, li, k0, p0 + pib + 0);
      tk_fast<SL4>(lv, li, k1, p0 + pib + 1);
      tk_fast<SL4>(lv, li, k2, p0 + pib + 2);
      tk_fast<SL4>(lv, li, k3, p0 + pib + 3);
    }
    __syncthreads();
  }

  float v9[KPS4]; int i9[KPS4];
#pragma unroll
  for (int j = 0; j < KPS4; ++j) {
    v9[j] = (j < SL4) ? lv[j] : INFINITY;
    i9[j] = (j < SL4) ? li[j] : 0x7fffffff;
  }
#pragma unroll
  for (int j = 0; j < SL4; ++j) {
    float rv = __shfl_xor(lv[j], 16);
    int ri = __shfl_xor(li[j], 16);
    tk_fast<KPS4>(v9, i9, rv, ri);
  }
  {
    float tv[KPS4]; int ti[KPS4];
#pragma unroll
    for (int j = 0; j < KPS4; ++j) { tv[j] = v9[j]; ti[j] = i9[j]; }
#pragma unroll
    for (int j = 0; j < KPS4; ++j) {
      float rv = __shfl_xor(tv[j], 32);
      int ri = __shfl_xor(ti[j], 32);
      tk_fast<KPS4>(v9, i9, rv, ri);
    }
  }
  if (kg == 0) {
    int lab = lab0 + col;
    size_t base = ((size_t)lab * NCH4 + chunk) * KPS4;
#pragma unroll
    for (int j = 0; j < KPS4; ++j) { part_s[base + j] = v9[j]; part_i[base + j] = i9[j]; }
  }
}

// ---------------- kernel: merge + EXACT np-f32 re-rank + max-agg ------------
// funnel 64x12 -> 16x12 = 192 candidates (every stream depth >= KTOP=9, so a
// true top-9 entry can never be dropped), exact np-f32 keys (float4 chain,
// bit-identical order), parallel rank (lexicographic (key,idx)).

__global__ void k_merge_mfma(const float* __restrict__ part_s,
                             const int* __restrict__ part_i,
                             const float* __restrict__ patch,
                             const float* __restrict__ lbl,
                             const float* __restrict__ pnorm,
                             const float* __restrict__ lnorm,
                             float* __restrict__ ctx) {
  const int lab = blockIdx.x;
  const int tid = threadIdx.x;
  __shared__ float lsh[CDIM];
  __shared__ float sv[64 * 12];
  __shared__ int   si[64 * 12];
  __shared__ int   cidx[NCAND];
  __shared__ float ckey[NCAND];
  __shared__ int   nb[KTOP];

  lsh[tid] = lbl[(size_t)lab * CDIM + tid];
  const int total = NCH4 * KPS4;  // 909
  if (tid < 64) {
    float v[12]; int ii[12];
#pragma unroll
    for (int j = 0; j < 12; ++j) { v[j] = INFINITY; ii[j] = 0x7fffffff; }
    for (int e = tid; e < total; e += 64)
      tk_insert<12>(v, ii, part_s[(size_t)lab * total + e],
                    part_i[(size_t)lab * total + e]);
#pragma unroll
    for (int j = 0; j < 12; ++j) { sv[tid * 12 + j] = v[j]; si[tid * 12 + j] = ii[j]; }
  }
  __syncthreads();
  if (tid < 16) {
    float v[12]; int ii[12];
#pragma unroll
    for (int j = 0; j < 12; ++j) { v[j] = INFINITY; ii[j] = 0x7fffffff; }
    for (int e = 0; e < 48; ++e)
      tk_insert<12>(v, ii, sv[tid * 48 + e], si[tid * 48 + e]);
#pragma unroll
    for (int j = 0; j < 12; ++j) cidx[tid * 12 + j] = ii[j];
  }
  __syncthreads();
  if (tid < NCAND) {
    int c = cidx[tid];
    float key = INFINITY;
    if (c != 0x7fffffff)
      key = np_key(lnorm[lab], dot_chain_v4(lsh, &patch[(size_t)c * CDIM]),
                   pnorm[c]);
    ckey[tid] = key;
  }
  __syncthreads();
  if (tid < NCAND) {
    float myk = ckey[tid]; int myc = cidx[tid];
    int rank = 0;
    for (int j = 0; j < NCAND; ++j) {
      float kj = ckey[j]; int cj = cidx[j];
      rank += (kj < myk || (kj == myk && cj < myc)) ? 1 : 0;
    }
    if (myc != 0x7fffffff && rank < KTOP) nb[rank] = myc;
  }
  __syncthreads();
  float mx = -INFINITY;
#pragma unroll
  for (int j = 0; j < KTOP; ++j)
    mx = fmaxf(mx, patch[(size_t)nb[j] * CDIM + tid]);
  ctx[(size_t)lab * CDIM + tid] = mx - lsh[tid];
}

// ---------------- kernel: small label->label agg (np-f32, float4 loads) -----

__global__ void k_small_agg(const float* __restrict__ lbl_rows,
                            const float* __restrict__ tgt, int M, int k,
                            float* __restrict__ ctx) {
  const int row = blockIdx.x;
  const int tid = threadIdx.x;
  __shared__ float lsh[CDIM];
  __shared__ float skey[256];
  __shared__ float lns;
  __shared__ int nb[4];
  lsh[tid] = lbl_rows[(size_t)row * CDIM + tid];
  __syncthreads();
  if (tid == 0) lns = np_sq256_v4(lsh);
  __syncthreads();
  float key = INFINITY;
  if (tid < M) {
    const float* trow = &tgt[(size_t)tid * CDIM];
    float tn = np_sq256_v4(trow);
    float dot = dot_chain_v4(lsh, trow);
    key = np_key(lns, dot, tn);
  }
  skey[tid] = key;
  __syncthreads();
  {
    int rank = 0;
    for (int j = 0; j < M; ++j) {
      float kj = skey[j];
      rank += (kj < key || (kj == key && j < tid)) ? 1 : 0;
    }
    if (tid < M && rank < k) nb[rank] = tid;
  }
  __syncthreads();
  float mx = -INFINITY;
  for (int t = 0; t < k; ++t) mx = fmaxf(mx, tgt[(size_t)nb[t] * CDIM + tid]);
  ctx[(size_t)row * CDIM + tid] = mx - lsh[tid];
}

// ---------------- kernel: linear(concat) + residual + LayerNorm (f64) -------
// 8-way ILP f64 partials (breaks the dependent-chain latency; f64 accuracy
// makes the assoc change irrelevant vs the 0.0875 threshold).

__device__ __forceinline__ double block_sum_256d(double x, double* red) {
#pragma unroll
  for (int m = 32; m >= 1; m >>= 1) x += __shfl_xor(x, m);
  int wid = threadIdx.x >> 6, lane = threadIdx.x & 63;
  if (lane == 0) red[wid] = x;
  __syncthreads();
  double s = red[0] + red[1] + red[2] + red[3];
  __syncthreads();
  return s;
}

__global__ void k_level_out(const float* __restrict__ emb,
                            const float* __restrict__ c1,
                            const float* __restrict__ c2,
                            const float* __restrict__ c3, int nseg,
                            const float* __restrict__ W,
                            const float* __restrict__ bias,
                            const float* __restrict__ gamma,
                            const float* __restrict__ beta,
                            float* __restrict__ out) {
  __shared__ float xs[4 * CDIM];
  __shared__ double red[4];
  const int row = blockIdx.x, ch = threadIdx.x;
  float e = emb[(size_t)row * CDIM + ch];
  xs[ch] = e;
  if (nseg > 1) xs[CDIM + ch] = c1[(size_t)row * CDIM + ch];
  if (nseg > 2) xs[2 * CDIM + ch] = c2[(size_t)row * CDIM + ch];
  if (nseg > 3) xs[3 * CDIM + ch] = c3[(size_t)row * CDIM + ch];
  __syncthreads();
  const int F = nseg * CDIM;
  double ys[8];
#pragma unroll
  for (int m = 0; m < 8; ++m) ys[m] = 0.0;
  for (int j = 0; j < F; j += 8)
#pragma unroll
    for (int m = 0; m < 8; ++m)
      ys[m] += (double)xs[j + m] * (double)W[(size_t)(j + m) * CDIM + ch];
  double y = (double)e + (double)bias[ch] +
             (((ys[0] + ys[1]) + (ys[2] + ys[3])) +
              ((ys[4] + ys[5]) + (ys[6] + ys[7])));
  double mu = block_sum_256d(y, red) * (1.0 / 256.0);
  double d = y - mu;
  double var = block_sum_256d(d * d, red) * (1.0 / 256.0);
  out[(size_t)row * CDIM + ch] =
      (float)(d / sqrt(var + 1e-5) * (double)gamma[ch] + (double)beta[ch]);
}

// ---------------- FALLBACK: R4 f32 screen + merge (known-green) -------------

__global__ void k_concat_labels(const float* __restrict__ mood,
                                const float* __restrict__ genre,
                                const float* __restrict__ sub,
                                float* __restrict__ lbl) {
  int i = blockIdx.x * 256 + threadIdx.x;
  if (i < NMOOD * CDIM) lbl[i] = mood[i];
  else if (i < (NMOOD + NGENRE) * CDIM) lbl[i] = genre[i - NMOOD * CDIM];
  else lbl[i] = sub[i - (NMOOD + NGENRE) * CDIM];
}

__global__ void k_norms_np(const float* __restrict__ m, int n,
                           float* __restrict__ out) {
  int i = blockIdx.x * blockDim.x + threadIdx.x;
  int stride = gridDim.x * blockDim.x;
  for (; i < n; i += stride) out[i] = np_sq256(m + (size_t)i * CDIM);
}

__global__ void k_screen_f32(const float* __restrict__ lbl,
                             const float* __restrict__ patch,
                             const float* __restrict__ pnorm,
                             const float* __restrict__ lnorm,
                             float* __restrict__ part_s,
                             int* __restrict__ part_i) {
  __shared__ float Asm[KC][BLK];
  __shared__ float Bsm[KC][BLK];
  __shared__ float sc[BLK][BLK + 1];
  const int tid = threadIdx.x;
  const int tr = tid >> 4, tc = tid & 15;
  const int lbase = blockIdx.y * BLK;
  const int chunk = blockIdx.x;
  const int p0 = chunk * CHUNK;
  const int p1 = (p0 + CHUNK < NPATCH) ? p0 + CHUNK : NPATCH;

  float tv[KP]; int ti[KP];
#pragma unroll
  for (int j = 0; j < KP; ++j) { tv[j] = INFINITY; ti[j] = 0x7fffffff; }
  const float ln = (tid < BLK) ? lnorm[lbase + tid] : 0.f;

  const int sl = tid >> 2;
  const int skq = (tid & 3) * 4;

  for (int pt = p0; pt < p1; pt += BLK) {
    float acc[4][4];
#pragma unroll
    for (int a = 0; a < 4; ++a)
#pragma unroll
      for (int b = 0; b < 4; ++b) acc[a][b] = 0.f;

    for (int kc = 0; kc < CDIM; kc += KC) {
      __syncthreads();
      {
        const float* arow = &lbl[(size_t)(lbase + sl) * CDIM + kc];
        float4 va0 = *(const float4*)(arow + skq);
        float4 va1 = *(const float4*)(arow + 16 + skq);
        Asm[skq + 0][sl] = va0.x; Asm[skq + 1][sl] = va0.y;
        Asm[skq + 2][sl] = va0.z; Asm[skq + 3][sl] = va0.w;
        Asm[16 + skq + 0][sl] = va1.x; Asm[16 + skq + 1][sl] = va1.y;
        Asm[16 + skq + 2][sl] = va1.z; Asm[16 + skq + 3][sl] = va1.w;
        int p = pt + sl;
        float4 vb0 = make_float4(0.f, 0.f, 0.f, 0.f), vb1 = vb0;
        if (p < p1) {
          const float* brow = &patch[(size_t)p * CDIM + kc];
          vb0 = *(const float4*)(brow + skq);
          vb1 = *(const float4*)(brow + 16 + skq);
        }
        Bsm[skq + 0][sl] = vb0.x; Bsm[skq + 1][sl] = vb0.y;
        Bsm[skq + 2][sl] = vb0.z; Bsm[skq + 3][sl] = vb0.w;
        Bsm[16 + skq + 0][sl] = vb1.x; Bsm[16 + skq + 1][sl] = vb1.y;
        Bsm[16 + skq + 2][sl] = vb1.z; Bsm[16 + skq + 3][sl] = vb1.w;
      }
      __syncthreads();
#pragma unroll
      for (int k = 0; k < KC; ++k) {
        float4 a4 = *(const float4*)&Asm[k][tr * 4];
        float4 b4 = *(const float4*)&Bsm[k][tc * 4];
        const float av[4] = {a4.x, a4.y, a4.z, a4.w};
        const float bv[4] = {b4.x, b4.y, b4.z, b4.w};
#pragma unroll
        for (int a = 0; a < 4; ++a)
#pragma unroll
          for (int b = 0; b < 4; ++b) acc[a][b] = fmaf(av[a], bv[b], acc[a][b]);
      }
    }
#pragma unroll
    for (int a = 0; a < 4; ++a)
#pragma unroll
      for (int b = 0; b < 4; ++b) sc[tr * 4 + a][tc * 4 + b] = acc[a][b];
    __syncthreads();
    if (tid < BLK) {
      for (int c = 0; c < BLK; ++c) {
        int p = pt + c;
        if (p < p1) tk_insert<KP>(tv, ti, np_key(ln, sc[tid][c], pnorm[p]), p);
      }
    }
  }

  if (tid < BLK) {
    int lab = lbase + tid;
    size_t base = ((size_t)lab * NCHUNK + chunk) * KP;
#pragma unroll
    for (int j = 0; j < KP; ++j) { part_s[base + j] = tv[j]; part_i[base + j] = ti[j]; }
  }
}

__global__ void k_merge_f32(const float* __restrict__ part_s,
                            const int* __restrict__ part_i,
                            const float* __restrict__ patch,
                            const float* __restrict__ lbl,
                            float* __restrict__ ctx) {
  const int lab = blockIdx.x;
  const int tid = threadIdx.x;
  __shared__ float cv[16][KP];
  __shared__ int ci[16][KP];
  __shared__ int nb[KTOP];

  const int total = NCHUNK * KP;
  if (tid < 16) {
    float v[KP]; int ii[KP];
#pragma unroll
    for (int j = 0; j < KP; ++j) { v[j] = INFINITY; ii[j] = 0x7fffffff; }
    for (int e = tid; e < total; e += 16)
      tk_insert<KP>(v, ii, part_s[(size_t)lab * total + e],
                    part_i[(size_t)lab * total + e]);
#pragma unroll
    for (int j = 0; j < KP; ++j) { cv[tid][j] = v[j]; ci[tid][j] = ii[j]; }
  }
  __syncthreads();
  if (tid == 0) {
    float v[KP]; int ii[KP];
#pragma unroll
    for (int j = 0; j < KP; ++j) { v[j] = INFINITY; ii[j] = 0x7fffffff; }
    for (int t = 0; t < 16; ++t)
      for (int j = 0; j < KP; ++j) tk_insert<KP>(v, ii, cv[t][j], ci[t][j]);
#pragma unroll
    for (int j = 0; j < KTOP; ++j) nb[j] = ii[j];
  }
  __syncthreads();
  float l = lbl[(size_t)lab * CDIM + tid];
  float mx = -INFINITY;
#pragma unroll
  for (int j = 0; j < KTOP; ++j)
    mx = fmaxf(mx, patch[(size_t)nb[j] * CDIM + tid]);
  ctx[(size_t)lab * CDIM + tid] = mx - l;
}

// ---------------- launch ----------------------------------------------------

static void launch_tail(const float* mood_emb, const float* genre_emb,
                        const float* sub_emb, const float* Wm_w, const float* Wm_b,
                        const float* Wg_w, const float* Wg_b, const float* Ws_w,
                        const float* Ws_b, const float* lnm_g, const float* lnm_b,
                        const float* lng_g, const float* lng_b, const float* lns_g,
                        const float* lns_b, const float* ctx_all, float* ctx_gm,
                        float* ctx_sm, float* ctx_sg, float* out,
                        hipStream_t stream) {
  k_level_out<<<NMOOD, 256, 0, stream>>>(mood_emb, ctx_all, nullptr, nullptr, 2,
                                         Wm_w, Wm_b, lnm_g, lnm_b, out);
  k_small_agg<<<NGENRE, 256, 0, stream>>>(genre_emb, out, NMOOD, 4, ctx_gm);
  k_level_out<<<NGENRE, 256, 0, stream>>>(genre_emb, ctx_all + NMOOD * CDIM, ctx_gm,
                                          nullptr, 3, Wg_w, Wg_b, lng_g, lng_b,
                                          out + NMOOD * CDIM);
  k_small_agg<<<NSUB, 256, 0, stream>>>(sub_emb, out, NMOOD, 3, ctx_sm);
  k_small_agg<<<NSUB, 256, 0, stream>>>(sub_emb, out + NMOOD * CDIM, NGENRE, 4, ctx_sg);
  k_level_out<<<NSUB, 256, 0, stream>>>(sub_emb, ctx_all + (NMOOD + NGENRE) * CDIM,
                                        ctx_sm, ctx_sg, 4, Ws_w, Ws_b, lns_g, lns_b,
                                        out + NMOOD * CDIM + NGENRE * CDIM);
}

extern "C" void kernel_launch(void* const* d_in, const int* in_sizes, int n_in,
                              void* d_out, int out_size, void* d_ws, size_t ws_size,
                              hipStream_t stream) {
  const float* patch     = (const float*)d_in[0];
  const float* mood_emb  = (const float*)d_in[1];
  const float* genre_emb = (const float*)d_in[2];
  const float* sub_emb   = (const float*)d_in[3];
  const float* Wm_w = (const float*)d_in[4];
  const float* Wm_b = (const float*)d_in[5];
  const float* Wg_w = (const float*)d_in[6];
  const float* Wg_b = (const float*)d_in[7];
  const float* Ws_w = (const float*)d_in[8];
  const float* Ws_b = (const float*)d_in[9];
  const float* lnm_g = (const float*)d_in[10];
  const float* lnm_b = (const float*)d_in[11];
  const float* lng_g = (const float*)d_in[12];
  const float* lng_b = (const float*)d_in[13];
  const float* lns_g = (const float*)d_in[14];
  const float* lns_b = (const float*)d_in[15];
  float* out = (float*)d_out;
  float* ws = (float*)d_ws;

  const size_t REQ = 15274112ull * 4ull;  // ~61.1 MB (proven fits, R10/R11)

  if (ws_size >= REQ) {
    // ---- MFMA path layout (unchanged from R11) ----
    float* lbl     = ws;                     // 212992
    float* pnorm   = lbl + NLBL * CDIM;      // 100352
    float* lnorm   = pnorm + 100352;         // 1024
    float* ctx_all = lnorm + 1024;           // 212992
    float* ctx_gm  = ctx_all + NLBL * CDIM;  // 65536
    float* ctx_sm  = ctx_gm + NGENRE * CDIM; // 131072
    float* ctx_sg  = ctx_sm + NSUB * CDIM;   // 131072
    float* part_s  = ctx_sg + NSUB * CDIM;   // 832*101*9 = 756288
    int*   part_i  = (int*)(part_s + (size_t)NLBL * NCH4 * KPS4);
    unsigned short* packed = (unsigned short*)(part_i + (size_t)NLBL * NCH4 * KPS4);
    unsigned short* lblbf  = packed + (size_t)NPATCH * CDIM;

    k_lbl_prep<<<NLBL / 16, 256, 0, stream>>>(mood_emb, genre_emb, sub_emb,
                                              lbl, lblbf, lnorm);
    k_prep3<<<2048, 256, 0, stream>>>(patch, packed, pnorm);
    k_screen_mfma<<<13 * NCH4, 256, 0, stream>>>(lblbf, packed, pnorm,
                                                 part_s, part_i);
    k_merge_mfma<<<NLBL, 256, 0, stream>>>(part_s, part_i, patch, lbl, pnorm,
                                           lnorm, ctx_all);
    launch_tail(mood_emb, genre_emb, sub_emb, Wm_w, Wm_b, Wg_w, Wg_b, Ws_w, Ws_b,
                lnm_g, lnm_b, lng_g, lng_b, lns_g, lns_b, ctx_all, ctx_gm, ctx_sm,
                ctx_sg, out, stream);
  } else {
    // ---- R4 fallback layout (known to fit) ----
    float* lbl    = ws;
    float* pnorm  = lbl + NLBL * CDIM;
    float* lnorm  = pnorm + 100352;
    float* part_s = lnorm + 1024;
    int*   part_i = (int*)(part_s + NLBL * NCHUNK * KP);
    float* ctx_all = part_s + 2 * NLBL * NCHUNK * KP;
    float* ctx_gm  = ctx_all + NLBL * CDIM;
    float* ctx_sm  = ctx_gm + NGENRE * CDIM;
    float* ctx_sg  = ctx_sm + NSUB * CDIM;

    k_concat_labels<<<NLBL, 256, 0, stream>>>(mood_emb, genre_emb, sub_emb, lbl);
    k_norms_np<<<512, 256, 0, stream>>>(patch, NPATCH, pnorm);
    k_norms_np<<<4, 256, 0, stream>>>(lbl, NLBL, lnorm);
    dim3 gscr(NCHUNK, NLBL / BLK);
    k_screen_f32<<<gscr, 256, 0, stream>>>(lbl, patch, pnorm, lnorm, part_s, part_i);
    k_merge_f32<<<NLBL, 256, 0, stream>>>(part_s, part_i, patch, lbl, ctx_all);
    launch_tail(mood_emb, genre_emb, sub_emb, Wm_w, Wm_b, Wg_w, Wg_b, Ws_w, Ws_b,
                lnm_g, lnm_b, lng_g, lng_b, lns_g, lns_b, ctx_all, ctx_gm, ctx_sm,
                ctx_sg, out, stream);
  }
}

// Round 13
// 525.334 us; speedup vs baseline: 4.3151x; 1.0898x over previous
//
#include <hip/hip_runtime.h>
#include <math.h>

#define NPATCH 100000
#define CDIM   256
#define NMOOD  64
#define NGENRE 256
#define NSUB   512
#define NLBL   832          // 64+256+512
#define KTOP   9
#define NGRPTOT 6250        // NPATCH/16

// ---- f32 fallback screen constants (R4, known-green) ----
#define NCHUNK 39
#define CHUNK  2624
#define BLK    64
#define KC     32
#define KP     12

// ---- MFMA screen constants ----
#define PBLK4  992          // patches per chunk (62 groups)
#define NCH4   101          // 101*992 = 100192 >= 100000
#define SL4    4            // per-lane list depth
#define KPS4   9            // per-(label,chunk) stored candidates
#define NCAND  192          // merge candidates (64x12 -> 16x12)

typedef __attribute__((ext_vector_type(8))) short bf16x8;
typedef __attribute__((ext_vector_type(8))) unsigned short u16x8;
typedef __attribute__((ext_vector_type(4))) float f32x4;

// ---------------- serial top-k insert (ascending by (val,idx)) --------------

template <int K>
__device__ __forceinline__ void tk_insert(float (&v)[K], int (&ii)[K],
                                          float s, int idx) {
  if (s < v[K - 1] || (s == v[K - 1] && idx < ii[K - 1])) {
    v[K - 1] = s; ii[K - 1] = idx;
#pragma unroll
    for (int t = K - 1; t > 0; --t) {
      bool sw = (v[t] < v[t - 1]) || (v[t] == v[t - 1] && ii[t] < ii[t - 1]);
      if (sw) {
        float fv = v[t]; v[t] = v[t - 1]; v[t - 1] = fv;
        int fi = ii[t]; ii[t] = ii[t - 1]; ii[t - 1] = fi;
      }
    }
  }
}

// fast screen insert: branch-free, NO idx tie-break (ascending-idx processing
// keeps lower idx on equal keys; exact re-rank downstream finalizes order).

template <int K>
__device__ __forceinline__ void tk_fast(float (&v)[K], int (&ii)[K],
                                        float s, int idx) {
  bool ins = s < v[K - 1];
  v[K - 1] = ins ? s : v[K - 1];
  ii[K - 1] = ins ? idx : ii[K - 1];
#pragma unroll
  for (int t = K - 1; t > 0; --t) {
    bool sw = v[t] < v[t - 1];
    float a0 = sw ? v[t] : v[t - 1];
    float a1 = sw ? v[t - 1] : v[t];
    int b0 = sw ? ii[t] : ii[t - 1];
    int b1 = sw ? ii[t - 1] : ii[t];
    v[t - 1] = a0; v[t] = a1; ii[t - 1] = b0; ii[t] = b1;
  }
}

// ------ numpy-pairwise sum of squares over 256 contiguous floats ------------

__device__ float np_sq256(const float* a) {
  float b0, b1;
  {
    float r[8];
#pragma unroll
    for (int i = 0; i < 8; ++i) { float x = a[i]; r[i] = __fmul_rn(x, x); }
    for (int j = 8; j < 128; j += 8)
#pragma unroll
      for (int i = 0; i < 8; ++i) {
        float x = a[j + i];
        r[i] = __fadd_rn(r[i], __fmul_rn(x, x));
      }
    b0 = __fadd_rn(__fadd_rn(__fadd_rn(r[0], r[1]), __fadd_rn(r[2], r[3])),
                   __fadd_rn(__fadd_rn(r[4], r[5]), __fadd_rn(r[6], r[7])));
  }
  {
    float r[8];
#pragma unroll
    for (int i = 0; i < 8; ++i) { float x = a[128 + i]; r[i] = __fmul_rn(x, x); }
    for (int j = 8; j < 128; j += 8)
#pragma unroll
      for (int i = 0; i < 8; ++i) {
        float x = a[128 + j + i];
        r[i] = __fadd_rn(r[i], __fmul_rn(x, x));
      }
    b1 = __fadd_rn(__fadd_rn(__fadd_rn(r[0], r[1]), __fadd_rn(r[2], r[3])),
                   __fadd_rn(__fadd_rn(r[4], r[5]), __fadd_rn(r[6], r[7])));
  }
  return __fadd_rn(b0, b1);
}

__device__ __forceinline__ float np_key(float ln, float dot, float pn) {
  return __fadd_rn(__fsub_rn(ln, __fmul_rn(2.f, dot)), pn);
}

__device__ __forceinline__ unsigned short f2bf(float x) {
  unsigned u = __float_as_uint(x);
  return (unsigned short)((u + 0x7fffu + ((u >> 16) & 1u)) >> 16);
}

// ---------------- kernel: fused patch prep: packed bf16 + np-exact norms ----

__global__ __launch_bounds__(256) void k_prep3(const float* __restrict__ src,
                                               unsigned short* __restrict__ packed,
                                               float* __restrict__ norms) {
  __shared__ float lds[4][4][260];
  const int tid = threadIdx.x;
  const int w = tid >> 6, l = tid & 63;
  const int rr = l >> 4;            // row within wave quad
  const int h = (l >> 3) & 1;       // 128-half
  const int i = l & 7;              // np accumulator class
  const int kk = l >> 3, kg = (l >> 1) & 3, e = (l & 1) * 4;  // pack coords
  for (int base = blockIdx.x * 16; base < NPATCH; base += gridDim.x * 16) {
    int row = base + w * 4;
    __syncthreads();
#pragma unroll
    for (int q = 0; q < 4; ++q) {
      int r = row + q;
      if (r < NPATCH) {
        float4 v = *(const float4*)&src[(size_t)r * CDIM + l * 4];
        ushort4 o = make_ushort4(f2bf(v.x), f2bf(v.y), f2bf(v.z), f2bf(v.w));
        int gg = r >> 4, col = r & 15;
        *(ushort4*)&packed[((size_t)(gg * 8 + kk)) * 512 + (col + 16 * kg) * 8 + e] = o;
        lds[w][q][l * 4 + 0] = v.x; lds[w][q][l * 4 + 1] = v.y;
        lds[w][q][l * 4 + 2] = v.z; lds[w][q][l * 4 + 3] = v.w;
      }
    }
    __syncthreads();
    int r = row + rr;
    if (r < NPATCH) {
      const float* a = &lds[w][rr][h * 128];
      float x = a[i];
      float acc = __fmul_rn(x, x);
#pragma unroll
      for (int j = 1; j < 16; ++j) {
        float y = a[j * 8 + i];
        acc = __fadd_rn(acc, __fmul_rn(y, y));
      }
      float t = __fadd_rn(acc, __shfl_xor(acc, 1));
      t = __fadd_rn(t, __shfl_xor(t, 2));
      t = __fadd_rn(t, __shfl_xor(t, 4));
      float o = __shfl_xor(t, 8);
      if (h == 0 && i == 0) norms[r] = __fadd_rn(t, o);
    }
  }
}

// ---------------- kernel: fused label prep: concat + f32 + bf16 + norms -----

__global__ __launch_bounds__(256) void k_lbl_prep(
    const float* __restrict__ mood, const float* __restrict__ genre,
    const float* __restrict__ sub, float* __restrict__ lbl,
    unsigned short* __restrict__ lblbf, float* __restrict__ lnorm) {
  __shared__ float lds[4][4][260];
  const int tid = threadIdx.x;
  const int w = tid >> 6, l = tid & 63;
  const int rr = l >> 4, h = (l >> 3) & 1, i = l & 7;
  const int row = blockIdx.x * 16 + w * 4;
#pragma unroll
  for (int q = 0; q < 4; ++q) {
    int r = row + q;
    const float* srcr = (r < NMOOD) ? &mood[(size_t)r * CDIM]
                      : (r < NMOOD + NGENRE) ? &genre[(size_t)(r - NMOOD) * CDIM]
                      : &sub[(size_t)(r - NMOOD - NGENRE) * CDIM];
    float4 v = *(const float4*)&srcr[l * 4];
    *(float4*)&lbl[(size_t)r * CDIM + l * 4] = v;
    ushort4 o = make_ushort4(f2bf(v.x), f2bf(v.y), f2bf(v.z), f2bf(v.w));
    *(ushort4*)&lblbf[(size_t)r * CDIM + l * 4] = o;
    lds[w][q][l * 4 + 0] = v.x; lds[w][q][l * 4 + 1] = v.y;
    lds[w][q][l * 4 + 2] = v.z; lds[w][q][l * 4 + 3] = v.w;
  }
  __syncthreads();
  {
    int r = row + rr;
    const float* a = &lds[w][rr][h * 128];
    float x = a[i];
    float acc = __fmul_rn(x, x);
#pragma unroll
    for (int j = 1; j < 16; ++j) {
      float y = a[j * 8 + i];
      acc = __fadd_rn(acc, __fmul_rn(y, y));
    }
    float t = __fadd_rn(acc, __shfl_xor(acc, 1));
    t = __fadd_rn(t, __shfl_xor(t, 2));
    t = __fadd_rn(t, __shfl_xor(t, 4));
    float o = __shfl_xor(t, 8);
    if (h == 0 && i == 0) lnorm[r] = __fadd_rn(t, o);
  }
}

// ---------------- async global->LDS helper ----------------------------------

__device__ __forceinline__ void gload_lds16(const void* g, void* l) {
  __builtin_amdgcn_global_load_lds(
      (const __attribute__((address_space(1))) unsigned int*)g,
      (__attribute__((address_space(3))) unsigned int*)l, 16, 0, 0);
}

// ---------------- kernel: MFMA bf16 screen (R11, unchanged — proven) --------

__global__ __launch_bounds__(256) void k_screen_mfma(
    const unsigned short* __restrict__ lblbf,
    const unsigned short* __restrict__ packed,
    const float* __restrict__ pnorm,
    float* __restrict__ part_s, int* __restrict__ part_i) {
  __shared__ float pn_lds[PBLK4];                  // 3.97 KB
  __shared__ __align__(16) char smem[2][8192];     // 16 KB
  const int tid = threadIdx.x;
  const int w = tid >> 6, l = tid & 63;
  const int col = l & 15, kg = l >> 4;
  const int lgrp = blockIdx.x % 13;
  const int chunk = blockIdx.x / 13;
  const int lab0 = lgrp * 64 + w * 16;
  const int p0 = chunk * PBLK4;
  const int grp0 = p0 >> 4;
  const int ngrp = min(PBLK4 / 16, (NPATCH - p0 + 15) >> 4);

  for (int e = tid; e < PBLK4; e += 256) {
    int p = p0 + e;
    pn_lds[e] = (p < NPATCH) ? pnorm[p] : INFINITY;
  }

  bf16x8 a[8];
#pragma unroll
  for (int kk = 0; kk < 8; ++kk)
    a[kk] = *(const bf16x8*)&lblbf[(size_t)(lab0 + col) * CDIM + kk * 32 + kg * 8];

  float lv[SL4]; int li[SL4];
#pragma unroll
  for (int j = 0; j < SL4; ++j) { lv[j] = INFINITY; li[j] = 0x7fffffff; }

  auto stage = [&](int buf, int g) {
    int gg = grp0 + g;
    if (gg > NGRPTOT - 1) gg = NGRPTOT - 1;
    const char* gsrc = (const char*)packed + (size_t)gg * 8192;
    gload_lds16(gsrc + tid * 16, &smem[buf][tid * 16]);
    gload_lds16(gsrc + (tid + 256) * 16, &smem[buf][(tid + 256) * 16]);
  };

  stage(0, 0);
  __syncthreads();
  for (int g = 0; g < ngrp; ++g) {
    const int cb = g & 1;
    if (g + 1 < ngrp) stage(cb ^ 1, g + 1);
    const char* gb = smem[cb];
    bf16x8 bb[8];
#pragma unroll
    for (int kk = 0; kk < 8; ++kk)
      bb[kk] = *(const bf16x8*)(gb + kk * 1024 + l * 16);
    f32x4 ac0 = {0.f, 0.f, 0.f, 0.f}, ac1 = {0.f, 0.f, 0.f, 0.f};
#pragma unroll
    for (int kk = 0; kk < 4; ++kk) {
      ac0 = __builtin_amdgcn_mfma_f32_16x16x32_bf16(bb[2 * kk], a[2 * kk],
                                                    ac0, 0, 0, 0);
      ac1 = __builtin_amdgcn_mfma_f32_16x16x32_bf16(bb[2 * kk + 1],
                                                    a[2 * kk + 1], ac1,
                                                    0, 0, 0);
    }
    const int pib = g * 16 + kg * 4;
    float k0 = fmaf(-2.f, ac0[0] + ac1[0], pn_lds[pib + 0]);
    float k1 = fmaf(-2.f, ac0[1] + ac1[1], pn_lds[pib + 1]);
    float k2 = fmaf(-2.f, ac0[2] + ac1[2], pn_lds[pib + 2]);
    float k3 = fmaf(-2.f, ac0[3] + ac1[3], pn_lds[pib + 3]);
    if (fminf(fminf(k0, k1), fminf(k2, k3)) < lv[SL4 - 1]) {
      tk_fast<SL4>(lv, li, k0, p0 + pib + 0);
      tk_fast<SL4>(lv, li, k1, p0 + pib + 1);
      tk_fast<SL4>(lv, li, k2, p0 + pib + 2);
      tk_fast<SL4>(lv, li, k3, p0 + pib + 3);
    }
    __syncthreads();
  }

  float v9[KPS4]; int i9[KPS4];
#pragma unroll
  for (int j = 0; j < KPS4; ++j) {
    v9[j] = (j < SL4) ? lv[j] : INFINITY;
    i9[j] = (j < SL4) ? li[j] : 0x7fffffff;
  }
#pragma unroll
  for (int j = 0; j < SL4; ++j) {
    float rv = __shfl_xor(lv[j], 16);
    int ri = __shfl_xor(li[j], 16);
    tk_fast<KPS4>(v9, i9, rv, ri);
  }
  {
    float tv[KPS4]; int ti[KPS4];
#pragma unroll
    for (int j = 0; j < KPS4; ++j) { tv[j] = v9[j]; ti[j] = i9[j]; }
#pragma unroll
    for (int j = 0; j < KPS4; ++j) {
      float rv = __shfl_xor(tv[j], 32);
      int ri = __shfl_xor(ti[j], 32);
      tk_fast<KPS4>(v9, i9, rv, ri);
    }
  }
  if (kg == 0) {
    int lab = lab0 + col;
    size_t base = ((size_t)lab * NCH4 + chunk) * KPS4;
#pragma unroll
    for (int j = 0; j < KPS4; ++j) { part_s[base + j] = v9[j]; part_i[base + j] = i9[j]; }
  }
}

// ---------------- kernel: merge + EXACT np-f32 re-rank + max-agg ------------
// funnel 64x12 -> 16x12 = 192 candidates (every stream depth >= KTOP=9).
// Exact chains run from LDS-STAGED candidate rows (coalesced 1KB-per-row
// bursts; pad-257 -> conflict-free lane-per-row reads). Chain order is the
// same sequential fmaf k=0..255 -> bit-identical keys. Parallel rank.

__global__ void k_merge_mfma(const float* __restrict__ part_s,
                             const int* __restrict__ part_i,
                             const float* __restrict__ patch,
                             const float* __restrict__ lbl,
                             const float* __restrict__ pnorm,
                             const float* __restrict__ lnorm,
                             float* __restrict__ ctx) {
  const int lab = blockIdx.x;
  const int tid = threadIdx.x;
  __shared__ float lsh[CDIM];
  __shared__ float st[64][257];    // 65.8 KB staging
  __shared__ float sv[64 * 12];
  __shared__ int   si[64 * 12];
  __shared__ int   cidx[NCAND];
  __shared__ float ckey[NCAND];
  __shared__ int   nb[KTOP];

  lsh[tid] = lbl[(size_t)lab * CDIM + tid];
  const int total = NCH4 * KPS4;  // 909
  if (tid < 64) {
    float v[12]; int ii[12];
#pragma unroll
    for (int j = 0; j < 12; ++j) { v[j] = INFINITY; ii[j] = 0x7fffffff; }
    for (int e = tid; e < total; e += 64)
      tk_insert<12>(v, ii, part_s[(size_t)lab * total + e],
                    part_i[(size_t)lab * total + e]);
#pragma unroll
    for (int j = 0; j < 12; ++j) { sv[tid * 12 + j] = v[j]; si[tid * 12 + j] = ii[j]; }
  }
  __syncthreads();
  if (tid < 16) {
    float v[12]; int ii[12];
#pragma unroll
    for (int j = 0; j < 12; ++j) { v[j] = INFINITY; ii[j] = 0x7fffffff; }
    for (int e = 0; e < 48; ++e)
      tk_insert<12>(v, ii, sv[tid * 48 + e], si[tid * 48 + e]);
#pragma unroll
    for (int j = 0; j < 12; ++j) cidx[tid * 12 + j] = ii[j];
  }
  __syncthreads();
  // exact keys, 64-candidate batches staged through LDS
  float key = INFINITY;
  const float ln = lnorm[lab];
#pragma unroll 1
  for (int b = 0; b < NCAND / 64; ++b) {
    for (int idx = tid; idx < 64 * 64; idx += 256) {
      int r = idx >> 6, j = idx & 63;
      int c = cidx[b * 64 + r];
      if (c != 0x7fffffff) {
        float4 v = *(const float4*)&patch[(size_t)c * CDIM + j * 4];
        st[r][j * 4 + 0] = v.x; st[r][j * 4 + 1] = v.y;
        st[r][j * 4 + 2] = v.z; st[r][j * 4 + 3] = v.w;
      }
    }
    __syncthreads();
    int myr = tid - b * 64;
    if (myr >= 0 && myr < 64) {
      int c = cidx[tid];
      if (c != 0x7fffffff) {
        const float* a = st[myr];
        float dot = 0.f;
        for (int k = 0; k < CDIM; ++k) dot = fmaf(lsh[k], a[k], dot);
        key = np_key(ln, dot, pnorm[c]);
      }
    }
    __syncthreads();
  }
  if (tid < NCAND) ckey[tid] = key;
  __syncthreads();
  if (tid < NCAND) {
    float myk = ckey[tid]; int myc = cidx[tid];
    int rank = 0;
    for (int j = 0; j < NCAND; ++j) {
      float kj = ckey[j]; int cj = cidx[j];
      rank += (kj < myk || (kj == myk && cj < myc)) ? 1 : 0;
    }
    if (myc != 0x7fffffff && rank < KTOP) nb[rank] = myc;
  }
  __syncthreads();
  float mx = -INFINITY;
#pragma unroll
  for (int j = 0; j < KTOP; ++j)
    mx = fmaxf(mx, patch[(size_t)nb[j] * CDIM + tid]);
  ctx[(size_t)lab * CDIM + tid] = mx - lsh[tid];
}

// ---------------- kernel: small label->label agg (np-f32, LDS-staged) -------
// label norm from precomputed lnormb[row] (bit-identical producer tree);
// target norms from precomputed tnorm[] (level_out epilogue tree); target
// rows staged 64/batch into LDS (coalesced), chains conflict-free (pad 257).

__global__ void k_small_agg(const float* __restrict__ lbl_rows,
                            const float* __restrict__ tgt,
                            const float* __restrict__ lnormb,
                            const float* __restrict__ tnorm,
                            int M, int k, float* __restrict__ ctx) {
  const int row = blockIdx.x;
  const int tid = threadIdx.x;
  __shared__ float lsh[CDIM];
  __shared__ float st[64][257];    // 65.8 KB
  __shared__ float skey[256];
  __shared__ int nb[4];
  lsh[tid] = lbl_rows[(size_t)row * CDIM + tid];
  const float lns = lnormb[row];
  float key = INFINITY;
  const int nbatch = (M + 63) / 64;
#pragma unroll 1
  for (int b = 0; b < nbatch; ++b) {
    __syncthreads();
    for (int idx = tid; idx < 64 * 64; idx += 256) {
      int r = idx >> 6, j = idx & 63;
      int gr = b * 64 + r;
      if (gr < M) {
        float4 v = *(const float4*)&tgt[(size_t)gr * CDIM + j * 4];
        st[r][j * 4 + 0] = v.x; st[r][j * 4 + 1] = v.y;
        st[r][j * 4 + 2] = v.z; st[r][j * 4 + 3] = v.w;
      }
    }
    __syncthreads();
    int myr = tid - b * 64;
    if (myr >= 0 && myr < 64 && tid < M) {
      const float* a = st[myr];
      float dot = 0.f;
      for (int c = 0; c < CDIM; ++c) dot = fmaf(lsh[c], a[c], dot);
      key = np_key(lns, dot, tnorm[tid]);
    }
  }
  skey[tid] = key;
  __syncthreads();
  {
    int rank = 0;
    for (int j = 0; j < M; ++j) {
      float kj = skey[j];
      rank += (kj < key || (kj == key && j < tid)) ? 1 : 0;
    }
    if (tid < M && rank < k) nb[rank] = tid;
  }
  __syncthreads();
  float mx = -INFINITY;
  for (int t = 0; t < k; ++t) mx = fmaxf(mx, tgt[(size_t)nb[t] * CDIM + tid]);
  ctx[(size_t)row * CDIM + tid] = mx - lsh[tid];
}

// ---------------- kernel: linear(concat) + residual + LayerNorm (f64) -------
// 8-way ILP f64 partials; optional np-exact output-row norm epilogue (class
// tree, bit-identical to np_sq256 over the stored f32 out row).

__device__ __forceinline__ double block_sum_256d(double x, double* red) {
#pragma unroll
  for (int m = 32; m >= 1; m >>= 1) x += __shfl_xor(x, m);
  int wid = threadIdx.x >> 6, lane = threadIdx.x & 63;
  if (lane == 0) red[wid] = x;
  __syncthreads();
  double s = red[0] + red[1] + red[2] + red[3];
  __syncthreads();
  return s;
}

__global__ void k_level_out(const float* __restrict__ emb,
                            const float* __restrict__ c1,
                            const float* __restrict__ c2,
                            const float* __restrict__ c3, int nseg,
                            const float* __restrict__ W,
                            const float* __restrict__ bias,
                            const float* __restrict__ gamma,
                            const float* __restrict__ beta,
                            float* __restrict__ out,
                            float* __restrict__ onorm) {
  __shared__ float xs[4 * CDIM];
  __shared__ double red[4];
  const int row = blockIdx.x, ch = threadIdx.x;
  float e = emb[(size_t)row * CDIM + ch];
  xs[ch] = e;
  if (nseg > 1) xs[CDIM + ch] = c1[(size_t)row * CDIM + ch];
  if (nseg > 2) xs[2 * CDIM + ch] = c2[(size_t)row * CDIM + ch];
  if (nseg > 3) xs[3 * CDIM + ch] = c3[(size_t)row * CDIM + ch];
  __syncthreads();
  const int F = nseg * CDIM;
  double ys[8];
#pragma unroll
  for (int m = 0; m < 8; ++m) ys[m] = 0.0;
  for (int j = 0; j < F; j += 8)
#pragma unroll
    for (int m = 0; m < 8; ++m)
      ys[m] += (double)xs[j + m] * (double)W[(size_t)(j + m) * CDIM + ch];
  double y = (double)e + (double)bias[ch] +
             (((ys[0] + ys[1]) + (ys[2] + ys[3])) +
              ((ys[4] + ys[5]) + (ys[6] + ys[7])));
  double mu = block_sum_256d(y, red) * (1.0 / 256.0);
  double d = y - mu;
  double var = block_sum_256d(d * d, red) * (1.0 / 256.0);
  float o = (float)(d / sqrt(var + 1e-5) * (double)gamma[ch] + (double)beta[ch]);
  out[(size_t)row * CDIM + ch] = o;
  if (onorm != nullptr) {
    __syncthreads();
    xs[ch] = o;
    __syncthreads();
    if (ch < 16) {
      int h = (ch >> 3) & 1, i = ch & 7;
      const float* a = &xs[h * 128];
      float x = a[i];
      float acc = __fmul_rn(x, x);
#pragma unroll
      for (int j = 1; j < 16; ++j) {
        float yv = a[j * 8 + i];
        acc = __fadd_rn(acc, __fmul_rn(yv, yv));
      }
      float t = __fadd_rn(acc, __shfl_xor(acc, 1));
      t = __fadd_rn(t, __shfl_xor(t, 2));
      t = __fadd_rn(t, __shfl_xor(t, 4));
      float ot = __shfl_xor(t, 8);
      if (h == 0 && i == 0) onorm[row] = __fadd_rn(t, ot);
    }
  }
}

// ---------------- FALLBACK: R4 f32 screen + merge (known-green) -------------

__global__ void k_concat_labels(const float* __restrict__ mood,
                                const float* __restrict__ genre,
                                const float* __restrict__ sub,
                                float* __restrict__ lbl) {
  int i = blockIdx.x * 256 + threadIdx.x;
  if (i < NMOOD * CDIM) lbl[i] = mood[i];
  else if (i < (NMOOD + NGENRE) * CDIM) lbl[i] = genre[i - NMOOD * CDIM];
  else lbl[i] = sub[i - (NMOOD + NGENRE) * CDIM];
}

__global__ void k_norms_np(const float* __restrict__ m, int n,
                           float* __restrict__ out) {
  int i = blockIdx.x * blockDim.x + threadIdx.x;
  int stride = gridDim.x * blockDim.x;
  for (; i < n; i += stride) out[i] = np_sq256(m + (size_t)i * CDIM);
}

__global__ void k_screen_f32(const float* __restrict__ lbl,
                             const float* __restrict__ patch,
                             const float* __restrict__ pnorm,
                             const float* __restrict__ lnorm,
                             float* __restrict__ part_s,
                             int* __restrict__ part_i) {
  __shared__ float Asm[KC][BLK];
  __shared__ float Bsm[KC][BLK];
  __shared__ float sc[BLK][BLK + 1];
  const int tid = threadIdx.x;
  const int tr = tid >> 4, tc = tid & 15;
  const int lbase = blockIdx.y * BLK;
  const int chunk = blockIdx.x;
  const int p0 = chunk * CHUNK;
  const int p1 = (p0 + CHUNK < NPATCH) ? p0 + CHUNK : NPATCH;

  float tv[KP]; int ti[KP];
#pragma unroll
  for (int j = 0; j < KP; ++j) { tv[j] = INFINITY; ti[j] = 0x7fffffff; }
  const float ln = (tid < BLK) ? lnorm[lbase + tid] : 0.f;

  const int sl = tid >> 2;
  const int skq = (tid & 3) * 4;

  for (int pt = p0; pt < p1; pt += BLK) {
    float acc[4][4];
#pragma unroll
    for (int a = 0; a < 4; ++a)
#pragma unroll
      for (int b = 0; b < 4; ++b) acc[a][b] = 0.f;

    for (int kc = 0; kc < CDIM; kc += KC) {
      __syncthreads();
      {
        const float* arow = &lbl[(size_t)(lbase + sl) * CDIM + kc];
        float4 va0 = *(const float4*)(arow + skq);
        float4 va1 = *(const float4*)(arow + 16 + skq);
        Asm[skq + 0][sl] = va0.x; Asm[skq + 1][sl] = va0.y;
        Asm[skq + 2][sl] = va0.z; Asm[skq + 3][sl] = va0.w;
        Asm[16 + skq + 0][sl] = va1.x; Asm[16 + skq + 1][sl] = va1.y;
        Asm[16 + skq + 2][sl] = va1.z; Asm[16 + skq + 3][sl] = va1.w;
        int p = pt + sl;
        float4 vb0 = make_float4(0.f, 0.f, 0.f, 0.f), vb1 = vb0;
        if (p < p1) {
          const float* brow = &patch[(size_t)p * CDIM + kc];
          vb0 = *(const float4*)(brow + skq);
          vb1 = *(const float4*)(brow + 16 + skq);
        }
        Bsm[skq + 0][sl] = vb0.x; Bsm[skq + 1][sl] = vb0.y;
        Bsm[skq + 2][sl] = vb0.z; Bsm[skq + 3][sl] = vb0.w;
        Bsm[16 + skq + 0][sl] = vb1.x; Bsm[16 + skq + 1][sl] = vb1.y;
        Bsm[16 + skq + 2][sl] = vb1.z; Bsm[16 + skq + 3][sl] = vb1.w;
      }
      __syncthreads();
#pragma unroll
      for (int k = 0; k < KC; ++k) {
        float4 a4 = *(const float4*)&Asm[k][tr * 4];
        float4 b4 = *(const float4*)&Bsm[k][tc * 4];
        const float av[4] = {a4.x, a4.y, a4.z, a4.w};
        const float bv[4] = {b4.x, b4.y, b4.z, b4.w};
#pragma unroll
        for (int a = 0; a < 4; ++a)
#pragma unroll
          for (int b = 0; b < 4; ++b) acc[a][b] = fmaf(av[a], bv[b], acc[a][b]);
      }
    }
#pragma unroll
    for (int a = 0; a < 4; ++a)
#pragma unroll
      for (int b = 0; b < 4; ++b) sc[tr * 4 + a][tc * 4 + b] = acc[a][b];
    __syncthreads();
    if (tid < BLK) {
      for (int c = 0; c < BLK; ++c) {
        int p = pt + c;
        if (p < p1) tk_insert<KP>(tv, ti, np_key(ln, sc[tid][c], pnorm[p]), p);
      }
    }
  }

  if (tid < BLK) {
    int lab = lbase + tid;
    size_t base = ((size_t)lab * NCHUNK + chunk) * KP;
#pragma unroll
    for (int j = 0; j < KP; ++j) { part_s[base + j] = tv[j]; part_i[base + j] = ti[j]; }
  }
}

__global__ void k_merge_f32(const float* __restrict__ part_s,
                            const int* __restrict__ part_i,
                            const float* __restrict__ patch,
                            const float* __restrict__ lbl,
                            float* __restrict__ ctx) {
  const int lab = blockIdx.x;
  const int tid = threadIdx.x;
  __shared__ float cv[16][KP];
  __shared__ int ci[16][KP];
  __shared__ int nb[KTOP];

  const int total = NCHUNK * KP;
  if (tid < 16) {
    float v[KP]; int ii[KP];
#pragma unroll
    for (int j = 0; j < KP; ++j) { v[j] = INFINITY; ii[j] = 0x7fffffff; }
    for (int e = tid; e < total; e += 16)
      tk_insert<KP>(v, ii, part_s[(size_t)lab * total + e],
                    part_i[(size_t)lab * total + e]);
#pragma unroll
    for (int j = 0; j < KP; ++j) { cv[tid][j] = v[j]; ci[tid][j] = ii[j]; }
  }
  __syncthreads();
  if (tid == 0) {
    float v[KP]; int ii[KP];
#pragma unroll
    for (int j = 0; j < KP; ++j) { v[j] = INFINITY; ii[j] = 0x7fffffff; }
    for (int t = 0; t < 16; ++t)
      for (int j = 0; j < KP; ++j) tk_insert<KP>(v, ii, cv[t][j], ci[t][j]);
#pragma unroll
    for (int j = 0; j < KTOP; ++j) nb[j] = ii[j];
  }
  __syncthreads();
  float l = lbl[(size_t)lab * CDIM + tid];
  float mx = -INFINITY;
#pragma unroll
  for (int j = 0; j < KTOP; ++j)
    mx = fmaxf(mx, patch[(size_t)nb[j] * CDIM + tid]);
  ctx[(size_t)lab * CDIM + tid] = mx - l;
}

// ---------------- launch ----------------------------------------------------

static void launch_tail(const float* mood_emb, const float* genre_emb,
                        const float* sub_emb, const float* Wm_w, const float* Wm_b,
                        const float* Wg_w, const float* Wg_b, const float* Ws_w,
                        const float* Ws_b, const float* lnm_g, const float* lnm_b,
                        const float* lng_g, const float* lng_b, const float* lns_g,
                        const float* lns_b, const float* ctx_all,
                        const float* lnorm, float* onorm_m, float* onorm_g,
                        float* ctx_gm, float* ctx_sm, float* ctx_sg, float* out,
                        hipStream_t stream) {
  k_level_out<<<NMOOD, 256, 0, stream>>>(mood_emb, ctx_all, nullptr, nullptr, 2,
                                         Wm_w, Wm_b, lnm_g, lnm_b, out, onorm_m);
  k_small_agg<<<NGENRE, 256, 0, stream>>>(genre_emb, out, lnorm + NMOOD,
                                          onorm_m, NMOOD, 4, ctx_gm);
  k_level_out<<<NGENRE, 256, 0, stream>>>(genre_emb, ctx_all + NMOOD * CDIM, ctx_gm,
                                          nullptr, 3, Wg_w, Wg_b, lng_g, lng_b,
                                          out + NMOOD * CDIM, onorm_g);
  k_small_agg<<<NSUB, 256, 0, stream>>>(sub_emb, out, lnorm + NMOOD + NGENRE,
                                        onorm_m, NMOOD, 3, ctx_sm);
  k_small_agg<<<NSUB, 256, 0, stream>>>(sub_emb, out + NMOOD * CDIM,
                                        lnorm + NMOOD + NGENRE, onorm_g,
                                        NGENRE, 4, ctx_sg);
  k_level_out<<<NSUB, 256, 0, stream>>>(sub_emb, ctx_all + (NMOOD + NGENRE) * CDIM,
                                        ctx_sm, ctx_sg, 4, Ws_w, Ws_b, lns_g, lns_b,
                                        out + NMOOD * CDIM + NGENRE * CDIM, nullptr);
}

extern "C" void kernel_launch(void* const* d_in, const int* in_sizes, int n_in,
                              void* d_out, int out_size, void* d_ws, size_t ws_size,
                              hipStream_t stream) {
  const float* patch     = (const float*)d_in[0];
  const float* mood_emb  = (const float*)d_in[1];
  const float* genre_emb = (const float*)d_in[2];
  const float* sub_emb   = (const float*)d_in[3];
  const float* Wm_w = (const float*)d_in[4];
  const float* Wm_b = (const float*)d_in[5];
  const float* Wg_w = (const float*)d_in[6];
  const float* Wg_b = (const float*)d_in[7];
  const float* Ws_w = (const float*)d_in[8];
  const float* Ws_b = (const float*)d_in[9];
  const float* lnm_g = (const float*)d_in[10];
  const float* lnm_b = (const float*)d_in[11];
  const float* lng_g = (const float*)d_in[12];
  const float* lng_b = (const float*)d_in[13];
  const float* lns_g = (const float*)d_in[14];
  const float* lns_b = (const float*)d_in[15];
  float* out = (float*)d_out;
  float* ws = (float*)d_ws;

  const size_t REQ = 15274432ull * 4ull;  // ~61.1 MB (R10 layout + 320 norm words)

  if (ws_size >= REQ) {
    // ---- MFMA path layout ----
    float* lbl     = ws;                     // 212992
    float* pnorm   = lbl + NLBL * CDIM;      // 100352
    float* lnorm   = pnorm + 100352;         // 1024
    float* ctx_all = lnorm + 1024;           // 212992
    float* ctx_gm  = ctx_all + NLBL * CDIM;  // 65536
    float* ctx_sm  = ctx_gm + NGENRE * CDIM; // 131072
    float* ctx_sg  = ctx_sm + NSUB * CDIM;   // 131072
    float* part_s  = ctx_sg + NSUB * CDIM;   // 756288
    int*   part_i  = (int*)(part_s + (size_t)NLBL * NCH4 * KPS4);
    unsigned short* packed = (unsigned short*)(part_i + (size_t)NLBL * NCH4 * KPS4);
    unsigned short* lblbf  = packed + (size_t)NPATCH * CDIM;
    float* onorm_m = (float*)(lblbf + (size_t)NLBL * CDIM);  // 64
    float* onorm_g = onorm_m + NMOOD;                        // 256

    k_lbl_prep<<<NLBL / 16, 256, 0, stream>>>(mood_emb, genre_emb, sub_emb,
                                              lbl, lblbf, lnorm);
    k_prep3<<<2048, 256, 0, stream>>>(patch, packed, pnorm);
    k_screen_mfma<<<13 * NCH4, 256, 0, stream>>>(lblbf, packed, pnorm,
                                                 part_s, part_i);
    k_merge_mfma<<<NLBL, 256, 0, stream>>>(part_s, part_i, patch, lbl, pnorm,
                                           lnorm, ctx_all);
    launch_tail(mood_emb, genre_emb, sub_emb, Wm_w, Wm_b, Wg_w, Wg_b, Ws_w, Ws_b,
                lnm_g, lnm_b, lng_g, lng_b, lns_g, lns_b, ctx_all, lnorm,
                onorm_m, onorm_g, ctx_gm, ctx_sm, ctx_sg, out, stream);
  } else {
    // ---- R4 fallback layout ----
    float* lbl    = ws;
    float* pnorm  = lbl + NLBL * CDIM;
    float* lnorm  = pnorm + 100352;
    float* part_s = lnorm + 1024;
    int*   part_i = (int*)(part_s + NLBL * NCHUNK * KP);
    float* ctx_all = part_s + 2 * NLBL * NCHUNK * KP;
    float* ctx_gm  = ctx_all + NLBL * CDIM;
    float* ctx_sm  = ctx_gm + NGENRE * CDIM;
    float* ctx_sg  = ctx_sm + NSUB * CDIM;
    float* onorm_m = ctx_sg + NSUB * CDIM;
    float* onorm_g = onorm_m + NMOOD;

    k_concat_labels<<<NLBL, 256, 0, stream>>>(mood_emb, genre_emb, sub_emb, lbl);
    k_norms_np<<<512, 256, 0, stream>>>(patch, NPATCH, pnorm);
    k_norms_np<<<4, 256, 0, stream>>>(lbl, NLBL, lnorm);
    dim3 gscr(NCHUNK, NLBL / BLK);
    k_screen_f32<<<gscr, 256, 0, stream>>>(lbl, patch, pnorm, lnorm, part_s, part_i);
    k_merge_f32<<<NLBL, 256, 0, stream>>>(part_s, part_i, patch, lbl, ctx_all);
    launch_tail(mood_emb, genre_emb, sub_emb, Wm_w, Wm_b, Wg_w, Wg_b, Ws_w, Ws_b,
                lnm_g, lnm_b, lng_g, lng_b, lns_g, lns_b, ctx_all, lnorm,
                onorm_m, onorm_g, ctx_gm, ctx_sm, ctx_sg, out, stream);
  }
}